// Round 1
// baseline (1251.919 us; speedup 1.0000x reference)
//
#include <hip/hip_runtime.h>

// ---------------------------------------------------------------------------
// TransformerBlock on MI355X (gfx950), round 0: correctness-first bf16 MFMA.
// Structure: rmsnorm -> QKV gemm -> rope/repack -> flash attn -> wo gemm(+x)
//            -> rmsnorm -> gate(top2, f32) -> shared FFN -> dense MoE (8 experts,
//            weighted accumulate) -> final fused add.
// GEMM: 128x128 tile, BK=64, 4 waves, mfma_f32_16x16x32_bf16,
//       global_load_lds(16B) staging with pre-swizzled source (m201 pattern).
// ---------------------------------------------------------------------------

typedef unsigned short u16;
typedef __attribute__((ext_vector_type(8))) short bh8;   // 8 x bf16 (4 VGPRs)
typedef __attribute__((ext_vector_type(4))) float fv4;

#define LOG2E 1.4426950408889634f

__device__ __forceinline__ float b2f(u16 u) {
  return __builtin_bit_cast(float, ((unsigned)u) << 16);
}
__device__ __forceinline__ u16 f2b(float f) {
  unsigned x = __builtin_bit_cast(unsigned, f);
  return (u16)((x + 0x7fffu + ((x >> 16) & 1u)) >> 16);  // RNE
}
__device__ __forceinline__ fv4 mfma16(bh8 a, bh8 b, fv4 c) {
  return __builtin_amdgcn_mfma_f32_16x16x32_bf16(a, b, c, 0, 0, 0);
}

#define GLD16(g, l)                                                        \
  __builtin_amdgcn_global_load_lds(                                        \
      (const __attribute__((address_space(1))) void*)(g),                  \
      (__attribute__((address_space(3))) void*)(l), 16, 0, 0)

// Read one MFMA fragment (16B) from a [rows][64] bf16 LDS tile whose rows are
// 128B and whose 16B blocks are XOR-swizzled by (row&7).
__device__ __forceinline__ bh8 lds_frag(const u16* base, int row, int b8) {
  int off = row * 128 + ((b8 * 16) ^ ((row & 7) << 4));
  return *(const bh8*)((const char*)base + off);
}

// ---------------------------------------------------------------------------
// Generic GEMM: C[M,N] = A[M,K] (bf16) @ B[N,K]^T (bf16), f32 accumulate.
// MODE 0: Cb = bf16(gemm)
// MODE 1: Cf = add1 + gemm
// MODE 2: Cf  = rowscale[row] * (gemm + bias[col])   (MoE init)
// MODE 3: Cf += rowscale[row] * (gemm + bias[col])   (MoE accumulate)
// MODE 4: Cf = add1 + add2 + gemm                     (final output)
// ---------------------------------------------------------------------------
template <int MODE>
__global__ __launch_bounds__(256) void gemm_bt(
    const u16* __restrict__ A, const u16* __restrict__ B, int M, int N, int K,
    u16* __restrict__ Cb, float* __restrict__ Cf,
    const float* __restrict__ add1, const float* __restrict__ add2,
    const float* __restrict__ rowscale, const float* __restrict__ bias) {
  __shared__ u16 As[128 * 64];
  __shared__ u16 Bs[128 * 64];
  const int lane = threadIdx.x & 63;
  const int wid = threadIdx.x >> 6;
  const int wr = wid >> 1, wc = wid & 1;
  const int m0 = blockIdx.y * 128, n0 = blockIdx.x * 128;
  const int rr = lane >> 3;              // row-within-chunk 0..7
  const int b8s = (lane & 7) ^ rr;       // pre-swizzled source block
  fv4 acc[4][4] = {};

  for (int k0 = 0; k0 < K; k0 += 64) {
    __syncthreads();
#pragma unroll
    for (int i = 0; i < 4; ++i) {
      int c = wid * 4 + i;               // chunk 0..15, 8 rows each
      int row = c * 8 + rr;
      GLD16(A + (size_t)(m0 + row) * K + k0 + b8s * 8, &As[c * 512]);
      GLD16(B + (size_t)(n0 + row) * K + k0 + b8s * 8, &Bs[c * 512]);
    }
    __syncthreads();
#pragma unroll
    for (int ks = 0; ks < 2; ++ks) {
      int b8 = ks * 4 + (lane >> 4);
      bh8 af[4], bf[4];
#pragma unroll
      for (int mi = 0; mi < 4; ++mi)
        af[mi] = lds_frag(As, wr * 64 + mi * 16 + (lane & 15), b8);
#pragma unroll
      for (int ni = 0; ni < 4; ++ni)
        bf[ni] = lds_frag(Bs, wc * 64 + ni * 16 + (lane & 15), b8);
#pragma unroll
      for (int mi = 0; mi < 4; ++mi)
#pragma unroll
        for (int ni = 0; ni < 4; ++ni)
          acc[mi][ni] = mfma16(af[mi], bf[ni], acc[mi][ni]);
    }
  }

  const int r0b = m0 + wr * 64 + (lane >> 4) * 4;
  const int c0b = n0 + wc * 64 + (lane & 15);
#pragma unroll
  for (int mi = 0; mi < 4; ++mi) {
#pragma unroll
    for (int ni = 0; ni < 4; ++ni) {
      int c = c0b + ni * 16;
#pragma unroll
      for (int r = 0; r < 4; ++r) {
        int row = r0b + mi * 16 + r;
        size_t idx = (size_t)row * N + c;
        float v = acc[mi][ni][r];
        if constexpr (MODE == 0) Cb[idx] = f2b(v);
        else if constexpr (MODE == 1) Cf[idx] = add1[idx] + v;
        else if constexpr (MODE == 2) Cf[idx] = rowscale[row] * (v + bias[c]);
        else if constexpr (MODE == 3) Cf[idx] += rowscale[row] * (v + bias[c]);
        else Cf[idx] = add1[idx] + add2[idx] + v;
      }
    }
  }
}

// ---------------------------------------------------------------------------
// RMSNorm: f32 [T,1024] -> bf16 [T,1024], one block per token.
// ---------------------------------------------------------------------------
__global__ __launch_bounds__(256) void rmsnorm_bf16(
    const float* __restrict__ x, const float* __restrict__ w,
    u16* __restrict__ out) {
  int t = blockIdx.x;
  const float* xr = x + (size_t)t * 1024;
  fv4 v = *(const fv4*)(xr + threadIdx.x * 4);
  float ss = v[0] * v[0] + v[1] * v[1] + v[2] * v[2] + v[3] * v[3];
#pragma unroll
  for (int off = 1; off < 64; off <<= 1) ss += __shfl_xor(ss, off);
  __shared__ float red[4];
  int lane = threadIdx.x & 63, wid = threadIdx.x >> 6;
  if (lane == 0) red[wid] = ss;
  __syncthreads();
  float inv = rsqrtf((red[0] + red[1] + red[2] + red[3]) * (1.0f / 1024.f) + 1e-6f);
  u16* op = out + (size_t)t * 1024 + threadIdx.x * 4;
  const float* wp = w + threadIdx.x * 4;
#pragma unroll
  for (int i = 0; i < 4; ++i) op[i] = f2b(v[i] * inv * wp[i]);
}

// ---------------------------------------------------------------------------
// RoPE + repack: q,k [T,1024] bf16 -> [B,NH,S,64] bf16 (rotated);
//                v   [T,1024] bf16 -> vt [B,NH,64,S] bf16 (transposed).
// ---------------------------------------------------------------------------
__global__ __launch_bounds__(256) void rope_repack(
    const u16* __restrict__ q, const u16* __restrict__ k,
    const u16* __restrict__ v, const float* __restrict__ fc,
    const float* __restrict__ fs, u16* __restrict__ qr, u16* __restrict__ kr,
    u16* __restrict__ vt, int S) {
  int t = blockIdx.x;
  int b = t / S, s = t % S;
  for (int p = threadIdx.x; p < 512; p += 256) {
    int h = p >> 5, i = p & 31;
    float c = fc[s * 32 + i], sn = fs[s * 32 + i];
    size_t src = (size_t)t * 1024 + h * 64 + 2 * i;
    size_t dst = ((size_t)(b * 16 + h) * S + s) * 64 + 2 * i;
    float a0 = b2f(q[src]), a1 = b2f(q[src + 1]);
    qr[dst] = f2b(a0 * c - a1 * sn);
    qr[dst + 1] = f2b(a0 * sn + a1 * c);
    float b0 = b2f(k[src]), b1 = b2f(k[src + 1]);
    kr[dst] = f2b(b0 * c - b1 * sn);
    kr[dst + 1] = f2b(b0 * sn + b1 * c);
  }
  for (int d = threadIdx.x; d < 1024; d += 256) {
    int h = d >> 6, dd = d & 63;
    vt[((size_t)(b * 16 + h) * 64 + dd) * S + s] = v[(size_t)t * 1024 + d];
  }
}

// ---------------------------------------------------------------------------
// Flash attention (causal). Grid: (S/64, B*NH). 4 waves x 16 q-rows.
// scores = (q.k) * 1/64 (double scale in reference), online softmax in f32.
// ---------------------------------------------------------------------------
__global__ __launch_bounds__(256) void attn_fwd(
    const u16* __restrict__ qr, const u16* __restrict__ kr,
    const u16* __restrict__ vt, u16* __restrict__ ob, int S, int NHc) {
  __shared__ u16 Ks[64 * 64];
  __shared__ u16 Vs[64 * 64];       // Vt tile: [d][j]
  __shared__ u16 Ps[4][16 * 64];    // per-wave P
  const int lane = threadIdx.x & 63;
  const int wid = threadIdx.x >> 6;
  const int bh = blockIdx.y;
  const int q0 = blockIdx.x * 64;
  const int b = bh / NHc, h = bh % NHc;
  const u16* qb = qr + (size_t)bh * S * 64;
  const u16* kb = kr + (size_t)bh * S * 64;
  const u16* vb = vt + (size_t)bh * 64 * S;
  u16* Psw = &Ps[wid][0];

  bh8 qf[2];
  {
    const u16* qp = qb + (size_t)(q0 + wid * 16 + (lane & 15)) * 64 + (lane >> 4) * 8;
    qf[0] = *(const bh8*)qp;
    qf[1] = *(const bh8*)(qp + 32);
  }
  fv4 oacc[4] = {};
  float mrow[4], lrow[4];
#pragma unroll
  for (int r = 0; r < 4; ++r) { mrow[r] = -1e30f; lrow[r] = 0.f; }
  const int rr = lane >> 3;
  const int b8s = (lane & 7) ^ rr;
  const int nkt = q0 / 64 + 1;
  const int qmaxw = q0 + wid * 16 + 15;

  for (int kt = 0; kt < nkt; ++kt) {
    const int j0 = kt * 64;
    __syncthreads();
#pragma unroll
    for (int i = 0; i < 2; ++i) {
      int c = wid * 2 + i;
      int row = c * 8 + rr;
      GLD16(kb + (size_t)(j0 + row) * 64 + b8s * 8, &Ks[c * 512]);
      GLD16(vb + (size_t)row * S + j0 + b8s * 8, &Vs[c * 512]);
    }
    __syncthreads();
    if (j0 <= qmaxw) {
      fv4 sc[4] = {};
#pragma unroll
      for (int ks = 0; ks < 2; ++ks) {
        int b8 = ks * 4 + (lane >> 4);
#pragma unroll
        for (int jt = 0; jt < 4; ++jt) {
          bh8 kf = lds_frag(Ks, jt * 16 + (lane & 15), b8);
          sc[jt] = mfma16(qf[ks], kf, sc[jt]);
        }
      }
      float sfac[4];
#pragma unroll
      for (int r = 0; r < 4; ++r) {
        int qg = q0 + wid * 16 + (lane >> 4) * 4 + r;
#pragma unroll
        for (int jt = 0; jt < 4; ++jt) {
          int j = j0 + jt * 16 + (lane & 15);
          float s = sc[jt][r] * 0.015625f;
          sc[jt][r] = (j <= qg) ? s : -1e30f;
        }
        float v = fmaxf(fmaxf(sc[0][r], sc[1][r]), fmaxf(sc[2][r], sc[3][r]));
        v = fmaxf(v, __shfl_xor(v, 1));
        v = fmaxf(v, __shfl_xor(v, 2));
        v = fmaxf(v, __shfl_xor(v, 4));
        v = fmaxf(v, __shfl_xor(v, 8));
        float mnew = fmaxf(mrow[r], v);
        sfac[r] = exp2f((mrow[r] - mnew) * LOG2E);
        mrow[r] = mnew;
      }
      float rsum[4] = {0.f, 0.f, 0.f, 0.f};
#pragma unroll
      for (int jt = 0; jt < 4; ++jt) {
#pragma unroll
        for (int r = 0; r < 4; ++r) {
          float p = exp2f((sc[jt][r] - mrow[r]) * LOG2E);
          rsum[r] += p;
          int rl = (lane >> 4) * 4 + r;
          int jl = jt * 16 + (lane & 15);
          *(u16*)((char*)Psw + rl * 128 + ((jl * 2) ^ ((rl & 7) << 4))) = f2b(p);
        }
      }
#pragma unroll
      for (int r = 0; r < 4; ++r) {
        float s = rsum[r];
        s += __shfl_xor(s, 1);
        s += __shfl_xor(s, 2);
        s += __shfl_xor(s, 4);
        s += __shfl_xor(s, 8);
        lrow[r] = lrow[r] * sfac[r] + s;
        oacc[0][r] *= sfac[r];
        oacc[1][r] *= sfac[r];
        oacc[2][r] *= sfac[r];
        oacc[3][r] *= sfac[r];
      }
#pragma unroll
      for (int ks = 0; ks < 2; ++ks) {
        int b8 = ks * 4 + (lane >> 4);
        bh8 pa = lds_frag(Psw, lane & 15, b8);
#pragma unroll
        for (int dt = 0; dt < 4; ++dt) {
          bh8 vf = lds_frag(Vs, dt * 16 + (lane & 15), b8);
          oacc[dt] = mfma16(pa, vf, oacc[dt]);
        }
      }
    }
  }
#pragma unroll
  for (int dt = 0; dt < 4; ++dt)
#pragma unroll
    for (int r = 0; r < 4; ++r) {
      int row = q0 + wid * 16 + (lane >> 4) * 4 + r;
      int col = dt * 16 + (lane & 15);
      ob[((size_t)b * S + row) * 1024 + h * 64 + col] = f2b(oacc[dt][r] / lrow[r]);
    }
}

// ---------------------------------------------------------------------------
// Gate + top-2: recompute rmsnorm in f32 (avoid bf16 selection flips),
// softmax over 8 experts, write dense wmask [E][T].
// ---------------------------------------------------------------------------
__global__ __launch_bounds__(256) void gate_topk(
    const float* __restrict__ x2, const float* __restrict__ nw,
    const float* __restrict__ gw, const float* __restrict__ gb,
    float* __restrict__ wmask, int T) {
  int t = blockIdx.x * 4 + (threadIdx.x >> 6);
  int lane = threadIdx.x & 63;
  const float* xr = x2 + (size_t)t * 1024;
  float hv[16];
  float ss = 0.f;
#pragma unroll
  for (int i = 0; i < 4; ++i) {
    fv4 v = *(const fv4*)(xr + lane * 16 + i * 4);
#pragma unroll
    for (int j = 0; j < 4; ++j) {
      hv[i * 4 + j] = v[j];
      ss += v[j] * v[j];
    }
  }
#pragma unroll
  for (int off = 1; off < 64; off <<= 1) ss += __shfl_xor(ss, off);
  float inv = rsqrtf(ss * (1.0f / 1024.f) + 1e-6f);
#pragma unroll
  for (int i = 0; i < 16; ++i) hv[i] = hv[i] * inv * nw[lane * 16 + i];
  float logit[8];
#pragma unroll
  for (int e = 0; e < 8; ++e) {
    const float* wp = gw + (size_t)e * 1024 + lane * 16;
    float s = 0.f;
#pragma unroll
    for (int i = 0; i < 16; ++i) s += hv[i] * wp[i];
#pragma unroll
    for (int off = 1; off < 64; off <<= 1) s += __shfl_xor(s, off);
    logit[e] = s + gb[e];
  }
  float mx = logit[0];
#pragma unroll
  for (int e = 1; e < 8; ++e) mx = fmaxf(mx, logit[e]);
  float pe[8], se = 0.f;
#pragma unroll
  for (int e = 0; e < 8; ++e) { pe[e] = __expf(logit[e] - mx); se += pe[e]; }
  float rs = 1.f / se;
#pragma unroll
  for (int e = 0; e < 8; ++e) pe[e] *= rs;
  int i0 = 0;
  float b0 = pe[0];
#pragma unroll
  for (int e = 1; e < 8; ++e) if (pe[e] > b0) { b0 = pe[e]; i0 = e; }
  int i1 = -1;
  float b1v = -1.f;
#pragma unroll
  for (int e = 0; e < 8; ++e) if (e != i0 && pe[e] > b1v) { b1v = pe[e]; i1 = e; }
  if (lane < 8)
    wmask[(size_t)lane * T + t] = (lane == i0) ? b0 : (lane == i1) ? b1v : 0.f;
}

// ---------------------------------------------------------------------------
// silu(a + ba) * (b + bb) -> bf16. 8 elems/thread. biases may be null.
// ---------------------------------------------------------------------------
__global__ __launch_bounds__(256) void silu_mul(
    const u16* __restrict__ a, const u16* __restrict__ b,
    const float* __restrict__ ba, const float* __restrict__ bb,
    u16* __restrict__ out, int H) {
  size_t i = ((size_t)blockIdx.x * 256 + threadIdx.x) * 8;
  bh8 av = *(const bh8*)(a + i);
  bh8 bv = *(const bh8*)(b + i);
  int col = (int)(i % (size_t)H);
  bh8 ov;
#pragma unroll
  for (int j = 0; j < 8; ++j) {
    float x = b2f((u16)av[j]) + (ba ? ba[col + j] : 0.f);
    float y = b2f((u16)bv[j]) + (bb ? bb[col + j] : 0.f);
    float s = x / (1.f + __expf(-x));
    ov[j] = (short)f2b(s * y);
  }
  *(bh8*)(out + i) = ov;
}

__global__ __launch_bounds__(256) void f2b_convert(
    const float* __restrict__ src, u16* __restrict__ dst) {
  size_t i = ((size_t)blockIdx.x * 256 + threadIdx.x) * 8;
  fv4 a = *(const fv4*)(src + i);
  fv4 b = *(const fv4*)(src + i + 4);
  bh8 o;
#pragma unroll
  for (int j = 0; j < 4; ++j) o[j] = (short)f2b(a[j]);
#pragma unroll
  for (int j = 0; j < 4; ++j) o[4 + j] = (short)f2b(b[j]);
  *(bh8*)(dst + i) = o;
}

// ---------------------------------------------------------------------------
extern "C" void kernel_launch(void* const* d_in, const int* in_sizes, int n_in,
                              void* d_out, int out_size, void* d_ws,
                              size_t ws_size, hipStream_t stream) {
  (void)in_sizes; (void)n_in; (void)out_size; (void)ws_size;
  const int Sc = 2048, Dc = 1024, NHc = 16, Tc = 4096, MH = 1024, SH = 2048;

  const float* x   = (const float*)d_in[0];
  const float* fc  = (const float*)d_in[1];
  const float* fs  = (const float*)d_in[2];
  const float* wq  = (const float*)d_in[4];
  const float* wk  = (const float*)d_in[5];
  const float* wv  = (const float*)d_in[6];
  const float* wo  = (const float*)d_in[7];
  const float* anw = (const float*)d_in[8];
  const float* fnw = (const float*)d_in[9];
  const float* gw  = (const float*)d_in[10];
  const float* gb  = (const float*)d_in[11];
  const float* w1  = (const float*)d_in[12];
  const float* b1  = (const float*)d_in[13];
  const float* w2  = (const float*)d_in[14];
  const float* b2  = (const float*)d_in[15];
  const float* w3  = (const float*)d_in[16];
  const float* b3  = (const float*)d_in[17];
  const float* sgw = (const float*)d_in[18];
  const float* suw = (const float*)d_in[19];
  const float* sdw = (const float*)d_in[20];
  float* out = (float*)d_out;

  char* base = (char*)d_ws;
  size_t off = 0;
  auto alloc = [&](size_t bytes) -> void* {
    void* p = base + off;
    off += (bytes + 255) & ~(size_t)255;
    return p;
  };
  // bf16 weights
  u16* wq_b = (u16*)alloc(2ull * Dc * Dc);
  u16* wk_b = (u16*)alloc(2ull * Dc * Dc);
  u16* wv_b = (u16*)alloc(2ull * Dc * Dc);
  u16* wo_b = (u16*)alloc(2ull * Dc * Dc);
  u16* sgw_b = (u16*)alloc(2ull * SH * Dc);
  u16* suw_b = (u16*)alloc(2ull * SH * Dc);
  u16* sdw_b = (u16*)alloc(2ull * Dc * SH);
  u16* w1_b = (u16*)alloc(2ull * 8 * MH * Dc);
  u16* w2_b = (u16*)alloc(2ull * 8 * Dc * MH);
  u16* w3_b = (u16*)alloc(2ull * 8 * MH * Dc);
  // activations (q_b..h_b and qr..o_b are contiguous for aliasing)
  u16* q_b = (u16*)alloc(2ull * Tc * Dc);
  u16* k_b = (u16*)alloc(2ull * Tc * Dc);
  u16* v_b = (u16*)alloc(2ull * Tc * Dc);
  u16* h_b = (u16*)alloc(2ull * Tc * Dc);
  u16* qr = (u16*)alloc(2ull * Tc * Dc);
  u16* kr = (u16*)alloc(2ull * Tc * Dc);
  u16* vt_ = (u16*)alloc(2ull * Tc * Dc);
  u16* o_b = (u16*)alloc(2ull * Tc * Dc);
  float* x2 = (float*)alloc(4ull * Tc * Dc);
  u16* hf_b = (u16*)alloc(2ull * Tc * Dc);
  float* wmask = (float*)alloc(4ull * 8 * Tc);
  u16* he_b = (u16*)alloc(2ull * Tc * MH);
  float* accf = (float*)alloc(4ull * Tc * Dc);
  // aliases (lifetimes disjoint)
  u16* sgact = q_b;   // spans q_b+k_b (16MB)
  u16* suact = v_b;   // spans v_b+h_b
  u16* hs_b = qr;     // spans qr+kr
  u16* a1_b = vt_;
  u16* a3_b = o_b;

  auto conv = [&](const float* s, u16* d, size_t n) {
    f2b_convert<<<dim3((unsigned)(n / 2048)), 256, 0, stream>>>(s, d);
  };
  conv(wq, wq_b, (size_t)Dc * Dc);
  conv(wk, wk_b, (size_t)Dc * Dc);
  conv(wv, wv_b, (size_t)Dc * Dc);
  conv(wo, wo_b, (size_t)Dc * Dc);
  conv(sgw, sgw_b, (size_t)SH * Dc);
  conv(suw, suw_b, (size_t)SH * Dc);
  conv(sdw, sdw_b, (size_t)Dc * SH);
  conv(w1, w1_b, (size_t)8 * MH * Dc);
  conv(w2, w2_b, (size_t)8 * Dc * MH);
  conv(w3, w3_b, (size_t)8 * MH * Dc);

  // attn branch
  rmsnorm_bf16<<<Tc, 256, 0, stream>>>(x, anw, h_b);
  gemm_bt<0><<<dim3(Dc / 128, Tc / 128), 256, 0, stream>>>(
      h_b, wq_b, Tc, Dc, Dc, q_b, nullptr, nullptr, nullptr, nullptr, nullptr);
  gemm_bt<0><<<dim3(Dc / 128, Tc / 128), 256, 0, stream>>>(
      h_b, wk_b, Tc, Dc, Dc, k_b, nullptr, nullptr, nullptr, nullptr, nullptr);
  gemm_bt<0><<<dim3(Dc / 128, Tc / 128), 256, 0, stream>>>(
      h_b, wv_b, Tc, Dc, Dc, v_b, nullptr, nullptr, nullptr, nullptr, nullptr);
  rope_repack<<<Tc, 256, 0, stream>>>(q_b, k_b, v_b, fc, fs, qr, kr, vt_, Sc);
  attn_fwd<<<dim3(Sc / 64, 2 * NHc), 256, 0, stream>>>(qr, kr, vt_, o_b, Sc, NHc);
  gemm_bt<1><<<dim3(Dc / 128, Tc / 128), 256, 0, stream>>>(
      o_b, wo_b, Tc, Dc, Dc, nullptr, x2, x, nullptr, nullptr, nullptr);

  // ffn branch
  rmsnorm_bf16<<<Tc, 256, 0, stream>>>(x2, fnw, hf_b);
  gate_topk<<<Tc / 4, 256, 0, stream>>>(x2, fnw, gw, gb, wmask, Tc);

  gemm_bt<0><<<dim3(SH / 128, Tc / 128), 256, 0, stream>>>(
      hf_b, sgw_b, Tc, SH, Dc, sgact, nullptr, nullptr, nullptr, nullptr, nullptr);
  gemm_bt<0><<<dim3(SH / 128, Tc / 128), 256, 0, stream>>>(
      hf_b, suw_b, Tc, SH, Dc, suact, nullptr, nullptr, nullptr, nullptr, nullptr);
  silu_mul<<<dim3((unsigned)(((size_t)Tc * SH) / 2048)), 256, 0, stream>>>(
      sgact, suact, nullptr, nullptr, hs_b, SH);

  for (int e = 0; e < 8; ++e) {
    gemm_bt<0><<<dim3(MH / 128, Tc / 128), 256, 0, stream>>>(
        hf_b, w1_b + (size_t)e * MH * Dc, Tc, MH, Dc, a1_b, nullptr, nullptr,
        nullptr, nullptr, nullptr);
    gemm_bt<0><<<dim3(MH / 128, Tc / 128), 256, 0, stream>>>(
        hf_b, w3_b + (size_t)e * MH * Dc, Tc, MH, Dc, a3_b, nullptr, nullptr,
        nullptr, nullptr, nullptr);
    silu_mul<<<dim3((unsigned)(((size_t)Tc * MH) / 2048)), 256, 0, stream>>>(
        a1_b, a3_b, b1 + (size_t)e * MH, b3 + (size_t)e * MH, he_b, MH);
    if (e == 0)
      gemm_bt<2><<<dim3(Dc / 128, Tc / 128), 256, 0, stream>>>(
          he_b, w2_b + (size_t)e * Dc * MH, Tc, Dc, MH, nullptr, accf, nullptr,
          nullptr, wmask + (size_t)e * Tc, b2 + (size_t)e * Dc);
    else
      gemm_bt<3><<<dim3(Dc / 128, Tc / 128), 256, 0, stream>>>(
          he_b, w2_b + (size_t)e * Dc * MH, Tc, Dc, MH, nullptr, accf, nullptr,
          nullptr, wmask + (size_t)e * Tc, b2 + (size_t)e * Dc);
  }

  // final: out = x2 + acc + shared_down
  gemm_bt<4><<<dim3(Dc / 128, Tc / 128), 256, 0, stream>>>(
      hs_b, sdw_b, Tc, Dc, SH, nullptr, out, x2, accf, nullptr, nullptr);
}

// Round 2
// 662.494 us; speedup vs baseline: 1.8897x; 1.8897x over previous
//
#include <hip/hip_runtime.h>

// ---------------------------------------------------------------------------
// TransformerBlock on MI355X (gfx950), round 1:
//  - sparse top-2 MoE via grouped gather-GEMM (replaces dense 8-expert loop)
//  - double-buffered flash attention (1 barrier / K-tile)
// GEMM: 128x128 tile, BK=64, 4 waves, mfma_f32_16x16x32_bf16,
//       global_load_lds(16B) staging with pre-swizzled source.
// ---------------------------------------------------------------------------

typedef unsigned short u16;
typedef __attribute__((ext_vector_type(8))) short bh8;   // 8 x bf16 (4 VGPRs)
typedef __attribute__((ext_vector_type(4))) float fv4;

#define LOG2E 1.4426950408889634f
#define MAX_TILES 72

__device__ __forceinline__ float b2f(u16 u) {
  return __builtin_bit_cast(float, ((unsigned)u) << 16);
}
__device__ __forceinline__ u16 f2b(float f) {
  unsigned x = __builtin_bit_cast(unsigned, f);
  return (u16)((x + 0x7fffu + ((x >> 16) & 1u)) >> 16);  // RNE
}
__device__ __forceinline__ fv4 mfma16(bh8 a, bh8 b, fv4 c) {
  return __builtin_amdgcn_mfma_f32_16x16x32_bf16(a, b, c, 0, 0, 0);
}

#define GLD16(g, l)                                                        \
  __builtin_amdgcn_global_load_lds(                                        \
      (const __attribute__((address_space(1))) void*)(g),                  \
      (__attribute__((address_space(3))) void*)(l), 16, 0, 0)

// Read one MFMA fragment (16B) from a [rows][64] bf16 LDS tile whose rows are
// 128B and whose 16B blocks are XOR-swizzled by (row&7).
__device__ __forceinline__ bh8 lds_frag(const u16* base, int row, int b8) {
  int off = row * 128 + ((b8 * 16) ^ ((row & 7) << 4));
  return *(const bh8*)((const char*)base + off);
}

// ---------------------------------------------------------------------------
// Generic GEMM: C[M,N] = A[M,K] (bf16) @ B[N,K]^T (bf16), f32 accumulate.
// MODE 0: Cb = bf16(gemm)
// MODE 1: Cf = add1 + gemm
// MODE 4: Cf = add1 + add2 + gemm                 (final output)
// MODE 5: gather-A grouped MoE: A rows via expert token list, B per-expert.
//         Cb compact = bf16(gemm)
// MODE 6: compact-A grouped MoE (w2): B per-expert, Cb = bf16(gemm + bias_e)
// ---------------------------------------------------------------------------
template <int MODE>
__global__ __launch_bounds__(256) void gemm_bt(
    const u16* __restrict__ A, const u16* __restrict__ B, int M, int N, int K,
    u16* __restrict__ Cb, float* __restrict__ Cf,
    const float* __restrict__ add1, const float* __restrict__ add2,
    const float* __restrict__ bias, const int* __restrict__ tmeta,
    const int* __restrict__ etok) {
  __shared__ u16 As[128 * 64];
  __shared__ u16 Bs[128 * 64];
  const int lane = threadIdx.x & 63;
  const int wid = threadIdx.x >> 6;
  const int wr = wid >> 1, wc = wid & 1;
  const int n0 = blockIdx.x * 128;
  const int rr = lane >> 3;              // row-within-chunk 0..7
  const int b8s = (lane & 7) ^ rr;       // pre-swizzled source block

  int m0 = 0, e = 0, m0l = 0, cnt = 0, row0 = 0;
  const u16* Bp = B;
  if constexpr (MODE == 5 || MODE == 6) {
    int tile = blockIdx.y;
    if (tile >= tmeta[0]) return;
    e = tmeta[16 + tile * 4];
    m0l = tmeta[17 + tile * 4];
    cnt = tmeta[18 + tile * 4];
    row0 = tmeta[19 + tile * 4];
    Bp = B + (size_t)e * N * K;
  } else {
    m0 = blockIdx.y * 128;
  }

  const u16* Arow[4];
  const u16* Brow[4];
#pragma unroll
  for (int i = 0; i < 4; ++i) {
    int c = wid * 4 + i;
    int row = c * 8 + rr;
    if constexpr (MODE == 5) {
      int li = m0l + row;
      li = li < cnt ? li : cnt - 1;
      int tok = etok[e * 4096 + li];
      Arow[i] = A + (size_t)tok * K + b8s * 8;
    } else if constexpr (MODE == 6) {
      Arow[i] = A + (size_t)(row0 + row) * K + b8s * 8;
    } else {
      Arow[i] = A + (size_t)(m0 + row) * K + b8s * 8;
    }
    Brow[i] = Bp + (size_t)(n0 + row) * K + b8s * 8;
  }

  fv4 acc[4][4] = {};
  for (int k0 = 0; k0 < K; k0 += 64) {
    __syncthreads();
#pragma unroll
    for (int i = 0; i < 4; ++i) {
      int c = wid * 4 + i;
      GLD16(Arow[i] + k0, &As[c * 512]);
      GLD16(Brow[i] + k0, &Bs[c * 512]);
    }
    __syncthreads();
#pragma unroll
    for (int ks = 0; ks < 2; ++ks) {
      int b8 = ks * 4 + (lane >> 4);
      bh8 af[4], bf[4];
#pragma unroll
      for (int mi = 0; mi < 4; ++mi)
        af[mi] = lds_frag(As, wr * 64 + mi * 16 + (lane & 15), b8);
#pragma unroll
      for (int ni = 0; ni < 4; ++ni)
        bf[ni] = lds_frag(Bs, wc * 64 + ni * 16 + (lane & 15), b8);
#pragma unroll
      for (int mi = 0; mi < 4; ++mi)
#pragma unroll
        for (int ni = 0; ni < 4; ++ni)
          acc[mi][ni] = mfma16(af[mi], bf[ni], acc[mi][ni]);
    }
  }

  const int rbase = (MODE == 5 || MODE == 6) ? row0 : m0;
  const int r0b = rbase + wr * 64 + (lane >> 4) * 4;
  const int c0b = n0 + wc * 64 + (lane & 15);
  const float* bb = nullptr;
  if constexpr (MODE == 6) bb = bias + (size_t)e * N;
#pragma unroll
  for (int mi = 0; mi < 4; ++mi) {
#pragma unroll
    for (int ni = 0; ni < 4; ++ni) {
      int c = c0b + ni * 16;
#pragma unroll
      for (int r = 0; r < 4; ++r) {
        int row = r0b + mi * 16 + r;
        size_t idx = (size_t)row * N + c;
        float v = acc[mi][ni][r];
        if constexpr (MODE == 0) Cb[idx] = f2b(v);
        else if constexpr (MODE == 1) Cf[idx] = add1[idx] + v;
        else if constexpr (MODE == 4) Cf[idx] = add1[idx] + add2[idx] + v;
        else if constexpr (MODE == 5) Cb[idx] = f2b(v);
        else Cb[idx] = f2b(v + bb[c]);
      }
    }
  }
}

// ---------------------------------------------------------------------------
// RMSNorm: f32 [T,1024] -> bf16 [T,1024], one block per token.
// ---------------------------------------------------------------------------
__global__ __launch_bounds__(256) void rmsnorm_bf16(
    const float* __restrict__ x, const float* __restrict__ w,
    u16* __restrict__ out) {
  int t = blockIdx.x;
  const float* xr = x + (size_t)t * 1024;
  fv4 v = *(const fv4*)(xr + threadIdx.x * 4);
  float ss = v[0] * v[0] + v[1] * v[1] + v[2] * v[2] + v[3] * v[3];
#pragma unroll
  for (int off = 1; off < 64; off <<= 1) ss += __shfl_xor(ss, off);
  __shared__ float red[4];
  int lane = threadIdx.x & 63, wid = threadIdx.x >> 6;
  if (lane == 0) red[wid] = ss;
  __syncthreads();
  float inv = rsqrtf((red[0] + red[1] + red[2] + red[3]) * (1.0f / 1024.f) + 1e-6f);
  u16* op = out + (size_t)t * 1024 + threadIdx.x * 4;
  const float* wp = w + threadIdx.x * 4;
#pragma unroll
  for (int i = 0; i < 4; ++i) op[i] = f2b(v[i] * inv * wp[i]);
}

// ---------------------------------------------------------------------------
// RoPE + repack: q,k [T,1024] bf16 -> [B,NH,S,64] bf16 (rotated);
//                v   [T,1024] bf16 -> vt [B,NH,64,S] bf16 (transposed).
// ---------------------------------------------------------------------------
__global__ __launch_bounds__(256) void rope_repack(
    const u16* __restrict__ q, const u16* __restrict__ k,
    const u16* __restrict__ v, const float* __restrict__ fc,
    const float* __restrict__ fs, u16* __restrict__ qr, u16* __restrict__ kr,
    u16* __restrict__ vt, int S) {
  int t = blockIdx.x;
  int b = t / S, s = t % S;
  for (int p = threadIdx.x; p < 512; p += 256) {
    int h = p >> 5, i = p & 31;
    float c = fc[s * 32 + i], sn = fs[s * 32 + i];
    size_t src = (size_t)t * 1024 + h * 64 + 2 * i;
    size_t dst = ((size_t)(b * 16 + h) * S + s) * 64 + 2 * i;
    float a0 = b2f(q[src]), a1 = b2f(q[src + 1]);
    qr[dst] = f2b(a0 * c - a1 * sn);
    qr[dst + 1] = f2b(a0 * sn + a1 * c);
    float b0 = b2f(k[src]), b1 = b2f(k[src + 1]);
    kr[dst] = f2b(b0 * c - b1 * sn);
    kr[dst + 1] = f2b(b0 * sn + b1 * c);
  }
  for (int d = threadIdx.x; d < 1024; d += 256) {
    int h = d >> 6, dd = d & 63;
    vt[((size_t)(b * 16 + h) * 64 + dd) * S + s] = v[(size_t)t * 1024 + d];
  }
}

// ---------------------------------------------------------------------------
// Flash attention (causal), double-buffered staging, softmax in log2 domain.
// Grid: (S/64, B*NH). 4 waves x 16 q-rows.
// ---------------------------------------------------------------------------
__global__ __launch_bounds__(256) void attn_fwd(
    const u16* __restrict__ qr, const u16* __restrict__ kr,
    const u16* __restrict__ vt, u16* __restrict__ ob, int S, int NHc) {
  __shared__ u16 Ks[2][64 * 64];
  __shared__ u16 Vs[2][64 * 64];   // Vt tile: [d][j]
  __shared__ u16 Ps[4][16 * 64];   // per-wave P
  const int lane = threadIdx.x & 63;
  const int wid = threadIdx.x >> 6;
  const int bh = blockIdx.y;
  const int q0 = blockIdx.x * 64;
  const int b = bh / NHc, h = bh % NHc;
  const u16* qb = qr + (size_t)bh * S * 64;
  const u16* kb = kr + (size_t)bh * S * 64;
  const u16* vb = vt + (size_t)bh * 64 * S;
  u16* Psw = &Ps[wid][0];
  const float SC = 0.015625f * LOG2E;  // both ref scales, log2 domain

  bh8 qf[2];
  {
    const u16* qp =
        qb + (size_t)(q0 + wid * 16 + (lane & 15)) * 64 + (lane >> 4) * 8;
    qf[0] = *(const bh8*)qp;
    qf[1] = *(const bh8*)(qp + 32);
  }
  fv4 oacc[4] = {};
  float mrow[4], lrow[4];
#pragma unroll
  for (int r = 0; r < 4; ++r) { mrow[r] = -1e30f; lrow[r] = 0.f; }
  const int rr = lane >> 3;
  const int b8s = (lane & 7) ^ rr;
  const int nkt = q0 / 64 + 1;

  auto stage = [&](int buf, int j0) {
#pragma unroll
    for (int i = 0; i < 2; ++i) {
      int c = wid * 2 + i;
      int row = c * 8 + rr;
      GLD16(kb + (size_t)(j0 + row) * 64 + b8s * 8, &Ks[buf][c * 512]);
      GLD16(vb + (size_t)row * S + j0 + b8s * 8, &Vs[buf][c * 512]);
    }
  };
  stage(0, 0);

  for (int kt = 0; kt < nkt; ++kt) {
    const int j0 = kt * 64;
    __syncthreads();  // drains vmcnt: buf[kt&1] staged; joins all waves
    if (kt + 1 < nkt) stage((kt + 1) & 1, (kt + 1) * 64);
    const u16* Kc = Ks[kt & 1];
    const u16* Vc = Vs[kt & 1];

    fv4 sc[4] = {};
#pragma unroll
    for (int ks = 0; ks < 2; ++ks) {
      int b8 = ks * 4 + (lane >> 4);
#pragma unroll
      for (int jt = 0; jt < 4; ++jt) {
        bh8 kf = lds_frag(Kc, jt * 16 + (lane & 15), b8);
        sc[jt] = mfma16(qf[ks], kf, sc[jt]);
      }
    }
    float sfac[4];
#pragma unroll
    for (int r = 0; r < 4; ++r) {
      int qg = q0 + wid * 16 + (lane >> 4) * 4 + r;
#pragma unroll
      for (int jt = 0; jt < 4; ++jt) {
        int j = j0 + jt * 16 + (lane & 15);
        float s = sc[jt][r] * SC;
        sc[jt][r] = (j <= qg) ? s : -1e30f;
      }
      float v = fmaxf(fmaxf(sc[0][r], sc[1][r]), fmaxf(sc[2][r], sc[3][r]));
      v = fmaxf(v, __shfl_xor(v, 1));
      v = fmaxf(v, __shfl_xor(v, 2));
      v = fmaxf(v, __shfl_xor(v, 4));
      v = fmaxf(v, __shfl_xor(v, 8));
      float mnew = fmaxf(mrow[r], v);
      sfac[r] = exp2f(mrow[r] - mnew);
      mrow[r] = mnew;
    }
    float rsum[4] = {0.f, 0.f, 0.f, 0.f};
#pragma unroll
    for (int jt = 0; jt < 4; ++jt) {
#pragma unroll
      for (int r = 0; r < 4; ++r) {
        float p = exp2f(sc[jt][r] - mrow[r]);
        rsum[r] += p;
        int rl = (lane >> 4) * 4 + r;
        int jl = jt * 16 + (lane & 15);
        *(u16*)((char*)Psw + rl * 128 + ((jl * 2) ^ ((rl & 7) << 4))) = f2b(p);
      }
    }
#pragma unroll
    for (int r = 0; r < 4; ++r) {
      float s = rsum[r];
      s += __shfl_xor(s, 1);
      s += __shfl_xor(s, 2);
      s += __shfl_xor(s, 4);
      s += __shfl_xor(s, 8);
      lrow[r] = lrow[r] * sfac[r] + s;
      oacc[0][r] *= sfac[r];
      oacc[1][r] *= sfac[r];
      oacc[2][r] *= sfac[r];
      oacc[3][r] *= sfac[r];
    }
#pragma unroll
    for (int ks = 0; ks < 2; ++ks) {
      int b8 = ks * 4 + (lane >> 4);
      bh8 pa = lds_frag(Psw, lane & 15, b8);
#pragma unroll
      for (int dt = 0; dt < 4; ++dt) {
        bh8 vf = lds_frag(Vc, dt * 16 + (lane & 15), b8);
        oacc[dt] = mfma16(pa, vf, oacc[dt]);
      }
    }
  }
#pragma unroll
  for (int dt = 0; dt < 4; ++dt)
#pragma unroll
    for (int r = 0; r < 4; ++r) {
      int row = q0 + wid * 16 + (lane >> 4) * 4 + r;
      int col = dt * 16 + (lane & 15);
      ob[((size_t)b * S + row) * 1024 + h * 64 + col] =
          f2b(oacc[dt][r] / lrow[r]);
    }
}

// ---------------------------------------------------------------------------
// MoE routing kernels
// ---------------------------------------------------------------------------
__global__ void zero_counts(int* counts) {
  if (threadIdx.x < 8) counts[threadIdx.x] = 0;
}

// Gate + top-2: recompute rmsnorm in f32, softmax over 8 experts, scatter
// token into its two experts' lists.
__global__ __launch_bounds__(256) void gate_topk(
    const float* __restrict__ x2, const float* __restrict__ nw,
    const float* __restrict__ gw, const float* __restrict__ gb,
    int* __restrict__ counts, int* __restrict__ topk_e,
    float* __restrict__ topk_w, int* __restrict__ pos_of,
    int* __restrict__ etok) {
  int t = blockIdx.x * 4 + (threadIdx.x >> 6);
  int lane = threadIdx.x & 63;
  const float* xr = x2 + (size_t)t * 1024;
  float hv[16];
  float ss = 0.f;
#pragma unroll
  for (int i = 0; i < 4; ++i) {
    fv4 v = *(const fv4*)(xr + lane * 16 + i * 4);
#pragma unroll
    for (int j = 0; j < 4; ++j) {
      hv[i * 4 + j] = v[j];
      ss += v[j] * v[j];
    }
  }
#pragma unroll
  for (int off = 1; off < 64; off <<= 1) ss += __shfl_xor(ss, off);
  float inv = rsqrtf(ss * (1.0f / 1024.f) + 1e-6f);
#pragma unroll
  for (int i = 0; i < 16; ++i) hv[i] = hv[i] * inv * nw[lane * 16 + i];
  float logit[8];
#pragma unroll
  for (int e = 0; e < 8; ++e) {
    const float* wp = gw + (size_t)e * 1024 + lane * 16;
    float s = 0.f;
#pragma unroll
    for (int i = 0; i < 16; ++i) s += hv[i] * wp[i];
#pragma unroll
    for (int off = 1; off < 64; off <<= 1) s += __shfl_xor(s, off);
    logit[e] = s + gb[e];
  }
  if (lane == 0) {
    float mx = logit[0];
#pragma unroll
    for (int e = 1; e < 8; ++e) mx = fmaxf(mx, logit[e]);
    float pe[8], se = 0.f;
#pragma unroll
    for (int e = 0; e < 8; ++e) { pe[e] = __expf(logit[e] - mx); se += pe[e]; }
    float rs = 1.f / se;
#pragma unroll
    for (int e = 0; e < 8; ++e) pe[e] *= rs;
    int i0 = 0;
    float b0 = pe[0];
#pragma unroll
    for (int e = 1; e < 8; ++e)
      if (pe[e] > b0) { b0 = pe[e]; i0 = e; }
    int i1 = -1;
    float b1v = -1.f;
#pragma unroll
    for (int e = 0; e < 8; ++e)
      if (e != i0 && pe[e] > b1v) { b1v = pe[e]; i1 = e; }
    topk_e[2 * t] = i0;
    topk_e[2 * t + 1] = i1;
    topk_w[2 * t] = b0;
    topk_w[2 * t + 1] = b1v;
    int p0 = atomicAdd(&counts[i0], 1);
    etok[i0 * 4096 + p0] = t;
    pos_of[2 * t] = p0;
    int p1 = atomicAdd(&counts[i1], 1);
    etok[i1 * 4096 + p1] = t;
    pos_of[2 * t + 1] = p1;
  }
}

// Build padded tile maps: meta[0]=ntiles, meta[1..8]=pad_base[e],
// meta[16+i*4..] = {expert, local_m0, count, global_row0}; fill rexp[row]=e.
__global__ __launch_bounds__(256) void sched_moe(const int* __restrict__ counts,
                                                 int* __restrict__ meta,
                                                 int* __restrict__ rexp) {
  __shared__ int s_e[MAX_TILES], s_row0[MAX_TILES], s_tt, s_rb;
  if (threadIdx.x == 0) {
    int tt = 0, rb = 0;
    for (int e = 0; e < 8; ++e) {
      meta[1 + e] = rb;
      int c = counts[e];
      int nt = (c + 127) >> 7;
      for (int i = 0; i < nt; ++i) {
        meta[16 + tt * 4] = e;
        meta[17 + tt * 4] = i * 128;
        meta[18 + tt * 4] = c;
        meta[19 + tt * 4] = rb + i * 128;
        s_e[tt] = e;
        s_row0[tt] = rb + i * 128;
        ++tt;
      }
      rb += nt * 128;
    }
    meta[0] = tt;
    s_tt = tt;
    s_rb = rb;
  }
  __syncthreads();
  int tt = s_tt;
  for (int tile = 0; tile < tt; ++tile) {
    int r0 = s_row0[tile], e = s_e[tile];
    for (int j = threadIdx.x; j < 128; j += 256) rexp[r0 + j] = e;
  }
  for (int r = s_rb + threadIdx.x; r < MAX_TILES * 128; r += 256) rexp[r] = 0;
}

// silu(a + b1[e]) * (b + b3[e]) over compact MoE rows.
__global__ __launch_bounds__(256) void silu_moe(
    const u16* __restrict__ a, const u16* __restrict__ b,
    const float* __restrict__ b1, const float* __restrict__ b3,
    const int* __restrict__ rexp, u16* __restrict__ out) {
  size_t i = ((size_t)blockIdx.x * 256 + threadIdx.x) * 8;
  int row = (int)(i >> 10), col = (int)(i & 1023);
  int e = rexp[row];
  const float* ba = b1 + (size_t)e * 1024 + col;
  const float* bb = b3 + (size_t)e * 1024 + col;
  bh8 av = *(const bh8*)(a + i);
  bh8 bv = *(const bh8*)(b + i);
  bh8 ov;
#pragma unroll
  for (int j = 0; j < 8; ++j) {
    float x = b2f((u16)av[j]) + ba[j];
    float y = b2f((u16)bv[j]) + bb[j];
    float s = x / (1.f + __expf(-x));
    ov[j] = (short)f2b(s * y);
  }
  *(bh8*)(out + i) = ov;
}

// router[t] = w0*eo[row(t,0)] + w1*eo[row(t,1)]
__global__ __launch_bounds__(128) void combine_router(
    const u16* __restrict__ eo, const int* __restrict__ topk_e,
    const float* __restrict__ topk_w, const int* __restrict__ pos_of,
    const int* __restrict__ meta, float* __restrict__ router) {
  int t = blockIdx.x;
  int c = threadIdx.x * 8;
  int e0 = topk_e[2 * t], e1 = topk_e[2 * t + 1];
  float w0 = topk_w[2 * t], w1 = topk_w[2 * t + 1];
  int r0 = meta[1 + e0] + pos_of[2 * t];
  int r1 = meta[1 + e1] + pos_of[2 * t + 1];
  bh8 v0 = *(const bh8*)(eo + (size_t)r0 * 1024 + c);
  bh8 v1 = *(const bh8*)(eo + (size_t)r1 * 1024 + c);
  float* rp = router + (size_t)t * 1024 + c;
#pragma unroll
  for (int j = 0; j < 8; ++j)
    rp[j] = w0 * b2f((u16)v0[j]) + w1 * b2f((u16)v1[j]);
}

// ---------------------------------------------------------------------------
// silu(a) * b -> bf16 (shared expert). 8 elems/thread.
// ---------------------------------------------------------------------------
__global__ __launch_bounds__(256) void silu_mul(const u16* __restrict__ a,
                                                const u16* __restrict__ b,
                                                u16* __restrict__ out) {
  size_t i = ((size_t)blockIdx.x * 256 + threadIdx.x) * 8;
  bh8 av = *(const bh8*)(a + i);
  bh8 bv = *(const bh8*)(b + i);
  bh8 ov;
#pragma unroll
  for (int j = 0; j < 8; ++j) {
    float x = b2f((u16)av[j]);
    float y = b2f((u16)bv[j]);
    float s = x / (1.f + __expf(-x));
    ov[j] = (short)f2b(s * y);
  }
  *(bh8*)(out + i) = ov;
}

__global__ __launch_bounds__(256) void f2b_convert(
    const float* __restrict__ src, u16* __restrict__ dst) {
  size_t i = ((size_t)blockIdx.x * 256 + threadIdx.x) * 8;
  fv4 a = *(const fv4*)(src + i);
  fv4 b = *(const fv4*)(src + i + 4);
  bh8 o;
#pragma unroll
  for (int j = 0; j < 4; ++j) o[j] = (short)f2b(a[j]);
#pragma unroll
  for (int j = 0; j < 4; ++j) o[4 + j] = (short)f2b(b[j]);
  *(bh8*)(dst + i) = o;
}

// ---------------------------------------------------------------------------
extern "C" void kernel_launch(void* const* d_in, const int* in_sizes, int n_in,
                              void* d_out, int out_size, void* d_ws,
                              size_t ws_size, hipStream_t stream) {
  (void)in_sizes; (void)n_in; (void)out_size; (void)ws_size;
  const int Sc = 2048, Dc = 1024, NHc = 16, Tc = 4096, MH = 1024, SH = 2048;

  const float* x   = (const float*)d_in[0];
  const float* fc  = (const float*)d_in[1];
  const float* fs  = (const float*)d_in[2];
  const float* wq  = (const float*)d_in[4];
  const float* wk  = (const float*)d_in[5];
  const float* wv  = (const float*)d_in[6];
  const float* wo  = (const float*)d_in[7];
  const float* anw = (const float*)d_in[8];
  const float* fnw = (const float*)d_in[9];
  const float* gw  = (const float*)d_in[10];
  const float* gb  = (const float*)d_in[11];
  const float* w1  = (const float*)d_in[12];
  const float* b1  = (const float*)d_in[13];
  const float* w2  = (const float*)d_in[14];
  const float* b2  = (const float*)d_in[15];
  const float* w3  = (const float*)d_in[16];
  const float* b3  = (const float*)d_in[17];
  const float* sgw = (const float*)d_in[18];
  const float* suw = (const float*)d_in[19];
  const float* sdw = (const float*)d_in[20];
  float* out = (float*)d_out;

  char* base = (char*)d_ws;
  size_t off = 0;
  auto alloc = [&](size_t bytes) -> void* {
    void* p = base + off;
    off += (bytes + 255) & ~(size_t)255;
    return p;
  };
  // bf16 weights
  u16* wq_b = (u16*)alloc(2ull * Dc * Dc);
  u16* wk_b = (u16*)alloc(2ull * Dc * Dc);
  u16* wv_b = (u16*)alloc(2ull * Dc * Dc);
  u16* wo_b = (u16*)alloc(2ull * Dc * Dc);
  u16* sgw_b = (u16*)alloc(2ull * SH * Dc);
  u16* suw_b = (u16*)alloc(2ull * SH * Dc);
  u16* sdw_b = (u16*)alloc(2ull * Dc * SH);
  u16* w1_b = (u16*)alloc(2ull * 8 * MH * Dc);
  u16* w2_b = (u16*)alloc(2ull * 8 * Dc * MH);
  u16* w3_b = (u16*)alloc(2ull * 8 * MH * Dc);
  // activations (contiguous 8MB regions; later aliased)
  u16* q_b = (u16*)alloc(2ull * Tc * Dc);
  u16* k_b = (u16*)alloc(2ull * Tc * Dc);
  u16* v_b = (u16*)alloc(2ull * Tc * Dc);
  u16* h_b = (u16*)alloc(2ull * Tc * Dc);
  u16* qr = (u16*)alloc(2ull * Tc * Dc);
  u16* kr = (u16*)alloc(2ull * Tc * Dc);
  u16* vt_ = (u16*)alloc(2ull * Tc * Dc);
  u16* o_b = (u16*)alloc(2ull * Tc * Dc);
  (void)kr; (void)o_b;
  float* x2 = (float*)alloc(4ull * Tc * Dc);
  u16* hf_b = (u16*)alloc(2ull * Tc * Dc);
  float* router = (float*)alloc(4ull * Tc * Dc);
  // MoE index arrays
  int* counts = (int*)alloc(8 * 4);
  int* topk_e = (int*)alloc(2ull * Tc * 4);
  float* topk_w = (float*)alloc(2ull * Tc * 4);
  int* pos_of = (int*)alloc(2ull * Tc * 4);
  int* etok = (int*)alloc(8ull * 4096 * 4);
  int* meta = (int*)alloc(512 * 4);
  int* rexp = (int*)alloc((size_t)MAX_TILES * 128 * 4);
  // aliases (lifetimes disjoint; attn buffers are dead by MoE time)
  u16* sgact = q_b;   // spans q_b,k_b (16MB)
  u16* suact = v_b;   // spans v_b,h_b (16MB)
  u16* hs_b = vt_;    // spans vt_,o_b (16MB)  -- lives until final GEMM
  u16* a1_c = q_b;    // compact MoE (18.9MB, spans q_b..v_b)
  u16* a3_c = h_b;    // compact MoE (18.9MB, spans h_b..kr)
  u16* he_c = a1_c;   // silu in-place
  u16* eo_c = h_b;    // w2 output (18.9MB, a3_c's region after silu)

  auto conv = [&](const float* s, u16* d, size_t n) {
    f2b_convert<<<dim3((unsigned)(n / 2048)), 256, 0, stream>>>(s, d);
  };
  conv(wq, wq_b, (size_t)Dc * Dc);
  conv(wk, wk_b, (size_t)Dc * Dc);
  conv(wv, wv_b, (size_t)Dc * Dc);
  conv(wo, wo_b, (size_t)Dc * Dc);
  conv(sgw, sgw_b, (size_t)SH * Dc);
  conv(suw, suw_b, (size_t)SH * Dc);
  conv(sdw, sdw_b, (size_t)Dc * SH);
  conv(w1, w1_b, (size_t)8 * MH * Dc);
  conv(w2, w2_b, (size_t)8 * Dc * MH);
  conv(w3, w3_b, (size_t)8 * MH * Dc);

  // ---- attention branch ----
  rmsnorm_bf16<<<Tc, 256, 0, stream>>>(x, anw, h_b);
  gemm_bt<0><<<dim3(Dc / 128, Tc / 128), 256, 0, stream>>>(
      h_b, wq_b, Tc, Dc, Dc, q_b, nullptr, nullptr, nullptr, nullptr, nullptr,
      nullptr);
  gemm_bt<0><<<dim3(Dc / 128, Tc / 128), 256, 0, stream>>>(
      h_b, wk_b, Tc, Dc, Dc, k_b, nullptr, nullptr, nullptr, nullptr, nullptr,
      nullptr);
  gemm_bt<0><<<dim3(Dc / 128, Tc / 128), 256, 0, stream>>>(
      h_b, wv_b, Tc, Dc, Dc, v_b, nullptr, nullptr, nullptr, nullptr, nullptr,
      nullptr);
  rope_repack<<<Tc, 256, 0, stream>>>(q_b, k_b, v_b, fc, fs, qr, kr, vt_, Sc);
  attn_fwd<<<dim3(Sc / 64, 2 * NHc), 256, 0, stream>>>(qr, kr, vt_, o_b, Sc,
                                                       NHc);
  gemm_bt<1><<<dim3(Dc / 128, Tc / 128), 256, 0, stream>>>(
      o_b, wo_b, Tc, Dc, Dc, nullptr, x2, x, nullptr, nullptr, nullptr,
      nullptr);

  // ---- ffn branch ----
  rmsnorm_bf16<<<Tc, 256, 0, stream>>>(x2, fnw, hf_b);
  zero_counts<<<1, 64, 0, stream>>>(counts);
  gate_topk<<<Tc / 4, 256, 0, stream>>>(x2, fnw, gw, gb, counts, topk_e,
                                        topk_w, pos_of, etok);
  sched_moe<<<1, 256, 0, stream>>>(counts, meta, rexp);

  // shared expert
  gemm_bt<0><<<dim3(SH / 128, Tc / 128), 256, 0, stream>>>(
      hf_b, sgw_b, Tc, SH, Dc, sgact, nullptr, nullptr, nullptr, nullptr,
      nullptr, nullptr);
  gemm_bt<0><<<dim3(SH / 128, Tc / 128), 256, 0, stream>>>(
      hf_b, suw_b, Tc, SH, Dc, suact, nullptr, nullptr, nullptr, nullptr,
      nullptr, nullptr);
  silu_mul<<<dim3((unsigned)(((size_t)Tc * SH) / 2048)), 256, 0, stream>>>(
      sgact, suact, hs_b);

  // sparse MoE (grouped)
  gemm_bt<5><<<dim3(MH / 128, MAX_TILES), 256, 0, stream>>>(
      hf_b, w1_b, Tc, MH, Dc, a1_c, nullptr, nullptr, nullptr, nullptr, meta,
      etok);
  gemm_bt<5><<<dim3(MH / 128, MAX_TILES), 256, 0, stream>>>(
      hf_b, w3_b, Tc, MH, Dc, a3_c, nullptr, nullptr, nullptr, nullptr, meta,
      etok);
  silu_moe<<<dim3((unsigned)(((size_t)MAX_TILES * 128 * MH) / 2048)), 256, 0,
             stream>>>(a1_c, a3_c, b1, b3, rexp, he_c);
  gemm_bt<6><<<dim3(Dc / 128, MAX_TILES), 256, 0, stream>>>(
      he_c, w2_b, Tc, Dc, MH, eo_c, nullptr, nullptr, nullptr, b2, meta,
      etok);
  combine_router<<<Tc, 128, 0, stream>>>(eo_c, topk_e, topk_w, pos_of, meta,
                                         router);

  // final: out = x2 + router + shared_down
  gemm_bt<4><<<dim3(Dc / 128, Tc / 128), 256, 0, stream>>>(
      hs_b, sdw_b, Tc, Dc, SH, nullptr, out, x2, router, nullptr, nullptr,
      nullptr);
}

// Round 3
// 561.981 us; speedup vs baseline: 2.2277x; 1.1789x over previous
//
#include <hip/hip_runtime.h>

// ---------------------------------------------------------------------------
// TransformerBlock on MI355X (gfx950), round 3:
//  - attention: swapped QK^T (lane-local softmax rows), in-register P via
//    cvt_pk_bf16, PV with permuted k-slots (no P LDS round-trip),
//    setprio around MFMA, heavy-tile-first dispatch
//  - fused QKV / sg|su / w1|w3 GEMMs
//  - coalesced V-transpose via LDS tile
// ---------------------------------------------------------------------------

typedef unsigned short u16;
typedef __attribute__((ext_vector_type(8))) short bh8;   // 8 x bf16
typedef __attribute__((ext_vector_type(4))) short sh4;   // 4 x bf16
typedef __attribute__((ext_vector_type(4))) float fv4;
typedef __attribute__((ext_vector_type(4))) unsigned uv4;

#define LOG2E 1.4426950408889634f
#define MAX_TILES 71

__device__ __forceinline__ float b2f(u16 u) {
  return __builtin_bit_cast(float, ((unsigned)u) << 16);
}
__device__ __forceinline__ u16 f2b(float f) {
  unsigned x = __builtin_bit_cast(unsigned, f);
  return (u16)((x + 0x7fffu + ((x >> 16) & 1u)) >> 16);  // RNE
}
__device__ __forceinline__ fv4 mfma16(bh8 a, bh8 b, fv4 c) {
  return __builtin_amdgcn_mfma_f32_16x16x32_bf16(a, b, c, 0, 0, 0);
}
__device__ __forceinline__ unsigned cvtpk(float lo, float hi) {
  unsigned r;
  asm("v_cvt_pk_bf16_f32 %0, %1, %2" : "=v"(r) : "v"(lo), "v"(hi));
  return r;
}

#define GLD16(g, l)                                                        \
  __builtin_amdgcn_global_load_lds(                                        \
      (const __attribute__((address_space(1))) void*)(g),                  \
      (__attribute__((address_space(3))) void*)(l), 16, 0, 0)

// Read one MFMA fragment (16B) from a [rows][64] bf16 LDS tile whose rows are
// 128B and whose 16B blocks are XOR-swizzled by (row&7).
__device__ __forceinline__ bh8 lds_frag(const u16* base, int row, int b8) {
  int off = row * 128 + ((b8 * 16) ^ ((row & 7) << 4));
  return *(const bh8*)((const char*)base + off);
}

// ---------------------------------------------------------------------------
// Generic GEMM: C[M,N] = A[M,K] (bf16) @ B[N,K]^T (bf16), f32 accumulate.
// MODE 0: Cb = bf16(gemm)
// MODE 1: Cf = add1 + gemm
// MODE 4: Cf = add1 + add2 + gemm                 (final output)
// MODE 5: gather-A grouped MoE (w1|w3): A rows via expert token list.
// MODE 6: compact-A grouped MoE (w2): lda passed via M; Cb = bf16(gemm+bias_e)
// ---------------------------------------------------------------------------
template <int MODE>
__global__ __launch_bounds__(256) void gemm_bt(
    const u16* __restrict__ A, const u16* __restrict__ B, int M, int N, int K,
    u16* __restrict__ Cb, float* __restrict__ Cf,
    const float* __restrict__ add1, const float* __restrict__ add2,
    const float* __restrict__ bias, const int* __restrict__ tmeta,
    const int* __restrict__ etok) {
  __shared__ u16 As[128 * 64];
  __shared__ u16 Bs[128 * 64];
  const int lane = threadIdx.x & 63;
  const int wid = threadIdx.x >> 6;
  const int wr = wid >> 1, wc = wid & 1;
  const int n0 = blockIdx.x * 128;
  const int rr = lane >> 3;
  const int b8s = (lane & 7) ^ rr;
  const int ldA = (MODE == 6) ? M : K;

  int m0 = 0, e = 0, m0l = 0, cnt = 0, row0 = 0;
  const u16* Bp = B;
  if constexpr (MODE == 5 || MODE == 6) {
    int tile = blockIdx.y;
    if (tile >= tmeta[0]) return;
    e = tmeta[16 + tile * 4];
    m0l = tmeta[17 + tile * 4];
    cnt = tmeta[18 + tile * 4];
    row0 = tmeta[19 + tile * 4];
    Bp = B + (size_t)e * N * K;
  } else {
    m0 = blockIdx.y * 128;
  }

  const u16* Arow[4];
  const u16* Brow[4];
#pragma unroll
  for (int i = 0; i < 4; ++i) {
    int c = wid * 4 + i;
    int row = c * 8 + rr;
    if constexpr (MODE == 5) {
      int li = m0l + row;
      li = li < cnt ? li : cnt - 1;
      int tok = etok[e * 4096 + li];
      Arow[i] = A + (size_t)tok * ldA + b8s * 8;
    } else if constexpr (MODE == 6) {
      Arow[i] = A + (size_t)(row0 + row) * ldA + b8s * 8;
    } else {
      Arow[i] = A + (size_t)(m0 + row) * ldA + b8s * 8;
    }
    Brow[i] = Bp + (size_t)(n0 + row) * K + b8s * 8;
  }

  fv4 acc[4][4] = {};
  for (int k0 = 0; k0 < K; k0 += 64) {
    __syncthreads();
#pragma unroll
    for (int i = 0; i < 4; ++i) {
      int c = wid * 4 + i;
      GLD16(Arow[i] + k0, &As[c * 512]);
      GLD16(Brow[i] + k0, &Bs[c * 512]);
    }
    __syncthreads();
#pragma unroll
    for (int ks = 0; ks < 2; ++ks) {
      int b8 = ks * 4 + (lane >> 4);
      bh8 af[4], bf[4];
#pragma unroll
      for (int mi = 0; mi < 4; ++mi)
        af[mi] = lds_frag(As, wr * 64 + mi * 16 + (lane & 15), b8);
#pragma unroll
      for (int ni = 0; ni < 4; ++ni)
        bf[ni] = lds_frag(Bs, wc * 64 + ni * 16 + (lane & 15), b8);
      __builtin_amdgcn_s_setprio(1);
#pragma unroll
      for (int mi = 0; mi < 4; ++mi)
#pragma unroll
        for (int ni = 0; ni < 4; ++ni)
          acc[mi][ni] = mfma16(af[mi], bf[ni], acc[mi][ni]);
      __builtin_amdgcn_s_setprio(0);
    }
  }

  const int rbase = (MODE == 5 || MODE == 6) ? row0 : m0;
  const int r0b = rbase + wr * 64 + (lane >> 4) * 4;
  const int c0b = n0 + wc * 64 + (lane & 15);
  const float* bb = nullptr;
  if constexpr (MODE == 6) bb = bias + (size_t)e * N;
#pragma unroll
  for (int mi = 0; mi < 4; ++mi) {
#pragma unroll
    for (int ni = 0; ni < 4; ++ni) {
      int c = c0b + ni * 16;
#pragma unroll
      for (int r = 0; r < 4; ++r) {
        int row = r0b + mi * 16 + r;
        size_t idx = (size_t)row * N + c;
        float v = acc[mi][ni][r];
        if constexpr (MODE == 0) Cb[idx] = f2b(v);
        else if constexpr (MODE == 1) Cf[idx] = add1[idx] + v;
        else if constexpr (MODE == 4) Cf[idx] = add1[idx] + add2[idx] + v;
        else if constexpr (MODE == 5) Cb[idx] = f2b(v);
        else Cb[idx] = f2b(v + bb[c]);
      }
    }
  }
}

// ---------------------------------------------------------------------------
// RMSNorm: f32 [T,1024] -> bf16 [T,1024], one block per token.
// ---------------------------------------------------------------------------
__global__ __launch_bounds__(256) void rmsnorm_bf16(
    const float* __restrict__ x, const float* __restrict__ w,
    u16* __restrict__ out) {
  int t = blockIdx.x;
  const float* xr = x + (size_t)t * 1024;
  fv4 v = *(const fv4*)(xr + threadIdx.x * 4);
  float ss = v[0] * v[0] + v[1] * v[1] + v[2] * v[2] + v[3] * v[3];
#pragma unroll
  for (int off = 1; off < 64; off <<= 1) ss += __shfl_xor(ss, off);
  __shared__ float red[4];
  int lane = threadIdx.x & 63, wid = threadIdx.x >> 6;
  if (lane == 0) red[wid] = ss;
  __syncthreads();
  float inv = rsqrtf((red[0] + red[1] + red[2] + red[3]) * (1.0f / 1024.f) + 1e-6f);
  u16* op = out + (size_t)t * 1024 + threadIdx.x * 4;
  const float* wp = w + threadIdx.x * 4;
#pragma unroll
  for (int i = 0; i < 4; ++i) op[i] = f2b(v[i] * inv * wp[i]);
}

// ---------------------------------------------------------------------------
// RoPE + repack from fused qkv [T,3072]:
//   q,k -> rotated [B,NH,S,64]; v -> vt [B,NH,64,S] via coalesced LDS transpose.
// Grid: (S/64, B, NH/4).
// ---------------------------------------------------------------------------
__global__ __launch_bounds__(256) void rope_repack(
    const u16* __restrict__ qkv, const float* __restrict__ fc,
    const float* __restrict__ fs, u16* __restrict__ qr, u16* __restrict__ kr,
    u16* __restrict__ vt, int S) {
  __shared__ u16 tile[64][65];
  const int s0 = blockIdx.x * 64;
  const int b = blockIdx.y;
  const int h0 = blockIdx.z * 4;
#pragma unroll 4
  for (int it = 0; it < 32; ++it) {
    int idx = threadIdx.x + it * 256;
    int tl = idx >> 7, rem = idx & 127;
    int h = h0 + (rem >> 5), i = rem & 31;
    int s = s0 + tl;
    float c = fc[s * 32 + i], sn = fs[s * 32 + i];
    size_t src = ((size_t)(b * S + s)) * 3072 + h * 64 + 2 * i;
    size_t dst = ((size_t)((b * 16 + h) * S + s)) * 64 + 2 * i;
    float a0 = b2f(qkv[src]), a1 = b2f(qkv[src + 1]);
    qr[dst] = f2b(a0 * c - a1 * sn);
    qr[dst + 1] = f2b(a0 * sn + a1 * c);
    float b0 = b2f(qkv[src + 1024]), b1 = b2f(qkv[src + 1025]);
    kr[dst] = f2b(b0 * c - b1 * sn);
    kr[dst + 1] = f2b(b0 * sn + b1 * c);
  }
  for (int hh = 0; hh < 4; ++hh) {
    int h = h0 + hh;
    __syncthreads();
    for (int cc = threadIdx.x; cc < 512; cc += 256) {
      int tl = cc >> 3, d8 = cc & 7;
      bh8 val = *(const bh8*)(qkv + ((size_t)(b * S + s0 + tl)) * 3072 + 2048 +
                              h * 64 + d8 * 8);
#pragma unroll
      for (int j = 0; j < 8; ++j) tile[tl][d8 * 8 + j] = (u16)val[j];
    }
    __syncthreads();
    for (int cc = threadIdx.x; cc < 512; cc += 256) {
      int d = cc >> 3, s8 = cc & 7;
      bh8 o;
#pragma unroll
      for (int j = 0; j < 8; ++j) o[j] = (short)tile[s8 * 8 + j][d];
      *(bh8*)(vt + ((size_t)((b * 16 + h) * 64 + d)) * S + s0 + s8 * 8) = o;
    }
  }
}

// ---------------------------------------------------------------------------
// Flash attention (causal), swapped QK^T: lane owns one q-row's scores.
// Grid: (S/64 heavy-first, B*NH). 4 waves x 16 q-rows, KVBLK=64, dbuf staging.
// ---------------------------------------------------------------------------
__global__ __launch_bounds__(256) void attn_fwd(
    const u16* __restrict__ qr, const u16* __restrict__ kr,
    const u16* __restrict__ vt, u16* __restrict__ ob, int S, int NHc) {
  __shared__ u16 Ks[2][64 * 64];
  __shared__ u16 Vs[2][64 * 64];   // V^T tile: [d][j]
  const int lane = threadIdx.x & 63;
  const int wid = threadIdx.x >> 6;
  const int g = lane >> 4;
  const int l15 = lane & 15;
  const int bh = blockIdx.y;
  const int nq = S / 64;
  const int q0 = (nq - 1 - (int)blockIdx.x) * 64;  // heavy tiles first
  const int b = bh / NHc, h = bh % NHc;
  const u16* qb = qr + (size_t)bh * S * 64;
  const u16* kb = kr + (size_t)bh * S * 64;
  const u16* vb = vt + (size_t)bh * 64 * S;
  const float SC = 0.015625f * LOG2E;  // both ref scales, log2 domain
  const int q_my = q0 + wid * 16 + l15;
  const int rr = lane >> 3;
  const int b8s = (lane & 7) ^ rr;

  bh8 qf[2];  // B-frag of Q: row q_my, d-blocks 8g and 32+8g
  {
    const u16* qp = qb + (size_t)q_my * 64 + g * 8;
    qf[0] = *(const bh8*)qp;
    qf[1] = *(const bh8*)(qp + 32);
  }
  fv4 oacc[4] = {};
  float mrow = -1e30f, lrow = 0.f;
  const int nkt = q0 / 64 + 1;

  auto stage = [&](int buf, int j0) {
#pragma unroll
    for (int i = 0; i < 2; ++i) {
      int c = wid * 2 + i;
      int row = c * 8 + rr;
      GLD16(kb + (size_t)(j0 + row) * 64 + b8s * 8, &Ks[buf][c * 512]);
      GLD16(vb + (size_t)row * S + j0 + b8s * 8, &Vs[buf][c * 512]);
    }
  };
  stage(0, 0);

  for (int kt = 0; kt < nkt; ++kt) {
    const int j0 = kt * 64;
    __syncthreads();
    if (kt + 1 < nkt) stage((kt + 1) & 1, (kt + 1) * 64);
    const u16* Kc = Ks[kt & 1];
    const u16* Vc = Vs[kt & 1];

    // S^T: st[jt][r] = score[k = j0+jt*16+4g+r][q = q_my]
    fv4 st[4] = {};
    __builtin_amdgcn_s_setprio(1);
#pragma unroll
    for (int ks = 0; ks < 2; ++ks) {
      int b8 = ks * 4 + g;
#pragma unroll
      for (int jt = 0; jt < 4; ++jt) {
        bh8 kf = lds_frag(Kc, jt * 16 + l15, b8);
        st[jt] = mfma16(kf, qf[ks], st[jt]);
      }
    }
    __builtin_amdgcn_s_setprio(0);

    float p[4][4];
    float mloc = -1e30f;
    const int jb = j0 + 4 * g;
#pragma unroll
    for (int jt = 0; jt < 4; ++jt)
#pragma unroll
      for (int r = 0; r < 4; ++r) {
        int j = jb + jt * 16 + r;
        float s = st[jt][r] * SC;
        s = (j <= q_my) ? s : -1e30f;
        p[jt][r] = s;
        mloc = fmaxf(mloc, s);
      }
    mloc = fmaxf(mloc, __shfl_xor(mloc, 16));
    mloc = fmaxf(mloc, __shfl_xor(mloc, 32));
    float mnew = fmaxf(mrow, mloc);
    float sfac = exp2f(mrow - mnew);
    mrow = mnew;
    float rsum = 0.f;
#pragma unroll
    for (int jt = 0; jt < 4; ++jt)
#pragma unroll
      for (int r = 0; r < 4; ++r) {
        float pv = exp2f(p[jt][r] - mnew);
        p[jt][r] = pv;
        rsum += pv;
      }
    rsum += __shfl_xor(rsum, 16);
    rsum += __shfl_xor(rsum, 32);
    lrow = lrow * sfac + rsum;
    // oacc[dt][r] holds q' = wid*16 + 4g + r -> fetch its sfac from lane 4g+r
    float sf[4];
#pragma unroll
    for (int r = 0; r < 4; ++r) sf[r] = __shfl(sfac, g * 4 + r);
#pragma unroll
    for (int dt = 0; dt < 4; ++dt)
#pragma unroll
      for (int r = 0; r < 4; ++r) oacc[dt][r] *= sf[r];

    // PV with permuted k-slots: mfma ks uses k = {16ks+4g+i, 16(ks+2)+4g+i}
    __builtin_amdgcn_s_setprio(1);
#pragma unroll
    for (int ks = 0; ks < 2; ++ks) {
      uv4 w;
      w[0] = cvtpk(p[ks][0], p[ks][1]);
      w[1] = cvtpk(p[ks][2], p[ks][3]);
      w[2] = cvtpk(p[ks + 2][0], p[ks + 2][1]);
      w[3] = cvtpk(p[ks + 2][2], p[ks + 2][3]);
      bh8 pa = __builtin_bit_cast(bh8, w);
      const int c0 = ks * 32 + g * 8;   // byte col of first 8B group
      const int cA = c0 & 48, cs = c0 & 8;
#pragma unroll
      for (int dt = 0; dt < 4; ++dt) {
        int row = dt * 16 + l15;
        int sw = (row & 7) << 4;
        const char* rp = (const char*)Vc + row * 128;
        sh4 lo = *(const sh4*)(rp + ((cA ^ sw) | cs));
        sh4 hi = *(const sh4*)(rp + (((cA + 64) ^ sw) | cs));
        bh8 vf = __builtin_shufflevector(lo, hi, 0, 1, 2, 3, 4, 5, 6, 7);
        oacc[dt] = mfma16(pa, vf, oacc[dt]);
      }
    }
    __builtin_amdgcn_s_setprio(0);
  }
  float lr[4];
#pragma unroll
  for (int r = 0; r < 4; ++r) lr[r] = __shfl(lrow, g * 4 + r);
#pragma unroll
  for (int dt = 0; dt < 4; ++dt)
#pragma unroll
    for (int r = 0; r < 4; ++r) {
      int row = q0 + wid * 16 + g * 4 + r;
      int col = dt * 16 + l15;
      ob[((size_t)b * S + row) * 1024 + h * 64 + col] =
          f2b(oacc[dt][r] / lr[r]);
    }
}

// ---------------------------------------------------------------------------
// MoE routing
// ---------------------------------------------------------------------------
__global__ void zero_counts(int* counts) {
  if (threadIdx.x < 8) counts[threadIdx.x] = 0;
}

__global__ __launch_bounds__(256) void gate_topk(
    const float* __restrict__ x2, const float* __restrict__ nw,
    const float* __restrict__ gw, const float* __restrict__ gb,
    int* __restrict__ counts, int* __restrict__ topk_e,
    float* __restrict__ topk_w, int* __restrict__ pos_of,
    int* __restrict__ etok) {
  int t = blockIdx.x * 4 + (threadIdx.x >> 6);
  int lane = threadIdx.x & 63;
  const float* xr = x2 + (size_t)t * 1024;
  float hv[16];
  float ss = 0.f;
#pragma unroll
  for (int i = 0; i < 4; ++i) {
    fv4 v = *(const fv4*)(xr + lane * 16 + i * 4);
#pragma unroll
    for (int j = 0; j < 4; ++j) {
      hv[i * 4 + j] = v[j];
      ss += v[j] * v[j];
    }
  }
#pragma unroll
  for (int off = 1; off < 64; off <<= 1) ss += __shfl_xor(ss, off);
  float inv = rsqrtf(ss * (1.0f / 1024.f) + 1e-6f);
#pragma unroll
  for (int i = 0; i < 16; ++i) hv[i] = hv[i] * inv * nw[lane * 16 + i];
  float logit[8];
#pragma unroll
  for (int e = 0; e < 8; ++e) {
    const float* wp = gw + (size_t)e * 1024 + lane * 16;
    float s = 0.f;
#pragma unroll
    for (int i = 0; i < 16; ++i) s += hv[i] * wp[i];
#pragma unroll
    for (int off = 1; off < 64; off <<= 1) s += __shfl_xor(s, off);
    logit[e] = s + gb[e];
  }
  if (lane == 0) {
    float mx = logit[0];
#pragma unroll
    for (int e = 1; e < 8; ++e) mx = fmaxf(mx, logit[e]);
    float pe[8], se = 0.f;
#pragma unroll
    for (int e = 0; e < 8; ++e) { pe[e] = __expf(logit[e] - mx); se += pe[e]; }
    float rs = 1.f / se;
#pragma unroll
    for (int e = 0; e < 8; ++e) pe[e] *= rs;
    int i0 = 0;
    float b0 = pe[0];
#pragma unroll
    for (int e = 1; e < 8; ++e)
      if (pe[e] > b0) { b0 = pe[e]; i0 = e; }
    int i1 = -1;
    float b1v = -1.f;
#pragma unroll
    for (int e = 0; e < 8; ++e)
      if (e != i0 && pe[e] > b1v) { b1v = pe[e]; i1 = e; }
    topk_e[2 * t] = i0;
    topk_e[2 * t + 1] = i1;
    topk_w[2 * t] = b0;
    topk_w[2 * t + 1] = b1v;
    int p0 = atomicAdd(&counts[i0], 1);
    etok[i0 * 4096 + p0] = t;
    pos_of[2 * t] = p0;
    int p1 = atomicAdd(&counts[i1], 1);
    etok[i1 * 4096 + p1] = t;
    pos_of[2 * t + 1] = p1;
  }
}

__global__ __launch_bounds__(256) void sched_moe(const int* __restrict__ counts,
                                                 int* __restrict__ meta,
                                                 int* __restrict__ rexp) {
  __shared__ int s_e[MAX_TILES], s_row0[MAX_TILES], s_tt, s_rb;
  if (threadIdx.x == 0) {
    int tt = 0, rb = 0;
    for (int e = 0; e < 8; ++e) {
      meta[1 + e] = rb;
      int c = counts[e];
      int nt = (c + 127) >> 7;
      for (int i = 0; i < nt; ++i) {
        meta[16 + tt * 4] = e;
        meta[17 + tt * 4] = i * 128;
        meta[18 + tt * 4] = c;
        meta[19 + tt * 4] = rb + i * 128;
        s_e[tt] = e;
        s_row0[tt] = rb + i * 128;
        ++tt;
      }
      rb += nt * 128;
    }
    meta[0] = tt;
    s_tt = tt;
    s_rb = rb;
  }
  __syncthreads();
  int tt = s_tt;
  for (int tile = 0; tile < tt; ++tile) {
    int r0 = s_row0[tile], e = s_e[tile];
    for (int j = threadIdx.x; j < 128; j += 256) rexp[r0 + j] = e;
  }
  for (int r = s_rb + threadIdx.x; r < MAX_TILES * 128; r += 256) rexp[r] = 0;
}

// silu(a13[:, c]+b1[e,c]) * (a13[:, 1024+c]+b3[e,c]) -> in-place lower half.
__global__ __launch_bounds__(256) void silu_moe(
    u16* __restrict__ a13, const float* __restrict__ b1,
    const float* __restrict__ b3, const int* __restrict__ rexp) {
  size_t i = ((size_t)blockIdx.x * 256 + threadIdx.x) * 8;
  int row = (int)(i >> 10), col = (int)(i & 1023);
  int e = rexp[row];
  const float* ba = b1 + (size_t)e * 1024 + col;
  const float* bb = b3 + (size_t)e * 1024 + col;
  u16* rp = a13 + (size_t)row * 2048 + col;
  bh8 av = *(const bh8*)rp;
  bh8 bv = *(const bh8*)(rp + 1024);
  bh8 ov;
#pragma unroll
  for (int j = 0; j < 8; ++j) {
    float x = b2f((u16)av[j]) + ba[j];
    float y = b2f((u16)bv[j]) + bb[j];
    float s = x / (1.f + __expf(-x));
    ov[j] = (short)f2b(s * y);
  }
  *(bh8*)rp = ov;
}

__global__ __launch_bounds__(128) void combine_router(
    const u16* __restrict__ eo, const int* __restrict__ topk_e,
    const float* __restrict__ topk_w, const int* __restrict__ pos_of,
    const int* __restrict__ meta, float* __restrict__ router) {
  int t = blockIdx.x;
  int c = threadIdx.x * 8;
  int e0 = topk_e[2 * t], e1 = topk_e[2 * t + 1];
  float w0 = topk_w[2 * t], w1 = topk_w[2 * t + 1];
  int r0 = meta[1 + e0] + pos_of[2 * t];
  int r1 = meta[1 + e1] + pos_of[2 * t + 1];
  bh8 v0 = *(const bh8*)(eo + (size_t)r0 * 1024 + c);
  bh8 v1 = *(const bh8*)(eo + (size_t)r1 * 1024 + c);
  float* rp = router + (size_t)t * 1024 + c;
#pragma unroll
  for (int j = 0; j < 8; ++j)
    rp[j] = w0 * b2f((u16)v0[j]) + w1 * b2f((u16)v1[j]);
}

// silu(sgu[:,c]) * sgu[:,2048+c] -> hs [T,2048]
__global__ __launch_bounds__(256) void silu_sh(const u16* __restrict__ sgu,
                                               u16* __restrict__ hs) {
  size_t i = ((size_t)blockIdx.x * 256 + threadIdx.x) * 8;
  size_t row = i >> 11, col = i & 2047;
  const u16* rp = sgu + row * 4096 + col;
  bh8 av = *(const bh8*)rp;
  bh8 bv = *(const bh8*)(rp + 2048);
  bh8 ov;
#pragma unroll
  for (int j = 0; j < 8; ++j) {
    float x = b2f((u16)av[j]);
    float y = b2f((u16)bv[j]);
    float s = x / (1.f + __expf(-x));
    ov[j] = (short)f2b(s * y);
  }
  *(bh8*)(hs + i) = ov;
}

__global__ __launch_bounds__(256) void f2b_convert(
    const float* __restrict__ src, u16* __restrict__ dst) {
  size_t i = ((size_t)blockIdx.x * 256 + threadIdx.x) * 8;
  fv4 a = *(const fv4*)(src + i);
  fv4 b = *(const fv4*)(src + i + 4);
  bh8 o;
#pragma unroll
  for (int j = 0; j < 4; ++j) o[j] = (short)f2b(a[j]);
#pragma unroll
  for (int j = 0; j < 4; ++j) o[4 + j] = (short)f2b(b[j]);
  *(bh8*)(dst + i) = o;
}

// interleave w1/w3 [E,1024,1024] f32 -> w13 [E,2048,1024] bf16 (half select)
__global__ __launch_bounds__(256) void f2b_convert_moe(
    const float* __restrict__ src, u16* __restrict__ dst, int halfoff) {
  size_t i = ((size_t)blockIdx.x * 256 + threadIdx.x) * 8;
  size_t e = i >> 20, inner = i & 1048575;
  fv4 a = *(const fv4*)(src + i);
  fv4 b = *(const fv4*)(src + i + 4);
  bh8 o;
#pragma unroll
  for (int j = 0; j < 4; ++j) o[j] = (short)f2b(a[j]);
#pragma unroll
  for (int j = 0; j < 4; ++j) o[4 + j] = (short)f2b(b[j]);
  *(bh8*)(dst + e * 2097152 + halfoff + inner) = o;
}

// ---------------------------------------------------------------------------
extern "C" void kernel_launch(void* const* d_in, const int* in_sizes, int n_in,
                              void* d_out, int out_size, void* d_ws,
                              size_t ws_size, hipStream_t stream) {
  (void)in_sizes; (void)n_in; (void)out_size; (void)ws_size;
  const int Sc = 2048, Dc = 1024, NHc = 16, Tc = 4096, SH = 2048;

  const float* x   = (const float*)d_in[0];
  const float* fc  = (const float*)d_in[1];
  const float* fs  = (const float*)d_in[2];
  const float* wq  = (const float*)d_in[4];
  const float* wk  = (const float*)d_in[5];
  const float* wv  = (const float*)d_in[6];
  const float* wo  = (const float*)d_in[7];
  const float* anw = (const float*)d_in[8];
  const float* fnw = (const float*)d_in[9];
  const float* gw  = (const float*)d_in[10];
  const float* gb  = (const float*)d_in[11];
  const float* w1  = (const float*)d_in[12];
  const float* b1  = (const float*)d_in[13];
  const float* w2  = (const float*)d_in[14];
  const float* b2  = (const float*)d_in[15];
  const float* w3  = (const float*)d_in[16];
  const float* b3  = (const float*)d_in[17];
  const float* sgw = (const float*)d_in[18];
  const float* suw = (const float*)d_in[19];
  const float* sdw = (const float*)d_in[20];
  float* out = (float*)d_out;

  char* base = (char*)d_ws;
  size_t off = 0;
  auto alloc = [&](size_t bytes) -> void* {
    void* p = base + off;
    off += (bytes + 255) & ~(size_t)255;
    return p;
  };
  // weights: wqkv+wo FIRST (their region is reused as hf_b after wo-gemm)
  u16* wqkv_b = (u16*)alloc(2ull * 3072 * 1024);   // 6.29 MB
  u16* wo_b   = (u16*)alloc(2ull * 1024 * 1024);   // 2.10 MB
  u16* sgu_b  = (u16*)alloc(2ull * 4096 * 1024);   // 8.39 MB
  u16* sdw_b  = (u16*)alloc(2ull * 1024 * 2048);   // 4.19 MB
  u16* w13_b  = (u16*)alloc(2ull * 8 * 2048 * 1024); // 33.6 MB
  u16* w2_b   = (u16*)alloc(2ull * 8 * 1024 * 1024); // 16.8 MB
  // region A: qkv_out (25.2) -> sgu_out (33.6) -> eo (18.6)
  char* regA = (char*)alloc(2ull * Tc * 4096);
  // region B: h_b/qr/kr/vt/o_b (33.6) -> a13 (37.2) -> router (16.8)
  char* regB = (char*)alloc(2ull * (size_t)MAX_TILES * 128 * 2048);
  float* x2  = (float*)alloc(4ull * Tc * Dc);      // 16.8 MB
  u16* hs_b  = (u16*)alloc(2ull * Tc * SH);        // 16.8 MB
  int* counts = (int*)alloc(8 * 4);
  int* topk_e = (int*)alloc(2ull * Tc * 4);
  float* topk_w = (float*)alloc(2ull * Tc * 4);
  int* pos_of = (int*)alloc(2ull * Tc * 4);
  int* etok = (int*)alloc(8ull * 4096 * 4);
  int* meta = (int*)alloc(512 * 4);
  int* rexp = (int*)alloc((size_t)MAX_TILES * 128 * 4);

  u16* qkv_out = (u16*)regA;
  u16* sgu_out = (u16*)regA;
  u16* eo_c    = (u16*)regA;
  u16* h_b  = (u16*)regB;
  u16* qr   = (u16*)regB;
  u16* kr   = (u16*)(regB + 2ull * Tc * Dc);
  u16* vt_  = (u16*)(regB + 4ull * Tc * Dc);
  u16* o_b  = (u16*)(regB + 6ull * Tc * Dc);
  u16* a13_c = (u16*)regB;
  float* router = (float*)regB;
  u16* hf_b = wqkv_b;  // overlays wqkv+wo after attention branch done

  auto conv = [&](const float* s, u16* d, size_t n) {
    f2b_convert<<<dim3((unsigned)(n / 2048)), 256, 0, stream>>>(s, d);
  };
  conv(wq, wqkv_b, (size_t)Dc * Dc);
  conv(wk, wqkv_b + 1048576, (size_t)Dc * Dc);
  conv(wv, wqkv_b + 2097152, (size_t)Dc * Dc);
  conv(wo, wo_b, (size_t)Dc * Dc);
  conv(sgw, sgu_b, (size_t)SH * Dc);
  conv(suw, sgu_b + 2097152, (size_t)SH * Dc);
  conv(sdw, sdw_b, (size_t)Dc * SH);
  conv(w2, w2_b, 8ull * 1024 * 1024);
  f2b_convert_moe<<<4096, 256, 0, stream>>>(w1, w13_b, 0);
  f2b_convert_moe<<<4096, 256, 0, stream>>>(w3, w13_b, 1048576);

  // ---- attention branch ----
  rmsnorm_bf16<<<Tc, 256, 0, stream>>>(x, anw, h_b);
  gemm_bt<0><<<dim3(3072 / 128, Tc / 128), 256, 0, stream>>>(
      h_b, wqkv_b, Tc, 3072, Dc, qkv_out, nullptr, nullptr, nullptr, nullptr,
      nullptr, nullptr);
  rope_repack<<<dim3(Sc / 64, 2, 4), 256, 0, stream>>>(qkv_out, fc, fs, qr, kr,
                                                       vt_, Sc);
  attn_fwd<<<dim3(Sc / 64, 2 * NHc), 256, 0, stream>>>(qr, kr, vt_, o_b, Sc,
                                                       NHc);
  gemm_bt<1><<<dim3(Dc / 128, Tc / 128), 256, 0, stream>>>(
      o_b, wo_b, Tc, Dc, Dc, nullptr, x2, x, nullptr, nullptr, nullptr,
      nullptr);

  // ---- ffn branch ----
  rmsnorm_bf16<<<Tc, 256, 0, stream>>>(x2, fnw, hf_b);
  zero_counts<<<1, 64, 0, stream>>>(counts);
  gate_topk<<<Tc / 4, 256, 0, stream>>>(x2, fnw, gw, gb, counts, topk_e,
                                        topk_w, pos_of, etok);
  sched_moe<<<1, 256, 0, stream>>>(counts, meta, rexp);

  // shared expert: fused gate|up GEMM then silu
  gemm_bt<0><<<dim3(4096 / 128, Tc / 128), 256, 0, stream>>>(
      hf_b, sgu_b, Tc, 4096, Dc, sgu_out, nullptr, nullptr, nullptr, nullptr,
      nullptr, nullptr);
  silu_sh<<<dim3((unsigned)(((size_t)Tc * SH) / 2048)), 256, 0, stream>>>(
      sgu_out, hs_b);

  // sparse MoE: fused w1|w3 grouped gather GEMM, silu in-place, w2
  gemm_bt<5><<<dim3(2048 / 128, MAX_TILES), 256, 0, stream>>>(
      hf_b, w13_b, Tc, 2048, Dc, a13_c, nullptr, nullptr, nullptr, nullptr,
      meta, etok);
  silu_moe<<<dim3((unsigned)(((size_t)MAX_TILES * 128 * 1024) / 2048)), 256, 0,
             stream>>>(a13_c, b1, b3, rexp);
  gemm_bt<6><<<dim3(Dc / 128, MAX_TILES), 256, 0, stream>>>(
      a13_c, w2_b, /*lda=*/2048, Dc, 1024, eo_c, nullptr, nullptr, nullptr,
      b2, meta, etok);
  combine_router<<<Tc, 128, 0, stream>>>(eo_c, topk_e, topk_w, pos_of, meta,
                                         router);

  // final: out = x2 + router + hs @ sdw^T
  gemm_bt<4><<<dim3(Dc / 128, Tc / 128), 256, 0, stream>>>(
      hs_b, sdw_b, Tc, Dc, SH, nullptr, out, x2, router, nullptr, nullptr,
      nullptr);
}

// Round 4
// 508.028 us; speedup vs baseline: 2.4643x; 1.1062x over previous
//
#include <hip/hip_runtime.h>

// ---------------------------------------------------------------------------
// TransformerBlock on MI355X (gfx950), round 4:
//  - atomic-free MoE routing: gate computes top-2 only; a single-block
//    ballot/popcount scatter kernel assigns deterministic positions
//    (kills the 102us atomic-contention stall in gate_topk)
//  - attention: swapped QK^T, in-register P, permuted k-slots
//  - fused QKV / sg|su / w1|w3 GEMMs
// ---------------------------------------------------------------------------

typedef unsigned short u16;
typedef __attribute__((ext_vector_type(8))) short bh8;   // 8 x bf16
typedef __attribute__((ext_vector_type(4))) short sh4;   // 4 x bf16
typedef __attribute__((ext_vector_type(4))) float fv4;
typedef __attribute__((ext_vector_type(4))) unsigned uv4;
typedef __attribute__((ext_vector_type(2))) int iv2;

#define LOG2E 1.4426950408889634f
#define MAX_TILES 71

__device__ __forceinline__ float b2f(u16 u) {
  return __builtin_bit_cast(float, ((unsigned)u) << 16);
}
__device__ __forceinline__ u16 f2b(float f) {
  unsigned x = __builtin_bit_cast(unsigned, f);
  return (u16)((x + 0x7fffu + ((x >> 16) & 1u)) >> 16);  // RNE
}
__device__ __forceinline__ fv4 mfma16(bh8 a, bh8 b, fv4 c) {
  return __builtin_amdgcn_mfma_f32_16x16x32_bf16(a, b, c, 0, 0, 0);
}
__device__ __forceinline__ unsigned cvtpk(float lo, float hi) {
  unsigned r;
  asm("v_cvt_pk_bf16_f32 %0, %1, %2" : "=v"(r) : "v"(lo), "v"(hi));
  return r;
}

#define GLD16(g, l)                                                        \
  __builtin_amdgcn_global_load_lds(                                        \
      (const __attribute__((address_space(1))) void*)(g),                  \
      (__attribute__((address_space(3))) void*)(l), 16, 0, 0)

// Read one MFMA fragment (16B) from a [rows][64] bf16 LDS tile whose rows are
// 128B and whose 16B blocks are XOR-swizzled by (row&7).
__device__ __forceinline__ bh8 lds_frag(const u16* base, int row, int b8) {
  int off = row * 128 + ((b8 * 16) ^ ((row & 7) << 4));
  return *(const bh8*)((const char*)base + off);
}

// ---------------------------------------------------------------------------
// Generic GEMM: C[M,N] = A[M,K] (bf16) @ B[N,K]^T (bf16), f32 accumulate.
// MODE 0: Cb = bf16(gemm)
// MODE 1: Cf = add1 + gemm
// MODE 4: Cf = add1 + add2 + gemm                 (final output)
// MODE 5: gather-A grouped MoE (w1|w3): A rows via expert token list.
// MODE 6: compact-A grouped MoE (w2): lda passed via M; Cb = bf16(gemm+bias_e)
// ---------------------------------------------------------------------------
template <int MODE>
__global__ __launch_bounds__(256) void gemm_bt(
    const u16* __restrict__ A, const u16* __restrict__ B, int M, int N, int K,
    u16* __restrict__ Cb, float* __restrict__ Cf,
    const float* __restrict__ add1, const float* __restrict__ add2,
    const float* __restrict__ bias, const int* __restrict__ tmeta,
    const int* __restrict__ etok) {
  __shared__ u16 As[128 * 64];
  __shared__ u16 Bs[128 * 64];
  const int lane = threadIdx.x & 63;
  const int wid = threadIdx.x >> 6;
  const int wr = wid >> 1, wc = wid & 1;
  const int n0 = blockIdx.x * 128;
  const int rr = lane >> 3;
  const int b8s = (lane & 7) ^ rr;
  const int ldA = (MODE == 6) ? M : K;

  int m0 = 0, e = 0, m0l = 0, cnt = 0, row0 = 0;
  const u16* Bp = B;
  if constexpr (MODE == 5 || MODE == 6) {
    int tile = blockIdx.y;
    if (tile >= tmeta[0]) return;
    e = tmeta[16 + tile * 4];
    m0l = tmeta[17 + tile * 4];
    cnt = tmeta[18 + tile * 4];
    row0 = tmeta[19 + tile * 4];
    Bp = B + (size_t)e * N * K;
  } else {
    m0 = blockIdx.y * 128;
  }

  const u16* Arow[4];
  const u16* Brow[4];
#pragma unroll
  for (int i = 0; i < 4; ++i) {
    int c = wid * 4 + i;
    int row = c * 8 + rr;
    if constexpr (MODE == 5) {
      int li = m0l + row;
      li = li < cnt ? li : cnt - 1;
      int tok = etok[e * 4096 + li];
      Arow[i] = A + (size_t)tok * ldA + b8s * 8;
    } else if constexpr (MODE == 6) {
      Arow[i] = A + (size_t)(row0 + row) * ldA + b8s * 8;
    } else {
      Arow[i] = A + (size_t)(m0 + row) * ldA + b8s * 8;
    }
    Brow[i] = Bp + (size_t)(n0 + row) * K + b8s * 8;
  }

  fv4 acc[4][4] = {};
  for (int k0 = 0; k0 < K; k0 += 64) {
    __syncthreads();
#pragma unroll
    for (int i = 0; i < 4; ++i) {
      int c = wid * 4 + i;
      GLD16(Arow[i] + k0, &As[c * 512]);
      GLD16(Brow[i] + k0, &Bs[c * 512]);
    }
    __syncthreads();
#pragma unroll
    for (int ks = 0; ks < 2; ++ks) {
      int b8 = ks * 4 + (lane >> 4);
      bh8 af[4], bf[4];
#pragma unroll
      for (int mi = 0; mi < 4; ++mi)
        af[mi] = lds_frag(As, wr * 64 + mi * 16 + (lane & 15), b8);
#pragma unroll
      for (int ni = 0; ni < 4; ++ni)
        bf[ni] = lds_frag(Bs, wc * 64 + ni * 16 + (lane & 15), b8);
      __builtin_amdgcn_s_setprio(1);
#pragma unroll
      for (int mi = 0; mi < 4; ++mi)
#pragma unroll
        for (int ni = 0; ni < 4; ++ni)
          acc[mi][ni] = mfma16(af[mi], bf[ni], acc[mi][ni]);
      __builtin_amdgcn_s_setprio(0);
    }
  }

  const int rbase = (MODE == 5 || MODE == 6) ? row0 : m0;
  const int r0b = rbase + wr * 64 + (lane >> 4) * 4;
  const int c0b = n0 + wc * 64 + (lane & 15);
  const float* bb = nullptr;
  if constexpr (MODE == 6) bb = bias + (size_t)e * N;
#pragma unroll
  for (int mi = 0; mi < 4; ++mi) {
#pragma unroll
    for (int ni = 0; ni < 4; ++ni) {
      int c = c0b + ni * 16;
#pragma unroll
      for (int r = 0; r < 4; ++r) {
        int row = r0b + mi * 16 + r;
        size_t idx = (size_t)row * N + c;
        float v = acc[mi][ni][r];
        if constexpr (MODE == 0) Cb[idx] = f2b(v);
        else if constexpr (MODE == 1) Cf[idx] = add1[idx] + v;
        else if constexpr (MODE == 4) Cf[idx] = add1[idx] + add2[idx] + v;
        else if constexpr (MODE == 5) Cb[idx] = f2b(v);
        else Cb[idx] = f2b(v + bb[c]);
      }
    }
  }
}

// ---------------------------------------------------------------------------
// RMSNorm: f32 [T,1024] -> bf16 [T,1024], one block per token.
// ---------------------------------------------------------------------------
__global__ __launch_bounds__(256) void rmsnorm_bf16(
    const float* __restrict__ x, const float* __restrict__ w,
    u16* __restrict__ out) {
  int t = blockIdx.x;
  const float* xr = x + (size_t)t * 1024;
  fv4 v = *(const fv4*)(xr + threadIdx.x * 4);
  float ss = v[0] * v[0] + v[1] * v[1] + v[2] * v[2] + v[3] * v[3];
#pragma unroll
  for (int off = 1; off < 64; off <<= 1) ss += __shfl_xor(ss, off);
  __shared__ float red[4];
  int lane = threadIdx.x & 63, wid = threadIdx.x >> 6;
  if (lane == 0) red[wid] = ss;
  __syncthreads();
  float inv = rsqrtf((red[0] + red[1] + red[2] + red[3]) * (1.0f / 1024.f) + 1e-6f);
  u16* op = out + (size_t)t * 1024 + threadIdx.x * 4;
  const float* wp = w + threadIdx.x * 4;
#pragma unroll
  for (int i = 0; i < 4; ++i) op[i] = f2b(v[i] * inv * wp[i]);
}

// ---------------------------------------------------------------------------
// RoPE + repack from fused qkv [T,3072]:
//   q,k -> rotated [B,NH,S,64]; v -> vt [B,NH,64,S] via coalesced LDS transpose.
// Grid: (S/64, B, NH/4).
// ---------------------------------------------------------------------------
__global__ __launch_bounds__(256) void rope_repack(
    const u16* __restrict__ qkv, const float* __restrict__ fc,
    const float* __restrict__ fs, u16* __restrict__ qr, u16* __restrict__ kr,
    u16* __restrict__ vt, int S) {
  __shared__ u16 tile[64][65];
  const int s0 = blockIdx.x * 64;
  const int b = blockIdx.y;
  const int h0 = blockIdx.z * 4;
#pragma unroll 4
  for (int it = 0; it < 32; ++it) {
    int idx = threadIdx.x + it * 256;
    int tl = idx >> 7, rem = idx & 127;
    int h = h0 + (rem >> 5), i = rem & 31;
    int s = s0 + tl;
    float c = fc[s * 32 + i], sn = fs[s * 32 + i];
    size_t src = ((size_t)(b * S + s)) * 3072 + h * 64 + 2 * i;
    size_t dst = ((size_t)((b * 16 + h) * S + s)) * 64 + 2 * i;
    float a0 = b2f(qkv[src]), a1 = b2f(qkv[src + 1]);
    qr[dst] = f2b(a0 * c - a1 * sn);
    qr[dst + 1] = f2b(a0 * sn + a1 * c);
    float b0 = b2f(qkv[src + 1024]), b1 = b2f(qkv[src + 1025]);
    kr[dst] = f2b(b0 * c - b1 * sn);
    kr[dst + 1] = f2b(b0 * sn + b1 * c);
  }
  for (int hh = 0; hh < 4; ++hh) {
    int h = h0 + hh;
    __syncthreads();
    for (int cc = threadIdx.x; cc < 512; cc += 256) {
      int tl = cc >> 3, d8 = cc & 7;
      bh8 val = *(const bh8*)(qkv + ((size_t)(b * S + s0 + tl)) * 3072 + 2048 +
                              h * 64 + d8 * 8);
#pragma unroll
      for (int j = 0; j < 8; ++j) tile[tl][d8 * 8 + j] = (u16)val[j];
    }
    __syncthreads();
    for (int cc = threadIdx.x; cc < 512; cc += 256) {
      int d = cc >> 3, s8 = cc & 7;
      bh8 o;
#pragma unroll
      for (int j = 0; j < 8; ++j) o[j] = (short)tile[s8 * 8 + j][d];
      *(bh8*)(vt + ((size_t)((b * 16 + h) * 64 + d)) * S + s0 + s8 * 8) = o;
    }
  }
}

// ---------------------------------------------------------------------------
// Flash attention (causal), swapped QK^T: lane owns one q-row's scores.
// Grid: (S/64 heavy-first, B*NH). 4 waves x 16 q-rows, KVBLK=64, dbuf staging.
// ---------------------------------------------------------------------------
__global__ __launch_bounds__(256) void attn_fwd(
    const u16* __restrict__ qr, const u16* __restrict__ kr,
    const u16* __restrict__ vt, u16* __restrict__ ob, int S, int NHc) {
  __shared__ u16 Ks[2][64 * 64];
  __shared__ u16 Vs[2][64 * 64];   // V^T tile: [d][j]
  const int lane = threadIdx.x & 63;
  const int wid = threadIdx.x >> 6;
  const int g = lane >> 4;
  const int l15 = lane & 15;
  const int bh = blockIdx.y;
  const int nq = S / 64;
  const int q0 = (nq - 1 - (int)blockIdx.x) * 64;  // heavy tiles first
  const int b = bh / NHc, h = bh % NHc;
  const u16* qb = qr + (size_t)bh * S * 64;
  const u16* kb = kr + (size_t)bh * S * 64;
  const u16* vb = vt + (size_t)bh * 64 * S;
  const float SC = 0.015625f * LOG2E;  // both ref scales, log2 domain
  const int q_my = q0 + wid * 16 + l15;
  const int rr = lane >> 3;
  const int b8s = (lane & 7) ^ rr;

  bh8 qf[2];  // B-frag of Q: row q_my, d-blocks 8g and 32+8g
  {
    const u16* qp = qb + (size_t)q_my * 64 + g * 8;
    qf[0] = *(const bh8*)qp;
    qf[1] = *(const bh8*)(qp + 32);
  }
  fv4 oacc[4] = {};
  float mrow = -1e30f, lrow = 0.f;
  const int nkt = q0 / 64 + 1;

  auto stage = [&](int buf, int j0) {
#pragma unroll
    for (int i = 0; i < 2; ++i) {
      int c = wid * 2 + i;
      int row = c * 8 + rr;
      GLD16(kb + (size_t)(j0 + row) * 64 + b8s * 8, &Ks[buf][c * 512]);
      GLD16(vb + (size_t)row * S + j0 + b8s * 8, &Vs[buf][c * 512]);
    }
  };
  stage(0, 0);

  for (int kt = 0; kt < nkt; ++kt) {
    const int j0 = kt * 64;
    __syncthreads();
    if (kt + 1 < nkt) stage((kt + 1) & 1, (kt + 1) * 64);
    const u16* Kc = Ks[kt & 1];
    const u16* Vc = Vs[kt & 1];

    // S^T: st[jt][r] = score[k = j0+jt*16+4g+r][q = q_my]
    fv4 st[4] = {};
    __builtin_amdgcn_s_setprio(1);
#pragma unroll
    for (int ks = 0; ks < 2; ++ks) {
      int b8 = ks * 4 + g;
#pragma unroll
      for (int jt = 0; jt < 4; ++jt) {
        bh8 kf = lds_frag(Kc, jt * 16 + l15, b8);
        st[jt] = mfma16(kf, qf[ks], st[jt]);
      }
    }
    __builtin_amdgcn_s_setprio(0);

    float p[4][4];
    float mloc = -1e30f;
    const int jb = j0 + 4 * g;
#pragma unroll
    for (int jt = 0; jt < 4; ++jt)
#pragma unroll
      for (int r = 0; r < 4; ++r) {
        int j = jb + jt * 16 + r;
        float s = st[jt][r] * SC;
        s = (j <= q_my) ? s : -1e30f;
        p[jt][r] = s;
        mloc = fmaxf(mloc, s);
      }
    mloc = fmaxf(mloc, __shfl_xor(mloc, 16));
    mloc = fmaxf(mloc, __shfl_xor(mloc, 32));
    float mnew = fmaxf(mrow, mloc);
    float sfac = exp2f(mrow - mnew);
    mrow = mnew;
    float rsum = 0.f;
#pragma unroll
    for (int jt = 0; jt < 4; ++jt)
#pragma unroll
      for (int r = 0; r < 4; ++r) {
        float pv = exp2f(p[jt][r] - mnew);
        p[jt][r] = pv;
        rsum += pv;
      }
    rsum += __shfl_xor(rsum, 16);
    rsum += __shfl_xor(rsum, 32);
    lrow = lrow * sfac + rsum;
    // oacc[dt][r] holds q' = wid*16 + 4g + r -> fetch its sfac from lane 4g+r
    float sf[4];
#pragma unroll
    for (int r = 0; r < 4; ++r) sf[r] = __shfl(sfac, g * 4 + r);
#pragma unroll
    for (int dt = 0; dt < 4; ++dt)
#pragma unroll
      for (int r = 0; r < 4; ++r) oacc[dt][r] *= sf[r];

    // PV with permuted k-slots: mfma ks uses k = {16ks+4g+i, 16(ks+2)+4g+i}
    __builtin_amdgcn_s_setprio(1);
#pragma unroll
    for (int ks = 0; ks < 2; ++ks) {
      uv4 w;
      w[0] = cvtpk(p[ks][0], p[ks][1]);
      w[1] = cvtpk(p[ks][2], p[ks][3]);
      w[2] = cvtpk(p[ks + 2][0], p[ks + 2][1]);
      w[3] = cvtpk(p[ks + 2][2], p[ks + 2][3]);
      bh8 pa = __builtin_bit_cast(bh8, w);
      const int c0 = ks * 32 + g * 8;   // byte col of first 8B group
      const int cA = c0 & 48, cs = c0 & 8;
#pragma unroll
      for (int dt = 0; dt < 4; ++dt) {
        int row = dt * 16 + l15;
        int sw = (row & 7) << 4;
        const char* rp = (const char*)Vc + row * 128;
        sh4 lo = *(const sh4*)(rp + ((cA ^ sw) | cs));
        sh4 hi = *(const sh4*)(rp + (((cA + 64) ^ sw) | cs));
        bh8 vf = __builtin_shufflevector(lo, hi, 0, 1, 2, 3, 4, 5, 6, 7);
        oacc[dt] = mfma16(pa, vf, oacc[dt]);
      }
    }
    __builtin_amdgcn_s_setprio(0);
  }
  float lr[4];
#pragma unroll
  for (int r = 0; r < 4; ++r) lr[r] = __shfl(lrow, g * 4 + r);
#pragma unroll
  for (int dt = 0; dt < 4; ++dt)
#pragma unroll
    for (int r = 0; r < 4; ++r) {
      int row = q0 + wid * 16 + g * 4 + r;
      int col = dt * 16 + l15;
      ob[((size_t)b * S + row) * 1024 + h * 64 + col] =
          f2b(oacc[dt][r] / lr[r]);
    }
}

// ---------------------------------------------------------------------------
// MoE routing (atomic-free)
// ---------------------------------------------------------------------------
// Gate + top-2: recompute rmsnorm in f32, softmax over 8 experts; store the
// per-token top-2 experts/weights only. No atomics.
__global__ __launch_bounds__(256) void gate_topk(
    const float* __restrict__ x2, const float* __restrict__ nw,
    const float* __restrict__ gw, const float* __restrict__ gb,
    int* __restrict__ topk_e, float* __restrict__ topk_w) {
  int t = blockIdx.x * 4 + (threadIdx.x >> 6);
  int lane = threadIdx.x & 63;
  const float* xr = x2 + (size_t)t * 1024;
  float hv[16];
  float ss = 0.f;
#pragma unroll
  for (int i = 0; i < 4; ++i) {
    fv4 v = *(const fv4*)(xr + lane * 16 + i * 4);
#pragma unroll
    for (int j = 0; j < 4; ++j) {
      hv[i * 4 + j] = v[j];
      ss += v[j] * v[j];
    }
  }
#pragma unroll
  for (int off = 1; off < 64; off <<= 1) ss += __shfl_xor(ss, off);
  float inv = rsqrtf(ss * (1.0f / 1024.f) + 1e-6f);
  const fv4* nwp = (const fv4*)(nw + lane * 16);
#pragma unroll
  for (int i = 0; i < 4; ++i) {
    fv4 wv = nwp[i];
#pragma unroll
    for (int j = 0; j < 4; ++j) hv[i * 4 + j] *= inv * wv[j];
  }
  float logit[8];
#pragma unroll
  for (int e = 0; e < 8; ++e) {
    const fv4* wp = (const fv4*)(gw + (size_t)e * 1024 + lane * 16);
    float s = 0.f;
#pragma unroll
    for (int i = 0; i < 4; ++i) {
      fv4 wv = wp[i];
#pragma unroll
      for (int j = 0; j < 4; ++j) s += hv[i * 4 + j] * wv[j];
    }
    logit[e] = s;
  }
#pragma unroll
  for (int off = 1; off < 64; off <<= 1)
#pragma unroll
    for (int e = 0; e < 8; ++e) logit[e] += __shfl_xor(logit[e], off);
  if (lane == 0) {
#pragma unroll
    for (int e = 0; e < 8; ++e) logit[e] += gb[e];
    float mx = logit[0];
#pragma unroll
    for (int e = 1; e < 8; ++e) mx = fmaxf(mx, logit[e]);
    float pe[8], se = 0.f;
#pragma unroll
    for (int e = 0; e < 8; ++e) { pe[e] = __expf(logit[e] - mx); se += pe[e]; }
    float rs = 1.f / se;
#pragma unroll
    for (int e = 0; e < 8; ++e) pe[e] *= rs;
    int i0 = 0;
    float b0 = pe[0];
#pragma unroll
    for (int e = 1; e < 8; ++e)
      if (pe[e] > b0) { b0 = pe[e]; i0 = e; }
    int i1 = -1;
    float b1v = -1.f;
#pragma unroll
    for (int e = 0; e < 8; ++e)
      if (e != i0 && pe[e] > b1v) { b1v = pe[e]; i1 = e; }
    topk_e[2 * t] = i0;
    topk_e[2 * t + 1] = i1;
    topk_w[2 * t] = b0;
    topk_w[2 * t + 1] = b1v;
  }
}

// One block, 8 waves. Wave e scans all 2T entries in token order, ranking
// its matches via ballot prefix -> deterministic positions, no atomics.
__global__ __launch_bounds__(512) void scatter_tokens(
    const int* __restrict__ topk_e, int* __restrict__ counts,
    int* __restrict__ pos_of, int* __restrict__ etok, int T2) {
  const int e = threadIdx.x >> 6;
  const int lane = threadIdx.x & 63;
  int base = 0;
  for (int i0 = 0; i0 < T2; i0 += 128) {
    iv2 te = *(const iv2*)(topk_e + i0 + lane * 2);
    unsigned long long m0 = __ballot(te[0] == e);
    unsigned long long m1 = __ballot(te[1] == e);
    unsigned long long lt = (1ull << lane) - 1;
    int pre = __popcll(m0 & lt) + __popcll(m1 & lt);
    if (te[0] == e) {
      int pos = base + pre;
      etok[e * 4096 + pos] = (i0 >> 1) + lane;
      pos_of[i0 + lane * 2] = pos;
      ++pre;
    }
    if (te[1] == e) {
      int pos = base + pre;
      etok[e * 4096 + pos] = (i0 >> 1) + lane;
      pos_of[i0 + lane * 2 + 1] = pos;
    }
    base += __popcll(m0) + __popcll(m1);
  }
  if (lane == 0) counts[e] = base;
}

__global__ __launch_bounds__(256) void sched_moe(const int* __restrict__ counts,
                                                 int* __restrict__ meta,
                                                 int* __restrict__ rexp) {
  __shared__ int s_e[MAX_TILES], s_row0[MAX_TILES], s_tt, s_rb;
  if (threadIdx.x == 0) {
    int tt = 0, rb = 0;
    for (int e = 0; e < 8; ++e) {
      meta[1 + e] = rb;
      int c = counts[e];
      int nt = (c + 127) >> 7;
      for (int i = 0; i < nt; ++i) {
        meta[16 + tt * 4] = e;
        meta[17 + tt * 4] = i * 128;
        meta[18 + tt * 4] = c;
        meta[19 + tt * 4] = rb + i * 128;
        s_e[tt] = e;
        s_row0[tt] = rb + i * 128;
        ++tt;
      }
      rb += nt * 128;
    }
    meta[0] = tt;
    s_tt = tt;
    s_rb = rb;
  }
  __syncthreads();
  int tt = s_tt;
  for (int tile = 0; tile < tt; ++tile) {
    int r0 = s_row0[tile], e = s_e[tile];
    for (int j = threadIdx.x; j < 128; j += 256) rexp[r0 + j] = e;
  }
  for (int r = s_rb + threadIdx.x; r < MAX_TILES * 128; r += 256) rexp[r] = 0;
}

// silu(a13[:, c]+b1[e,c]) * (a13[:, 1024+c]+b3[e,c]) -> in-place lower half.
__global__ __launch_bounds__(256) void silu_moe(
    u16* __restrict__ a13, const float* __restrict__ b1,
    const float* __restrict__ b3, const int* __restrict__ rexp) {
  size_t i = ((size_t)blockIdx.x * 256 + threadIdx.x) * 8;
  int row = (int)(i >> 10), col = (int)(i & 1023);
  int e = rexp[row];
  const float* ba = b1 + (size_t)e * 1024 + col;
  const float* bb = b3 + (size_t)e * 1024 + col;
  u16* rp = a13 + (size_t)row * 2048 + col;
  bh8 av = *(const bh8*)rp;
  bh8 bv = *(const bh8*)(rp + 1024);
  bh8 ov;
#pragma unroll
  for (int j = 0; j < 8; ++j) {
    float x = b2f((u16)av[j]) + ba[j];
    float y = b2f((u16)bv[j]) + bb[j];
    float s = x / (1.f + __expf(-x));
    ov[j] = (short)f2b(s * y);
  }
  *(bh8*)rp = ov;
}

__global__ __launch_bounds__(128) void combine_router(
    const u16* __restrict__ eo, const int* __restrict__ topk_e,
    const float* __restrict__ topk_w, const int* __restrict__ pos_of,
    const int* __restrict__ meta, float* __restrict__ router) {
  int t = blockIdx.x;
  int c = threadIdx.x * 8;
  int e0 = topk_e[2 * t], e1 = topk_e[2 * t + 1];
  float w0 = topk_w[2 * t], w1 = topk_w[2 * t + 1];
  int r0 = meta[1 + e0] + pos_of[2 * t];
  int r1 = meta[1 + e1] + pos_of[2 * t + 1];
  bh8 v0 = *(const bh8*)(eo + (size_t)r0 * 1024 + c);
  bh8 v1 = *(const bh8*)(eo + (size_t)r1 * 1024 + c);
  float* rp = router + (size_t)t * 1024 + c;
#pragma unroll
  for (int j = 0; j < 8; ++j)
    rp[j] = w0 * b2f((u16)v0[j]) + w1 * b2f((u16)v1[j]);
}

// silu(sgu[:,c]) * sgu[:,2048+c] -> hs [T,2048]
__global__ __launch_bounds__(256) void silu_sh(const u16* __restrict__ sgu,
                                               u16* __restrict__ hs) {
  size_t i = ((size_t)blockIdx.x * 256 + threadIdx.x) * 8;
  size_t row = i >> 11, col = i & 2047;
  const u16* rp = sgu + row * 4096 + col;
  bh8 av = *(const bh8*)rp;
  bh8 bv = *(const bh8*)(rp + 2048);
  bh8 ov;
#pragma unroll
  for (int j = 0; j < 8; ++j) {
    float x = b2f((u16)av[j]);
    float y = b2f((u16)bv[j]);
    float s = x / (1.f + __expf(-x));
    ov[j] = (short)f2b(s * y);
  }
  *(bh8*)(hs + i) = ov;
}

__global__ __launch_bounds__(256) void f2b_convert(
    const float* __restrict__ src, u16* __restrict__ dst) {
  size_t i = ((size_t)blockIdx.x * 256 + threadIdx.x) * 8;
  fv4 a = *(const fv4*)(src + i);
  fv4 b = *(const fv4*)(src + i + 4);
  bh8 o;
#pragma unroll
  for (int j = 0; j < 4; ++j) o[j] = (short)f2b(a[j]);
#pragma unroll
  for (int j = 0; j < 4; ++j) o[4 + j] = (short)f2b(b[j]);
  *(bh8*)(dst + i) = o;
}

// interleave w1/w3 [E,1024,1024] f32 -> w13 [E,2048,1024] bf16 (half select)
__global__ __launch_bounds__(256) void f2b_convert_moe(
    const float* __restrict__ src, u16* __restrict__ dst, int halfoff) {
  size_t i = ((size_t)blockIdx.x * 256 + threadIdx.x) * 8;
  size_t e = i >> 20, inner = i & 1048575;
  fv4 a = *(const fv4*)(src + i);
  fv4 b = *(const fv4*)(src + i + 4);
  bh8 o;
#pragma unroll
  for (int j = 0; j < 4; ++j) o[j] = (short)f2b(a[j]);
#pragma unroll
  for (int j = 0; j < 4; ++j) o[4 + j] = (short)f2b(b[j]);
  *(bh8*)(dst + e * 2097152 + halfoff + inner) = o;
}

// ---------------------------------------------------------------------------
extern "C" void kernel_launch(void* const* d_in, const int* in_sizes, int n_in,
                              void* d_out, int out_size, void* d_ws,
                              size_t ws_size, hipStream_t stream) {
  (void)in_sizes; (void)n_in; (void)out_size; (void)ws_size;
  const int Sc = 2048, Dc = 1024, NHc = 16, Tc = 4096, SH = 2048;

  const float* x   = (const float*)d_in[0];
  const float* fc  = (const float*)d_in[1];
  const float* fs  = (const float*)d_in[2];
  const float* wq  = (const float*)d_in[4];
  const float* wk  = (const float*)d_in[5];
  const float* wv  = (const float*)d_in[6];
  const float* wo  = (const float*)d_in[7];
  const float* anw = (const float*)d_in[8];
  const float* fnw = (const float*)d_in[9];
  const float* gw  = (const float*)d_in[10];
  const float* gb  = (const float*)d_in[11];
  const float* w1  = (const float*)d_in[12];
  const float* b1  = (const float*)d_in[13];
  const float* w2  = (const float*)d_in[14];
  const float* b2  = (const float*)d_in[15];
  const float* w3  = (const float*)d_in[16];
  const float* b3  = (const float*)d_in[17];
  const float* sgw = (const float*)d_in[18];
  const float* suw = (const float*)d_in[19];
  const float* sdw = (const float*)d_in[20];
  float* out = (float*)d_out;

  char* base = (char*)d_ws;
  size_t off = 0;
  auto alloc = [&](size_t bytes) -> void* {
    void* p = base + off;
    off += (bytes + 255) & ~(size_t)255;
    return p;
  };
  // weights: wqkv+wo FIRST (their region is reused as hf_b after wo-gemm)
  u16* wqkv_b = (u16*)alloc(2ull * 3072 * 1024);   // 6.29 MB
  u16* wo_b   = (u16*)alloc(2ull * 1024 * 1024);   // 2.10 MB
  u16* sgu_b  = (u16*)alloc(2ull * 4096 * 1024);   // 8.39 MB
  u16* sdw_b  = (u16*)alloc(2ull * 1024 * 2048);   // 4.19 MB
  u16* w13_b  = (u16*)alloc(2ull * 8 * 2048 * 1024); // 33.6 MB
  u16* w2_b   = (u16*)alloc(2ull * 8 * 1024 * 1024); // 16.8 MB
  // region A: qkv_out (25.2) -> sgu_out (33.6) -> eo (18.6)
  char* regA = (char*)alloc(2ull * Tc * 4096);
  // region B: h_b/qr/kr/vt/o_b (33.6) -> a13 (37.2) -> router (16.8)
  char* regB = (char*)alloc(2ull * (size_t)MAX_TILES * 128 * 2048);
  float* x2  = (float*)alloc(4ull * Tc * Dc);      // 16.8 MB
  u16* hs_b  = (u16*)alloc(2ull * Tc * SH);        // 16.8 MB
  int* counts = (int*)alloc(8 * 4);
  int* topk_e = (int*)alloc(2ull * Tc * 4);
  float* topk_w = (float*)alloc(2ull * Tc * 4);
  int* pos_of = (int*)alloc(2ull * Tc * 4);
  int* etok = (int*)alloc(8ull * 4096 * 4);
  int* meta = (int*)alloc(512 * 4);
  int* rexp = (int*)alloc((size_t)MAX_TILES * 128 * 4);

  u16* qkv_out = (u16*)regA;
  u16* sgu_out = (u16*)regA;
  u16* eo_c    = (u16*)regA;
  u16* h_b  = (u16*)regB;
  u16* qr   = (u16*)regB;
  u16* kr   = (u16*)(regB + 2ull * Tc * Dc);
  u16* vt_  = (u16*)(regB + 4ull * Tc * Dc);
  u16* o_b  = (u16*)(regB + 6ull * Tc * Dc);
  u16* a13_c = (u16*)regB;
  float* router = (float*)regB;
  u16* hf_b = wqkv_b;  // overlays wqkv+wo after attention branch done

  auto conv = [&](const float* s, u16* d, size_t n) {
    f2b_convert<<<dim3((unsigned)(n / 2048)), 256, 0, stream>>>(s, d);
  };
  conv(wq, wqkv_b, (size_t)Dc * Dc);
  conv(wk, wqkv_b + 1048576, (size_t)Dc * Dc);
  conv(wv, wqkv_b + 2097152, (size_t)Dc * Dc);
  conv(wo, wo_b, (size_t)Dc * Dc);
  conv(sgw, sgu_b, (size_t)SH * Dc);
  conv(suw, sgu_b + 2097152, (size_t)SH * Dc);
  conv(sdw, sdw_b, (size_t)Dc * SH);
  conv(w2, w2_b, 8ull * 1024 * 1024);
  f2b_convert_moe<<<4096, 256, 0, stream>>>(w1, w13_b, 0);
  f2b_convert_moe<<<4096, 256, 0, stream>>>(w3, w13_b, 1048576);

  // ---- attention branch ----
  rmsnorm_bf16<<<Tc, 256, 0, stream>>>(x, anw, h_b);
  gemm_bt<0><<<dim3(3072 / 128, Tc / 128), 256, 0, stream>>>(
      h_b, wqkv_b, Tc, 3072, Dc, qkv_out, nullptr, nullptr, nullptr, nullptr,
      nullptr, nullptr);
  rope_repack<<<dim3(Sc / 64, 2, 4), 256, 0, stream>>>(qkv_out, fc, fs, qr, kr,
                                                       vt_, Sc);
  attn_fwd<<<dim3(Sc / 64, 2 * NHc), 256, 0, stream>>>(qr, kr, vt_, o_b, Sc,
                                                       NHc);
  gemm_bt<1><<<dim3(Dc / 128, Tc / 128), 256, 0, stream>>>(
      o_b, wo_b, Tc, Dc, Dc, nullptr, x2, x, nullptr, nullptr, nullptr,
      nullptr);

  // ---- ffn branch ----
  rmsnorm_bf16<<<Tc, 256, 0, stream>>>(x2, fnw, hf_b);
  gate_topk<<<Tc / 4, 256, 0, stream>>>(x2, fnw, gw, gb, topk_e, topk_w);
  scatter_tokens<<<1, 512, 0, stream>>>(topk_e, counts, pos_of, etok, 2 * Tc);
  sched_moe<<<1, 256, 0, stream>>>(counts, meta, rexp);

  // shared expert: fused gate|up GEMM then silu
  gemm_bt<0><<<dim3(4096 / 128, Tc / 128), 256, 0, stream>>>(
      hf_b, sgu_b, Tc, 4096, Dc, sgu_out, nullptr, nullptr, nullptr, nullptr,
      nullptr, nullptr);
  silu_sh<<<dim3((unsigned)(((size_t)Tc * SH) / 2048)), 256, 0, stream>>>(
      sgu_out, hs_b);

  // sparse MoE: fused w1|w3 grouped gather GEMM, silu in-place, w2
  gemm_bt<5><<<dim3(2048 / 128, MAX_TILES), 256, 0, stream>>>(
      hf_b, w13_b, Tc, 2048, Dc, a13_c, nullptr, nullptr, nullptr, nullptr,
      meta, etok);
  silu_moe<<<dim3((unsigned)(((size_t)MAX_TILES * 128 * 1024) / 2048)), 256, 0,
             stream>>>(a13_c, b1, b3, rexp);
  gemm_bt<6><<<dim3(Dc / 128, MAX_TILES), 256, 0, stream>>>(
      a13_c, w2_b, /*lda=*/2048, Dc, 1024, eo_c, nullptr, nullptr, nullptr,
      b2, meta, etok);
  combine_router<<<Tc, 128, 0, stream>>>(eo_c, topk_e, topk_w, pos_of, meta,
                                         router);

  // final: out = x2 + router + hs @ sdw^T
  gemm_bt<4><<<dim3(Dc / 128, Tc / 128), 256, 0, stream>>>(
      hs_b, sdw_b, Tc, Dc, SH, nullptr, out, x2, router, nullptr, nullptr,
      nullptr);
}

// Round 5
// 444.307 us; speedup vs baseline: 2.8177x; 1.1434x over previous
//
#include <hip/hip_runtime.h>

// ---------------------------------------------------------------------------
// TransformerBlock on MI355X (gfx950), round 5:
//  - attention: paired q-tiles (balanced causal blocks, shared K/V staging),
//    permuted-V layout (PV reads = single swizzled ds_read_b128, no bank
//    conflicts), defer-max, interior-tile mask fast path, head-major grid
//  - BM=64 GEMM tiles for the N=1024 GEMMs (2 blocks/CU instead of 1)
//  - atomic-free MoE routing, grouped sparse MoE, fused QKV/sgu/w13 GEMMs
// ---------------------------------------------------------------------------

typedef unsigned short u16;
typedef __attribute__((ext_vector_type(8))) short bh8;   // 8 x bf16
typedef __attribute__((ext_vector_type(4))) float fv4;
typedef __attribute__((ext_vector_type(4))) unsigned uv4;
typedef __attribute__((ext_vector_type(2))) int iv2;

#define LOG2E 1.4426950408889634f
#define MAX_TILES 71

__device__ __forceinline__ float b2f(u16 u) {
  return __builtin_bit_cast(float, ((unsigned)u) << 16);
}
__device__ __forceinline__ u16 f2b(float f) {
  unsigned x = __builtin_bit_cast(unsigned, f);
  return (u16)((x + 0x7fffu + ((x >> 16) & 1u)) >> 16);  // RNE
}
__device__ __forceinline__ fv4 mfma16(bh8 a, bh8 b, fv4 c) {
  return __builtin_amdgcn_mfma_f32_16x16x32_bf16(a, b, c, 0, 0, 0);
}
__device__ __forceinline__ unsigned cvtpk(float lo, float hi) {
  unsigned r;
  asm("v_cvt_pk_bf16_f32 %0, %1, %2" : "=v"(r) : "v"(lo), "v"(hi));
  return r;
}

#define GLD16(g, l)                                                        \
  __builtin_amdgcn_global_load_lds(                                        \
      (const __attribute__((address_space(1))) void*)(g),                  \
      (__attribute__((address_space(3))) void*)(l), 16, 0, 0)

// Read one MFMA fragment (16B) from a [rows][64] bf16 LDS tile whose rows are
// 128B and whose 16B blocks are XOR-swizzled by (row&7).
__device__ __forceinline__ bh8 lds_frag(const u16* base, int row, int b8) {
  int off = row * 128 + ((b8 * 16) ^ ((row & 7) << 4));
  return *(const bh8*)((const char*)base + off);
}

// ---------------------------------------------------------------------------
// Generic GEMM: C[M,N] = A[M,K] (bf16) @ B[N,K]^T (bf16), f32 accumulate.
// TM: A-tile rows (128 or 64). B-tile is always 128 cols.
// MODE 0: Cb = bf16(gemm)
// MODE 1: Cf = add1 + gemm
// MODE 4: Cf = add1 + add2 + gemm                 (final output)
// MODE 5: gather-A grouped MoE (w1|w3): A rows via expert token list.
// MODE 6: compact-A grouped MoE (w2): lda passed via M; Cb = bf16(gemm+bias_e)
// ---------------------------------------------------------------------------
template <int MODE, int TM = 128>
__global__ __launch_bounds__(256) void gemm_bt(
    const u16* __restrict__ A, const u16* __restrict__ B, int M, int N, int K,
    u16* __restrict__ Cb, float* __restrict__ Cf,
    const float* __restrict__ add1, const float* __restrict__ add2,
    const float* __restrict__ bias, const int* __restrict__ tmeta,
    const int* __restrict__ etok) {
  constexpr int MR = TM / 32;  // M-frags per wave: 128->4, 64->2
  __shared__ u16 As[TM * 64];
  __shared__ u16 Bs[128 * 64];
  const int lane = threadIdx.x & 63;
  const int wid = threadIdx.x >> 6;
  const int wr = wid >> 1, wc = wid & 1;
  const int n0 = blockIdx.x * 128;
  const int rr = lane >> 3;
  const int b8s = (lane & 7) ^ rr;
  const int ldA = (MODE == 6) ? M : K;

  int m0 = 0, e = 0, m0l = 0, cnt = 0, row0 = 0;
  const u16* Bp = B;
  if constexpr (MODE == 5 || MODE == 6) {
    int tile = blockIdx.y;
    if (tile >= tmeta[0]) return;
    e = tmeta[16 + tile * 4];
    m0l = tmeta[17 + tile * 4];
    cnt = tmeta[18 + tile * 4];
    row0 = tmeta[19 + tile * 4];
    Bp = B + (size_t)e * N * K;
  } else {
    m0 = blockIdx.y * TM;
  }

  const u16* Arow[MR];
  const u16* Brow[4];
#pragma unroll
  for (int i = 0; i < MR; ++i) {
    int c = wid * MR + i;
    int row = c * 8 + rr;
    if constexpr (MODE == 5) {
      int li = m0l + row;
      li = li < cnt ? li : cnt - 1;
      int tok = etok[e * 4096 + li];
      Arow[i] = A + (size_t)tok * ldA + b8s * 8;
    } else if constexpr (MODE == 6) {
      Arow[i] = A + (size_t)(row0 + row) * ldA + b8s * 8;
    } else {
      Arow[i] = A + (size_t)(m0 + row) * ldA + b8s * 8;
    }
  }
#pragma unroll
  for (int i = 0; i < 4; ++i)
    Brow[i] = Bp + (size_t)(n0 + (wid * 4 + i) * 8 + rr) * K + b8s * 8;

  fv4 acc[MR][4] = {};
  for (int k0 = 0; k0 < K; k0 += 64) {
    __syncthreads();
#pragma unroll
    for (int i = 0; i < MR; ++i)
      GLD16(Arow[i] + k0, &As[(wid * MR + i) * 512]);
#pragma unroll
    for (int i = 0; i < 4; ++i)
      GLD16(Brow[i] + k0, &Bs[(wid * 4 + i) * 512]);
    __syncthreads();
#pragma unroll
    for (int ks = 0; ks < 2; ++ks) {
      int b8 = ks * 4 + (lane >> 4);
      bh8 af[MR], bf[4];
#pragma unroll
      for (int mi = 0; mi < MR; ++mi)
        af[mi] = lds_frag(As, wr * (16 * MR) + mi * 16 + (lane & 15), b8);
#pragma unroll
      for (int ni = 0; ni < 4; ++ni)
        bf[ni] = lds_frag(Bs, wc * 64 + ni * 16 + (lane & 15), b8);
      __builtin_amdgcn_s_setprio(1);
#pragma unroll
      for (int mi = 0; mi < MR; ++mi)
#pragma unroll
        for (int ni = 0; ni < 4; ++ni)
          acc[mi][ni] = mfma16(af[mi], bf[ni], acc[mi][ni]);
      __builtin_amdgcn_s_setprio(0);
    }
  }

  const int rbase = (MODE == 5 || MODE == 6) ? row0 : m0;
  const int r0b = rbase + wr * (16 * MR) + (lane >> 4) * 4;
  const int c0b = n0 + wc * 64 + (lane & 15);
  const float* bb = nullptr;
  if constexpr (MODE == 6) bb = bias + (size_t)e * N;
#pragma unroll
  for (int mi = 0; mi < MR; ++mi) {
#pragma unroll
    for (int ni = 0; ni < 4; ++ni) {
      int c = c0b + ni * 16;
#pragma unroll
      for (int r = 0; r < 4; ++r) {
        int row = r0b + mi * 16 + r;
        size_t idx = (size_t)row * N + c;
        float v = acc[mi][ni][r];
        if constexpr (MODE == 0) Cb[idx] = f2b(v);
        else if constexpr (MODE == 1) Cf[idx] = add1[idx] + v;
        else if constexpr (MODE == 4) Cf[idx] = add1[idx] + add2[idx] + v;
        else if constexpr (MODE == 5) Cb[idx] = f2b(v);
        else Cb[idx] = f2b(v + bb[c]);
      }
    }
  }
}

// ---------------------------------------------------------------------------
// RMSNorm: f32 [T,1024] -> bf16 [T,1024], one block per token.
// ---------------------------------------------------------------------------
__global__ __launch_bounds__(256) void rmsnorm_bf16(
    const float* __restrict__ x, const float* __restrict__ w,
    u16* __restrict__ out) {
  int t = blockIdx.x;
  const float* xr = x + (size_t)t * 1024;
  fv4 v = *(const fv4*)(xr + threadIdx.x * 4);
  float ss = v[0] * v[0] + v[1] * v[1] + v[2] * v[2] + v[3] * v[3];
#pragma unroll
  for (int off = 1; off < 64; off <<= 1) ss += __shfl_xor(ss, off);
  __shared__ float red[4];
  int lane = threadIdx.x & 63, wid = threadIdx.x >> 6;
  if (lane == 0) red[wid] = ss;
  __syncthreads();
  float inv = rsqrtf((red[0] + red[1] + red[2] + red[3]) * (1.0f / 1024.f) + 1e-6f);
  u16* op = out + (size_t)t * 1024 + threadIdx.x * 4;
  const float* wp = w + threadIdx.x * 4;
#pragma unroll
  for (int i = 0; i < 4; ++i) op[i] = f2b(v[i] * inv * wp[i]);
}

// ---------------------------------------------------------------------------
// RoPE + repack from fused qkv [T,3072]:
//   q,k -> rotated [B,NH,S,64]; v -> vt [B,NH,64,S] (transposed AND column-
//   permuted within each 64-block so attn PV B-frags are single b128 reads:
//   physical group pg=4ks+g holds logical j {16ks+4g+r, 16ks+32+4g+r}).
// Grid: (S/64, B, NH/4).
// ---------------------------------------------------------------------------
__global__ __launch_bounds__(256) void rope_repack(
    const u16* __restrict__ qkv, const float* __restrict__ fc,
    const float* __restrict__ fs, u16* __restrict__ qr, u16* __restrict__ kr,
    u16* __restrict__ vt, int S) {
  __shared__ u16 tile[64][65];
  const int s0 = blockIdx.x * 64;
  const int b = blockIdx.y;
  const int h0 = blockIdx.z * 4;
#pragma unroll 4
  for (int it = 0; it < 32; ++it) {
    int idx = threadIdx.x + it * 256;
    int tl = idx >> 7, rem = idx & 127;
    int h = h0 + (rem >> 5), i = rem & 31;
    int s = s0 + tl;
    float c = fc[s * 32 + i], sn = fs[s * 32 + i];
    size_t src = ((size_t)(b * S + s)) * 3072 + h * 64 + 2 * i;
    size_t dst = ((size_t)((b * 16 + h) * S + s)) * 64 + 2 * i;
    float a0 = b2f(qkv[src]), a1 = b2f(qkv[src + 1]);
    qr[dst] = f2b(a0 * c - a1 * sn);
    qr[dst + 1] = f2b(a0 * sn + a1 * c);
    float b0 = b2f(qkv[src + 1024]), b1 = b2f(qkv[src + 1025]);
    kr[dst] = f2b(b0 * c - b1 * sn);
    kr[dst + 1] = f2b(b0 * sn + b1 * c);
  }
  for (int hh = 0; hh < 4; ++hh) {
    int h = h0 + hh;
    __syncthreads();
    for (int cc = threadIdx.x; cc < 512; cc += 256) {
      int tl = cc >> 3, d8 = cc & 7;
      bh8 val = *(const bh8*)(qkv + ((size_t)(b * S + s0 + tl)) * 3072 + 2048 +
                              h * 64 + d8 * 8);
#pragma unroll
      for (int j = 0; j < 8; ++j) tile[tl][d8 * 8 + j] = (u16)val[j];
    }
    __syncthreads();
    for (int cc = threadIdx.x; cc < 512; cc += 256) {
      int d = cc >> 3, pg = cc & 7;
      int sbase = 16 * (pg >> 2) + 4 * (pg & 3);
      bh8 o;
#pragma unroll
      for (int j = 0; j < 8; ++j)
        o[j] = (short)tile[sbase + (j & 3) + ((j >> 2) << 5)][d];
      *(bh8*)(vt + ((size_t)((b * 16 + h) * 64 + d)) * S + s0 + pg * 8) = o;
    }
  }
}

// ---------------------------------------------------------------------------
// Flash attention (causal), paired q-tiles: block handles q-tile ia (light)
// and nq-1-ia (heavy) -> every block does exactly nq+1 tile-units; shared
// K/V staging for the overlap. Swapped QK^T, in-register P, permuted-V
// single-b128 PV reads, defer-max, interior-tile mask fast path.
// Grid: (B*NH, nq/2) -- head-major so one head's blocks share an XCD L2.
// ---------------------------------------------------------------------------
__global__ __launch_bounds__(256) void attn_fwd(
    const u16* __restrict__ qr, const u16* __restrict__ kr,
    const u16* __restrict__ vt, u16* __restrict__ ob, int S, int NHc) {
  __shared__ u16 Ks[2][64 * 64];
  __shared__ u16 Vs[2][64 * 64];   // V^T tile, column-permuted
  const int lane = threadIdx.x & 63;
  const int wid = threadIdx.x >> 6;
  const int g = lane >> 4;
  const int l15 = lane & 15;
  const int bh = blockIdx.x;
  const int ia = blockIdx.y;
  const int nq = S / 64;
  const int qa0 = ia * 64;                 // light q-tile
  const int qb0 = (nq - 1 - ia) * 64;      // heavy q-tile
  const int b = bh / NHc, h = bh % NHc;
  const u16* qbase = qr + (size_t)bh * S * 64;
  const u16* kb = kr + (size_t)bh * S * 64;
  const u16* vb = vt + (size_t)bh * 64 * S;
  const float SC = 0.015625f * LOG2E;  // both ref scales, log2 domain
  const int rr = lane >> 3;
  const int b8s = (lane & 7) ^ rr;

  bh8 qfA[2], qfB[2];
  {
    const u16* qp = qbase + (size_t)(qa0 + wid * 16 + l15) * 64 + g * 8;
    qfA[0] = *(const bh8*)qp;
    qfA[1] = *(const bh8*)(qp + 32);
    qp = qbase + (size_t)(qb0 + wid * 16 + l15) * 64 + g * 8;
    qfB[0] = *(const bh8*)qp;
    qfB[1] = *(const bh8*)(qp + 32);
  }
  fv4 oaccA[4] = {}, oaccB[4] = {};
  float mA = -1e30f, lA = 0.f, mB = -1e30f, lB = 0.f;
  const int nktB = nq - ia;

  auto stage = [&](int buf, int j0) {
#pragma unroll
    for (int i = 0; i < 2; ++i) {
      int c = wid * 2 + i;
      int row = c * 8 + rr;
      GLD16(kb + (size_t)(j0 + row) * 64 + b8s * 8, &Ks[buf][c * 512]);
      GLD16(vb + (size_t)row * S + j0 + b8s * 8, &Vs[buf][c * 512]);
    }
  };
  stage(0, 0);

  auto process = [&](const u16* Kc, const u16* Vc, int j0, int q0x, bh8* qf,
                     fv4* oacc, float& mrow, float& lrow) {
    const int q_my = q0x + wid * 16 + l15;
    fv4 st[4] = {};
    __builtin_amdgcn_s_setprio(1);
#pragma unroll
    for (int ks = 0; ks < 2; ++ks) {
      int b8 = ks * 4 + g;
#pragma unroll
      for (int jt = 0; jt < 4; ++jt) {
        bh8 kf = lds_frag(Kc, jt * 16 + l15, b8);
        st[jt] = mfma16(kf, qf[ks], st[jt]);
      }
    }
    __builtin_amdgcn_s_setprio(0);

    float p[4][4];
    float mloc = -1e30f;
    const int jb = j0 + 4 * g;
    if (j0 + 63 > q0x + wid * 16) {   // diagonal tile: apply causal mask
#pragma unroll
      for (int jt = 0; jt < 4; ++jt)
#pragma unroll
        for (int r = 0; r < 4; ++r) {
          int j = jb + jt * 16 + r;
          float s = st[jt][r] * SC;
          s = (j <= q_my) ? s : -1e30f;
          p[jt][r] = s;
          mloc = fmaxf(mloc, s);
        }
    } else {                          // interior: fully visible
#pragma unroll
      for (int jt = 0; jt < 4; ++jt)
#pragma unroll
        for (int r = 0; r < 4; ++r) {
          float s = st[jt][r] * SC;
          p[jt][r] = s;
          mloc = fmaxf(mloc, s);
        }
    }
    mloc = fmaxf(mloc, __shfl_xor(mloc, 16));
    mloc = fmaxf(mloc, __shfl_xor(mloc, 32));
    bool defer = __all(mloc <= mrow + 8.f);   // T13: skip rescale
    float sfac = 1.f;
    if (!defer) {
      float mnew = fmaxf(mrow, mloc);
      sfac = exp2f(mrow - mnew);
      mrow = mnew;
    }
    float rsum = 0.f;
#pragma unroll
    for (int jt = 0; jt < 4; ++jt)
#pragma unroll
      for (int r = 0; r < 4; ++r) {
        float pv = exp2f(p[jt][r] - mrow);
        p[jt][r] = pv;
        rsum += pv;
      }
    rsum += __shfl_xor(rsum, 16);
    rsum += __shfl_xor(rsum, 32);
    lrow = lrow * sfac + rsum;
    if (!defer) {
      float sf[4];
#pragma unroll
      for (int r = 0; r < 4; ++r) sf[r] = __shfl(sfac, g * 4 + r);
#pragma unroll
      for (int dt = 0; dt < 4; ++dt)
#pragma unroll
        for (int r = 0; r < 4; ++r) oacc[dt][r] *= sf[r];
    }

    // PV: pa slot (g,i) <-> logical j = 16ks + 32*(i>=4) + 4g + (i&3),
    // matching Vs' physical column permutation -> single b128 frag reads.
    __builtin_amdgcn_s_setprio(1);
#pragma unroll
    for (int ks = 0; ks < 2; ++ks) {
      uv4 w;
      w[0] = cvtpk(p[ks][0], p[ks][1]);
      w[1] = cvtpk(p[ks][2], p[ks][3]);
      w[2] = cvtpk(p[ks + 2][0], p[ks + 2][1]);
      w[3] = cvtpk(p[ks + 2][2], p[ks + 2][3]);
      bh8 pa = __builtin_bit_cast(bh8, w);
#pragma unroll
      for (int dt = 0; dt < 4; ++dt) {
        bh8 vf = lds_frag(Vc, dt * 16 + l15, ks * 4 + g);
        oacc[dt] = mfma16(pa, vf, oacc[dt]);
      }
    }
    __builtin_amdgcn_s_setprio(0);
  };

  for (int kt = 0; kt < nktB; ++kt) {
    const int j0 = kt * 64;
    __syncthreads();
    if (kt + 1 < nktB) stage((kt + 1) & 1, (kt + 1) * 64);
    const u16* Kc = Ks[kt & 1];
    const u16* Vc = Vs[kt & 1];
    process(Kc, Vc, j0, qb0, qfB, oaccB, mB, lB);
    if (kt <= ia) process(Kc, Vc, j0, qa0, qfA, oaccA, mA, lA);
  }

  auto wout = [&](fv4* oacc, float lrow, int q0x) {
    float lr[4];
#pragma unroll
    for (int r = 0; r < 4; ++r) lr[r] = __shfl(lrow, g * 4 + r);
#pragma unroll
    for (int dt = 0; dt < 4; ++dt)
#pragma unroll
      for (int r = 0; r < 4; ++r) {
        int row = q0x + wid * 16 + g * 4 + r;
        int col = dt * 16 + l15;
        ob[((size_t)b * S + row) * 1024 + h * 64 + col] =
            f2b(oacc[dt][r] / lr[r]);
      }
  };
  wout(oaccA, lA, qa0);
  wout(oaccB, lB, qb0);
}

// ---------------------------------------------------------------------------
// MoE routing (atomic-free)
// ---------------------------------------------------------------------------
__global__ __launch_bounds__(256) void gate_topk(
    const float* __restrict__ x2, const float* __restrict__ nw,
    const float* __restrict__ gw, const float* __restrict__ gb,
    int* __restrict__ topk_e, float* __restrict__ topk_w) {
  int t = blockIdx.x * 4 + (threadIdx.x >> 6);
  int lane = threadIdx.x & 63;
  const float* xr = x2 + (size_t)t * 1024;
  float hv[16];
  float ss = 0.f;
#pragma unroll
  for (int i = 0; i < 4; ++i) {
    fv4 v = *(const fv4*)(xr + lane * 16 + i * 4);
#pragma unroll
    for (int j = 0; j < 4; ++j) {
      hv[i * 4 + j] = v[j];
      ss += v[j] * v[j];
    }
  }
#pragma unroll
  for (int off = 1; off < 64; off <<= 1) ss += __shfl_xor(ss, off);
  float inv = rsqrtf(ss * (1.0f / 1024.f) + 1e-6f);
  const fv4* nwp = (const fv4*)(nw + lane * 16);
#pragma unroll
  for (int i = 0; i < 4; ++i) {
    fv4 wv = nwp[i];
#pragma unroll
    for (int j = 0; j < 4; ++j) hv[i * 4 + j] *= inv * wv[j];
  }
  float logit[8];
#pragma unroll
  for (int e = 0; e < 8; ++e) {
    const fv4* wp = (const fv4*)(gw + (size_t)e * 1024 + lane * 16);
    float s = 0.f;
#pragma unroll
    for (int i = 0; i < 4; ++i) {
      fv4 wv = wp[i];
#pragma unroll
      for (int j = 0; j < 4; ++j) s += hv[i * 4 + j] * wv[j];
    }
    logit[e] = s;
  }
#pragma unroll
  for (int off = 1; off < 64; off <<= 1)
#pragma unroll
    for (int e = 0; e < 8; ++e) logit[e] += __shfl_xor(logit[e], off);
  if (lane == 0) {
#pragma unroll
    for (int e = 0; e < 8; ++e) logit[e] += gb[e];
    float mx = logit[0];
#pragma unroll
    for (int e = 1; e < 8; ++e) mx = fmaxf(mx, logit[e]);
    float pe[8], se = 0.f;
#pragma unroll
    for (int e = 0; e < 8; ++e) { pe[e] = __expf(logit[e] - mx); se += pe[e]; }
    float rs = 1.f / se;
#pragma unroll
    for (int e = 0; e < 8; ++e) pe[e] *= rs;
    int i0 = 0;
    float b0 = pe[0];
#pragma unroll
    for (int e = 1; e < 8; ++e)
      if (pe[e] > b0) { b0 = pe[e]; i0 = e; }
    int i1 = -1;
    float b1v = -1.f;
#pragma unroll
    for (int e = 0; e < 8; ++e)
      if (e != i0 && pe[e] > b1v) { b1v = pe[e]; i1 = e; }
    topk_e[2 * t] = i0;
    topk_e[2 * t + 1] = i1;
    topk_w[2 * t] = b0;
    topk_w[2 * t + 1] = b1v;
  }
}

// One block, 8 waves. Wave e scans all 2T entries in token order, ranking
// its matches via ballot prefix -> deterministic positions, no atomics.
__global__ __launch_bounds__(512) void scatter_tokens(
    const int* __restrict__ topk_e, int* __restrict__ counts,
    int* __restrict__ pos_of, int* __restrict__ etok, int T2) {
  const int e = threadIdx.x >> 6;
  const int lane = threadIdx.x & 63;
  int base = 0;
  for (int i0 = 0; i0 < T2; i0 += 128) {
    iv2 te = *(const iv2*)(topk_e + i0 + lane * 2);
    unsigned long long m0 = __ballot(te[0] == e);
    unsigned long long m1 = __ballot(te[1] == e);
    unsigned long long lt = (1ull << lane) - 1;
    int pre = __popcll(m0 & lt) + __popcll(m1 & lt);
    if (te[0] == e) {
      int pos = base + pre;
      etok[e * 4096 + pos] = (i0 >> 1) + lane;
      pos_of[i0 + lane * 2] = pos;
      ++pre;
    }
    if (te[1] == e) {
      int pos = base + pre;
      etok[e * 4096 + pos] = (i0 >> 1) + lane;
      pos_of[i0 + lane * 2 + 1] = pos;
    }
    base += __popcll(m0) + __popcll(m1);
  }
  if (lane == 0) counts[e] = base;
}

__global__ __launch_bounds__(256) void sched_moe(const int* __restrict__ counts,
                                                 int* __restrict__ meta,
                                                 int* __restrict__ rexp) {
  __shared__ int s_e[MAX_TILES], s_row0[MAX_TILES], s_tt, s_rb;
  if (threadIdx.x == 0) {
    int tt = 0, rb = 0;
    for (int e = 0; e < 8; ++e) {
      meta[1 + e] = rb;
      int c = counts[e];
      int nt = (c + 127) >> 7;
      for (int i = 0; i < nt; ++i) {
        meta[16 + tt * 4] = e;
        meta[17 + tt * 4] = i * 128;
        meta[18 + tt * 4] = c;
        meta[19 + tt * 4] = rb + i * 128;
        s_e[tt] = e;
        s_row0[tt] = rb + i * 128;
        ++tt;
      }
      rb += nt * 128;
    }
    meta[0] = tt;
    s_tt = tt;
    s_rb = rb;
  }
  __syncthreads();
  int tt = s_tt;
  for (int tile = 0; tile < tt; ++tile) {
    int r0 = s_row0[tile], e = s_e[tile];
    for (int j = threadIdx.x; j < 128; j += 256) rexp[r0 + j] = e;
  }
  for (int r = s_rb + threadIdx.x; r < MAX_TILES * 128; r += 256) rexp[r] = 0;
}

// silu(a13[:, c]+b1[e,c]) * (a13[:, 1024+c]+b3[e,c]) -> in-place lower half.
__global__ __launch_bounds__(256) void silu_moe(
    u16* __restrict__ a13, const float* __restrict__ b1,
    const float* __restrict__ b3, const int* __restrict__ rexp) {
  size_t i = ((size_t)blockIdx.x * 256 + threadIdx.x) * 8;
  int row = (int)(i >> 10), col = (int)(i & 1023);
  int e = rexp[row];
  const float* ba = b1 + (size_t)e * 1024 + col;
  const float* bb = b3 + (size_t)e * 1024 + col;
  u16* rp = a13 + (size_t)row * 2048 + col;
  bh8 av = *(const bh8*)rp;
  bh8 bv = *(const bh8*)(rp + 1024);
  bh8 ov;
#pragma unroll
  for (int j = 0; j < 8; ++j) {
    float x = b2f((u16)av[j]) + ba[j];
    float y = b2f((u16)bv[j]) + bb[j];
    float s = x / (1.f + __expf(-x));
    ov[j] = (short)f2b(s * y);
  }
  *(bh8*)rp = ov;
}

__global__ __launch_bounds__(128) void combine_router(
    const u16* __restrict__ eo, const int* __restrict__ topk_e,
    const float* __restrict__ topk_w, const int* __restrict__ pos_of,
    const int* __restrict__ meta, float* __restrict__ router) {
  int t = blockIdx.x;
  int c = threadIdx.x * 8;
  int e0 = topk_e[2 * t], e1 = topk_e[2 * t + 1];
  float w0 = topk_w[2 * t], w1 = topk_w[2 * t + 1];
  int r0 = meta[1 + e0] + pos_of[2 * t];
  int r1 = meta[1 + e1] + pos_of[2 * t + 1];
  bh8 v0 = *(const bh8*)(eo + (size_t)r0 * 1024 + c);
  bh8 v1 = *(const bh8*)(eo + (size_t)r1 * 1024 + c);
  float* rp = router + (size_t)t * 1024 + c;
#pragma unroll
  for (int j = 0; j < 8; ++j)
    rp[j] = w0 * b2f((u16)v0[j]) + w1 * b2f((u16)v1[j]);
}

// silu(sgu[:,c]) * sgu[:,2048+c] -> hs [T,2048]
__global__ __launch_bounds__(256) void silu_sh(const u16* __restrict__ sgu,
                                               u16* __restrict__ hs) {
  size_t i = ((size_t)blockIdx.x * 256 + threadIdx.x) * 8;
  size_t row = i >> 11, col = i & 2047;
  const u16* rp = sgu + row * 4096 + col;
  bh8 av = *(const bh8*)rp;
  bh8 bv = *(const bh8*)(rp + 2048);
  bh8 ov;
#pragma unroll
  for (int j = 0; j < 8; ++j) {
    float x = b2f((u16)av[j]);
    float y = b2f((u16)bv[j]);
    float s = x / (1.f + __expf(-x));
    ov[j] = (short)f2b(s * y);
  }
  *(bh8*)(hs + i) = ov;
}

__global__ __launch_bounds__(256) void f2b_convert(
    const float* __restrict__ src, u16* __restrict__ dst) {
  size_t i = ((size_t)blockIdx.x * 256 + threadIdx.x) * 8;
  fv4 a = *(const fv4*)(src + i);
  fv4 b = *(const fv4*)(src + i + 4);
  bh8 o;
#pragma unroll
  for (int j = 0; j < 4; ++j) o[j] = (short)f2b(a[j]);
#pragma unroll
  for (int j = 0; j < 4; ++j) o[4 + j] = (short)f2b(b[j]);
  *(bh8*)(dst + i) = o;
}

// interleave w1/w3 [E,1024,1024] f32 -> w13 [E,2048,1024] bf16 (half select)
__global__ __launch_bounds__(256) void f2b_convert_moe(
    const float* __restrict__ src, u16* __restrict__ dst, int halfoff) {
  size_t i = ((size_t)blockIdx.x * 256 + threadIdx.x) * 8;
  size_t e = i >> 20, inner = i & 1048575;
  fv4 a = *(const fv4*)(src + i);
  fv4 b = *(const fv4*)(src + i + 4);
  bh8 o;
#pragma unroll
  for (int j = 0; j < 4; ++j) o[j] = (short)f2b(a[j]);
#pragma unroll
  for (int j = 0; j < 4; ++j) o[4 + j] = (short)f2b(b[j]);
  *(bh8*)(dst + e * 2097152 + halfoff + inner) = o;
}

// ---------------------------------------------------------------------------
extern "C" void kernel_launch(void* const* d_in, const int* in_sizes, int n_in,
                              void* d_out, int out_size, void* d_ws,
                              size_t ws_size, hipStream_t stream) {
  (void)in_sizes; (void)n_in; (void)out_size; (void)ws_size;
  const int Sc = 2048, Dc = 1024, NHc = 16, Tc = 4096, SH = 2048;

  const float* x   = (const float*)d_in[0];
  const float* fc  = (const float*)d_in[1];
  const float* fs  = (const float*)d_in[2];
  const float* wq  = (const float*)d_in[4];
  const float* wk  = (const float*)d_in[5];
  const float* wv  = (const float*)d_in[6];
  const float* wo  = (const float*)d_in[7];
  const float* anw = (const float*)d_in[8];
  const float* fnw = (const float*)d_in[9];
  const float* gw  = (const float*)d_in[10];
  const float* gb  = (const float*)d_in[11];
  const float* w1  = (const float*)d_in[12];
  const float* b1  = (const float*)d_in[13];
  const float* w2  = (const float*)d_in[14];
  const float* b2  = (const float*)d_in[15];
  const float* w3  = (const float*)d_in[16];
  const float* b3  = (const float*)d_in[17];
  const float* sgw = (const float*)d_in[18];
  const float* suw = (const float*)d_in[19];
  const float* sdw = (const float*)d_in[20];
  float* out = (float*)d_out;

  char* base = (char*)d_ws;
  size_t off = 0;
  auto alloc = [&](size_t bytes) -> void* {
    void* p = base + off;
    off += (bytes + 255) & ~(size_t)255;
    return p;
  };
  // weights: wqkv+wo FIRST (their region is reused as hf_b after wo-gemm)
  u16* wqkv_b = (u16*)alloc(2ull * 3072 * 1024);   // 6.29 MB
  u16* wo_b   = (u16*)alloc(2ull * 1024 * 1024);   // 2.10 MB
  u16* sgu_b  = (u16*)alloc(2ull * 4096 * 1024);   // 8.39 MB
  u16* sdw_b  = (u16*)alloc(2ull * 1024 * 2048);   // 4.19 MB
  u16* w13_b  = (u16*)alloc(2ull * 8 * 2048 * 1024); // 33.6 MB
  u16* w2_b   = (u16*)alloc(2ull * 8 * 1024 * 1024); // 16.8 MB
  // region A: qkv_out (25.2) -> sgu_out (33.6) -> eo (18.6)
  char* regA = (char*)alloc(2ull * Tc * 4096);
  // region B: h_b/qr/kr/vt/o_b (33.6) -> a13 (37.2) -> router (16.8)
  char* regB = (char*)alloc(2ull * (size_t)MAX_TILES * 128 * 2048);
  float* x2  = (float*)alloc(4ull * Tc * Dc);      // 16.8 MB
  u16* hs_b  = (u16*)alloc(2ull * Tc * SH);        // 16.8 MB
  int* counts = (int*)alloc(8 * 4);
  int* topk_e = (int*)alloc(2ull * Tc * 4);
  float* topk_w = (float*)alloc(2ull * Tc * 4);
  int* pos_of = (int*)alloc(2ull * Tc * 4);
  int* etok = (int*)alloc(8ull * 4096 * 4);
  int* meta = (int*)alloc(512 * 4);
  int* rexp = (int*)alloc((size_t)MAX_TILES * 128 * 4);

  u16* qkv_out = (u16*)regA;
  u16* sgu_out = (u16*)regA;
  u16* eo_c    = (u16*)regA;
  u16* h_b  = (u16*)regB;
  u16* qr   = (u16*)regB;
  u16* kr   = (u16*)(regB + 2ull * Tc * Dc);
  u16* vt_  = (u16*)(regB + 4ull * Tc * Dc);
  u16* o_b  = (u16*)(regB + 6ull * Tc * Dc);
  u16* a13_c = (u16*)regB;
  float* router = (float*)regB;
  u16* hf_b = wqkv_b;  // overlays wqkv+wo after attention branch done

  auto conv = [&](const float* s, u16* d, size_t n) {
    f2b_convert<<<dim3((unsigned)(n / 2048)), 256, 0, stream>>>(s, d);
  };
  conv(wq, wqkv_b, (size_t)Dc * Dc);
  conv(wk, wqkv_b + 1048576, (size_t)Dc * Dc);
  conv(wv, wqkv_b + 2097152, (size_t)Dc * Dc);
  conv(wo, wo_b, (size_t)Dc * Dc);
  conv(sgw, sgu_b, (size_t)SH * Dc);
  conv(suw, sgu_b + 2097152, (size_t)SH * Dc);
  conv(sdw, sdw_b, (size_t)Dc * SH);
  conv(w2, w2_b, 8ull * 1024 * 1024);
  f2b_convert_moe<<<4096, 256, 0, stream>>>(w1, w13_b, 0);
  f2b_convert_moe<<<4096, 256, 0, stream>>>(w3, w13_b, 1048576);

  // ---- attention branch ----
  rmsnorm_bf16<<<Tc, 256, 0, stream>>>(x, anw, h_b);
  gemm_bt<0><<<dim3(3072 / 128, Tc / 128), 256, 0, stream>>>(
      h_b, wqkv_b, Tc, 3072, Dc, qkv_out, nullptr, nullptr, nullptr, nullptr,
      nullptr, nullptr);
  rope_repack<<<dim3(Sc / 64, 2, 4), 256, 0, stream>>>(qkv_out, fc, fs, qr, kr,
                                                       vt_, Sc);
  attn_fwd<<<dim3(2 * NHc, Sc / 128), 256, 0, stream>>>(qr, kr, vt_, o_b, Sc,
                                                        NHc);
  gemm_bt<1, 64><<<dim3(Dc / 128, Tc / 64), 256, 0, stream>>>(
      o_b, wo_b, Tc, Dc, Dc, nullptr, x2, x, nullptr, nullptr, nullptr,
      nullptr);

  // ---- ffn branch ----
  rmsnorm_bf16<<<Tc, 256, 0, stream>>>(x2, fnw, hf_b);
  gate_topk<<<Tc / 4, 256, 0, stream>>>(x2, fnw, gw, gb, topk_e, topk_w);
  scatter_tokens<<<1, 512, 0, stream>>>(topk_e, counts, pos_of, etok, 2 * Tc);
  sched_moe<<<1, 256, 0, stream>>>(counts, meta, rexp);

  // shared expert: fused gate|up GEMM then silu
  gemm_bt<0><<<dim3(4096 / 128, Tc / 128), 256, 0, stream>>>(
      hf_b, sgu_b, Tc, 4096, Dc, sgu_out, nullptr, nullptr, nullptr, nullptr,
      nullptr, nullptr);
  silu_sh<<<dim3((unsigned)(((size_t)Tc * SH) / 2048)), 256, 0, stream>>>(
      sgu_out, hs_b);

  // sparse MoE: fused w1|w3 grouped gather GEMM, silu in-place, w2
  gemm_bt<5><<<dim3(2048 / 128, MAX_TILES), 256, 0, stream>>>(
      hf_b, w13_b, Tc, 2048, Dc, a13_c, nullptr, nullptr, nullptr, nullptr,
      meta, etok);
  silu_moe<<<dim3((unsigned)(((size_t)MAX_TILES * 128 * 1024) / 2048)), 256, 0,
             stream>>>(a13_c, b1, b3, rexp);
  gemm_bt<6><<<dim3(Dc / 128, MAX_TILES), 256, 0, stream>>>(
      a13_c, w2_b, /*lda=*/2048, Dc, 1024, eo_c, nullptr, nullptr, nullptr,
      b2, meta, etok);
  combine_router<<<Tc, 128, 0, stream>>>(eo_c, topk_e, topk_w, pos_of, meta,
                                         router);

  // final: out = x2 + router + hs @ sdw^T
  gemm_bt<4, 64><<<dim3(Dc / 128, Tc / 64), 256, 0, stream>>>(
      hs_b, sdw_b, Tc, Dc, SH, nullptr, out, x2, router, nullptr, nullptr,
      nullptr);
}

// Round 6
// 426.153 us; speedup vs baseline: 2.9377x; 1.0426x over previous
//
#include <hip/hip_runtime.h>

// ---------------------------------------------------------------------------
// TransformerBlock on MI355X (gfx950), round 6:
//  - attention: hoisted shared K/V frags, MFMA-based row-sum (l in C-layout),
//    fma-folded scale, paired q-tiles, permuted-V, defer-max
//  - silu fused into GEMM epilogues via 32-row-interleaved weights
//    (MODE 7 shared-expert -> hs, MODE 8 MoE w13 -> compact a13)
//  - single merged routing kernel (ballot scatter + tile scheduling)
// ---------------------------------------------------------------------------

typedef unsigned short u16;
typedef __attribute__((ext_vector_type(8))) short bh8;   // 8 x bf16
typedef __attribute__((ext_vector_type(4))) float fv4;
typedef __attribute__((ext_vector_type(4))) unsigned uv4;
typedef __attribute__((ext_vector_type(2))) int iv2;

#define LOG2E 1.4426950408889634f
#define MAX_TILES 71

__device__ __forceinline__ float b2f(u16 u) {
  return __builtin_bit_cast(float, ((unsigned)u) << 16);
}
__device__ __forceinline__ u16 f2b(float f) {
  unsigned x = __builtin_bit_cast(unsigned, f);
  return (u16)((x + 0x7fffu + ((x >> 16) & 1u)) >> 16);  // RNE
}
__device__ __forceinline__ fv4 mfma16(bh8 a, bh8 b, fv4 c) {
  return __builtin_amdgcn_mfma_f32_16x16x32_bf16(a, b, c, 0, 0, 0);
}
__device__ __forceinline__ unsigned cvtpk(float lo, float hi) {
  unsigned r;
  asm("v_cvt_pk_bf16_f32 %0, %1, %2" : "=v"(r) : "v"(lo), "v"(hi));
  return r;
}

#define GLD16(g, l)                                                        \
  __builtin_amdgcn_global_load_lds(                                        \
      (const __attribute__((address_space(1))) void*)(g),                  \
      (__attribute__((address_space(3))) void*)(l), 16, 0, 0)

// Read one MFMA fragment (16B) from a [rows][64] bf16 LDS tile whose rows are
// 128B and whose 16B blocks are XOR-swizzled by (row&7).
__device__ __forceinline__ bh8 lds_frag(const u16* base, int row, int b8) {
  int off = row * 128 + ((b8 * 16) ^ ((row & 7) << 4));
  return *(const bh8*)((const char*)base + off);
}

// ---------------------------------------------------------------------------
// Generic GEMM: C[M,N] = A[M,K] (bf16) @ B[N,K]^T (bf16), f32 accumulate.
// TM: A-tile rows (128 or 64). B-tile is always 128 cols.
// MODE 0: Cb = bf16(gemm)
// MODE 1: Cf = add1 + gemm
// MODE 4: Cf = add1 + add2 + gemm
// MODE 6: compact-A grouped MoE (w2): lda via M; Cb = bf16(gemm + bias_e)
// MODE 7: interleaved silu (shared expert): Cb[.,N/2] = silu(g)*u
// MODE 8: gather-A grouped MoE w13, interleaved silu + biases:
//         Cb[.,N/2] = silu(g + b1[e]) * (u + b3[e])   (add1=b1, add2=b3)
// ---------------------------------------------------------------------------
template <int MODE, int TM = 128>
__global__ __launch_bounds__(256) void gemm_bt(
    const u16* __restrict__ A, const u16* __restrict__ B, int M, int N, int K,
    u16* __restrict__ Cb, float* __restrict__ Cf,
    const float* __restrict__ add1, const float* __restrict__ add2,
    const float* __restrict__ bias, const int* __restrict__ tmeta,
    const int* __restrict__ etok) {
  constexpr int MR = TM / 32;  // M-frags per wave: 128->4, 64->2
  __shared__ u16 As[TM * 64];
  __shared__ u16 Bs[128 * 64];
  const int lane = threadIdx.x & 63;
  const int wid = threadIdx.x >> 6;
  const int wr = wid >> 1, wc = wid & 1;
  const int n0 = blockIdx.x * 128;
  const int rr = lane >> 3;
  const int b8s = (lane & 7) ^ rr;
  const int ldA = (MODE == 6) ? M : K;

  int m0 = 0, e = 0, m0l = 0, cnt = 0, row0 = 0;
  const u16* Bp = B;
  if constexpr (MODE == 6 || MODE == 8) {
    int tile = blockIdx.y;
    if (tile >= tmeta[0]) return;
    e = tmeta[16 + tile * 4];
    m0l = tmeta[17 + tile * 4];
    cnt = tmeta[18 + tile * 4];
    row0 = tmeta[19 + tile * 4];
    Bp = B + (size_t)e * N * K;
  } else {
    m0 = blockIdx.y * TM;
  }

  const u16* Arow[MR];
  const u16* Brow[4];
#pragma unroll
  for (int i = 0; i < MR; ++i) {
    int c = wid * MR + i;
    int row = c * 8 + rr;
    if constexpr (MODE == 8) {
      int li = m0l + row;
      li = li < cnt ? li : cnt - 1;
      int tok = etok[e * 4096 + li];
      Arow[i] = A + (size_t)tok * ldA + b8s * 8;
    } else if constexpr (MODE == 6) {
      Arow[i] = A + (size_t)(row0 + row) * ldA + b8s * 8;
    } else {
      Arow[i] = A + (size_t)(m0 + row) * ldA + b8s * 8;
    }
  }
#pragma unroll
  for (int i = 0; i < 4; ++i)
    Brow[i] = Bp + (size_t)(n0 + (wid * 4 + i) * 8 + rr) * K + b8s * 8;

  fv4 acc[MR][4] = {};
  for (int k0 = 0; k0 < K; k0 += 64) {
    __syncthreads();
#pragma unroll
    for (int i = 0; i < MR; ++i)
      GLD16(Arow[i] + k0, &As[(wid * MR + i) * 512]);
#pragma unroll
    for (int i = 0; i < 4; ++i)
      GLD16(Brow[i] + k0, &Bs[(wid * 4 + i) * 512]);
    __syncthreads();
#pragma unroll
    for (int ks = 0; ks < 2; ++ks) {
      int b8 = ks * 4 + (lane >> 4);
      bh8 af[MR], bf[4];
#pragma unroll
      for (int mi = 0; mi < MR; ++mi)
        af[mi] = lds_frag(As, wr * (16 * MR) + mi * 16 + (lane & 15), b8);
#pragma unroll
      for (int ni = 0; ni < 4; ++ni)
        bf[ni] = lds_frag(Bs, wc * 64 + ni * 16 + (lane & 15), b8);
      __builtin_amdgcn_s_setprio(1);
#pragma unroll
      for (int mi = 0; mi < MR; ++mi)
#pragma unroll
        for (int ni = 0; ni < 4; ++ni)
          acc[mi][ni] = mfma16(af[mi], bf[ni], acc[mi][ni]);
      __builtin_amdgcn_s_setprio(0);
    }
  }

  const int rbase = (MODE == 6 || MODE == 8) ? row0 : m0;
  const int r0b = rbase + wr * (16 * MR) + (lane >> 4) * 4;

  if constexpr (MODE == 7 || MODE == 8) {
    const int OUTN = N >> 1;
    const int colb = (n0 >> 1) + wc * 32;
    const float* bb1 = nullptr;
    const float* bb3 = nullptr;
    if constexpr (MODE == 8) {
      bb1 = add1 + (size_t)e * OUTN;
      bb3 = add2 + (size_t)e * OUTN;
    }
#pragma unroll
    for (int mi = 0; mi < MR; ++mi) {
#pragma unroll
      for (int ni = 0; ni < 2; ++ni) {
        int c = colb + ni * 16 + (lane & 15);
#pragma unroll
        for (int r = 0; r < 4; ++r) {
          int row = r0b + mi * 16 + r;
          float xg = acc[mi][ni][r];
          float yu = acc[mi][ni + 2][r];
          if constexpr (MODE == 8) {
            xg += bb1[c];
            yu += bb3[c];
          }
          float s = xg / (1.f + __expf(-xg));
          Cb[(size_t)row * OUTN + c] = f2b(s * yu);
        }
      }
    }
  } else {
    const int c0b = n0 + wc * 64 + (lane & 15);
    const float* bb = nullptr;
    if constexpr (MODE == 6) bb = bias + (size_t)e * N;
#pragma unroll
    for (int mi = 0; mi < MR; ++mi) {
#pragma unroll
      for (int ni = 0; ni < 4; ++ni) {
        int c = c0b + ni * 16;
#pragma unroll
        for (int r = 0; r < 4; ++r) {
          int row = r0b + mi * 16 + r;
          size_t idx = (size_t)row * N + c;
          float v = acc[mi][ni][r];
          if constexpr (MODE == 0) Cb[idx] = f2b(v);
          else if constexpr (MODE == 1) Cf[idx] = add1[idx] + v;
          else if constexpr (MODE == 4) Cf[idx] = add1[idx] + add2[idx] + v;
          else Cb[idx] = f2b(v + bb[c]);
        }
      }
    }
  }
}

// ---------------------------------------------------------------------------
// RMSNorm: f32 [T,1024] -> bf16 [T,1024], one block per token.
// ---------------------------------------------------------------------------
__global__ __launch_bounds__(256) void rmsnorm_bf16(
    const float* __restrict__ x, const float* __restrict__ w,
    u16* __restrict__ out) {
  int t = blockIdx.x;
  const float* xr = x + (size_t)t * 1024;
  fv4 v = *(const fv4*)(xr + threadIdx.x * 4);
  float ss = v[0] * v[0] + v[1] * v[1] + v[2] * v[2] + v[3] * v[3];
#pragma unroll
  for (int off = 1; off < 64; off <<= 1) ss += __shfl_xor(ss, off);
  __shared__ float red[4];
  int lane = threadIdx.x & 63, wid = threadIdx.x >> 6;
  if (lane == 0) red[wid] = ss;
  __syncthreads();
  float inv = rsqrtf((red[0] + red[1] + red[2] + red[3]) * (1.0f / 1024.f) + 1e-6f);
  u16* op = out + (size_t)t * 1024 + threadIdx.x * 4;
  const float* wp = w + threadIdx.x * 4;
#pragma unroll
  for (int i = 0; i < 4; ++i) op[i] = f2b(v[i] * inv * wp[i]);
}

// ---------------------------------------------------------------------------
// RoPE + repack from fused qkv [T,3072]:
//   q,k -> rotated [B,NH,S,64]; v -> vt [B,NH,64,S] (transposed AND column-
//   permuted per 64-block: physical group pg=4ks+g holds logical j
//   {16ks+4g+r, 16ks+32+4g+r}).  Grid: (S/64, B, NH/4).
// ---------------------------------------------------------------------------
__global__ __launch_bounds__(256) void rope_repack(
    const u16* __restrict__ qkv, const float* __restrict__ fc,
    const float* __restrict__ fs, u16* __restrict__ qr, u16* __restrict__ kr,
    u16* __restrict__ vt, int S) {
  __shared__ u16 tile[64][65];
  const int s0 = blockIdx.x * 64;
  const int b = blockIdx.y;
  const int h0 = blockIdx.z * 4;
#pragma unroll 4
  for (int it = 0; it < 32; ++it) {
    int idx = threadIdx.x + it * 256;
    int tl = idx >> 7, rem = idx & 127;
    int h = h0 + (rem >> 5), i = rem & 31;
    int s = s0 + tl;
    float c = fc[s * 32 + i], sn = fs[s * 32 + i];
    size_t src = ((size_t)(b * S + s)) * 3072 + h * 64 + 2 * i;
    size_t dst = ((size_t)((b * 16 + h) * S + s)) * 64 + 2 * i;
    float a0 = b2f(qkv[src]), a1 = b2f(qkv[src + 1]);
    qr[dst] = f2b(a0 * c - a1 * sn);
    qr[dst + 1] = f2b(a0 * sn + a1 * c);
    float b0 = b2f(qkv[src + 1024]), b1 = b2f(qkv[src + 1025]);
    kr[dst] = f2b(b0 * c - b1 * sn);
    kr[dst + 1] = f2b(b0 * sn + b1 * c);
  }
  for (int hh = 0; hh < 4; ++hh) {
    int h = h0 + hh;
    __syncthreads();
    for (int cc = threadIdx.x; cc < 512; cc += 256) {
      int tl = cc >> 3, d8 = cc & 7;
      bh8 val = *(const bh8*)(qkv + ((size_t)(b * S + s0 + tl)) * 3072 + 2048 +
                              h * 64 + d8 * 8);
#pragma unroll
      for (int j = 0; j < 8; ++j) tile[tl][d8 * 8 + j] = (u16)val[j];
    }
    __syncthreads();
    for (int cc = threadIdx.x; cc < 512; cc += 256) {
      int d = cc >> 3, pg = cc & 7;
      int sbase = 16 * (pg >> 2) + 4 * (pg & 3);
      bh8 o;
#pragma unroll
      for (int j = 0; j < 8; ++j)
        o[j] = (short)tile[sbase + (j & 3) + ((j >> 2) << 5)][d];
      *(bh8*)(vt + ((size_t)((b * 16 + h) * 64 + d)) * S + s0 + pg * 8) = o;
    }
  }
}

// ---------------------------------------------------------------------------
// Flash attention (causal), paired q-tiles, hoisted shared K/V frags,
// MFMA row-sum (l in C-layout), fma-folded scale, defer-max.
// Grid: (B*NH, nq/2). 4 waves x 16 q-rows, KVBLK=64, dbuf staging.
// ---------------------------------------------------------------------------
__global__ __launch_bounds__(256) void attn_fwd(
    const u16* __restrict__ qr, const u16* __restrict__ kr,
    const u16* __restrict__ vt, u16* __restrict__ ob, int S, int NHc) {
  __shared__ u16 Ks[2][64 * 64];
  __shared__ u16 Vs[2][64 * 64];   // V^T tile, column-permuted
  const int lane = threadIdx.x & 63;
  const int wid = threadIdx.x >> 6;
  const int g = lane >> 4;
  const int l15 = lane & 15;
  const int bh = blockIdx.x;
  const int ia = blockIdx.y;
  const int nq = S / 64;
  const int qa0 = ia * 64;                 // light q-tile
  const int qb0 = (nq - 1 - ia) * 64;      // heavy q-tile
  const int b = bh / NHc, h = bh % NHc;
  const u16* qbase = qr + (size_t)bh * S * 64;
  const u16* kb = kr + (size_t)bh * S * 64;
  const u16* vb = vt + (size_t)bh * 64 * S;
  const float SC = 0.015625f * LOG2E;  // both ref scales, log2 domain
  const int rr = lane >> 3;
  const int b8s = (lane & 7) ^ rr;

  bh8 ONES;
#pragma unroll
  for (int j = 0; j < 8; ++j) ONES[j] = (short)0x3f80;  // bf16 1.0

  bh8 qfA[2], qfB[2];
  {
    const u16* qp = qbase + (size_t)(qa0 + wid * 16 + l15) * 64 + g * 8;
    qfA[0] = *(const bh8*)qp;
    qfA[1] = *(const bh8*)(qp + 32);
    qp = qbase + (size_t)(qb0 + wid * 16 + l15) * 64 + g * 8;
    qfB[0] = *(const bh8*)qp;
    qfB[1] = *(const bh8*)(qp + 32);
  }
  fv4 oaccA[4] = {}, oaccB[4] = {};
  fv4 lA = {}, lB = {};                // row-sums, C-layout (row = 4g+r)
  float mA = -1e30f, mB = -1e30f;
  const int nktB = nq - ia;

  auto stage = [&](int buf, int j0) {
#pragma unroll
    for (int i = 0; i < 2; ++i) {
      int c = wid * 2 + i;
      int row = c * 8 + rr;
      GLD16(kb + (size_t)(j0 + row) * 64 + b8s * 8, &Ks[buf][c * 512]);
      GLD16(vb + (size_t)row * S + j0 + b8s * 8, &Vs[buf][c * 512]);
    }
  };
  stage(0, 0);

  auto process = [&](const bh8 (&kf)[2][4], const bh8 (&vf)[2][4], int j0,
                     int q0x, bh8* qf, fv4* oacc, float& mrow, fv4& lrowC) {
    const int q_my = q0x + wid * 16 + l15;
    fv4 st[4] = {};
    __builtin_amdgcn_s_setprio(1);
#pragma unroll
    for (int ks = 0; ks < 2; ++ks)
#pragma unroll
      for (int jt = 0; jt < 4; ++jt)
        st[jt] = mfma16(kf[ks][jt], qf[ks], st[jt]);
    __builtin_amdgcn_s_setprio(0);

    // mask + max on RAW scores (SC > 0 so max commutes with the scale)
    float sr[4][4];
    float mloc = -1e30f;
    const int jb = j0 + 4 * g;
    if (j0 + 63 > q0x + wid * 16) {   // diagonal tile
#pragma unroll
      for (int jt = 0; jt < 4; ++jt)
#pragma unroll
        for (int r = 0; r < 4; ++r) {
          int j = jb + jt * 16 + r;
          float s = (j <= q_my) ? st[jt][r] : -1e30f;
          sr[jt][r] = s;
          mloc = fmaxf(mloc, s);
        }
    } else {                          // interior: fully visible
#pragma unroll
      for (int jt = 0; jt < 4; ++jt)
#pragma unroll
        for (int r = 0; r < 4; ++r) {
          sr[jt][r] = st[jt][r];
          mloc = fmaxf(mloc, st[jt][r]);
        }
    }
    mloc = fmaxf(mloc, __shfl_xor(mloc, 16));
    mloc = fmaxf(mloc, __shfl_xor(mloc, 32));
    mloc *= SC;                        // scaled row max (log2 domain)
    bool defer = __all(mloc <= mrow + 8.f);   // T13
    if (!defer) {
      float mnew = fmaxf(mrow, mloc);
      float sfac = exp2f(mrow - mnew);
      mrow = mnew;
      float sfC[4];
#pragma unroll
      for (int r = 0; r < 4; ++r) sfC[r] = __shfl(sfac, g * 4 + r);
#pragma unroll
      for (int dt = 0; dt < 4; ++dt)
#pragma unroll
        for (int r = 0; r < 4; ++r) oacc[dt][r] *= sfC[r];
#pragma unroll
      for (int r = 0; r < 4; ++r) lrowC[r] *= sfC[r];
    }
    float p[4][4];
#pragma unroll
    for (int jt = 0; jt < 4; ++jt)
#pragma unroll
      for (int r = 0; r < 4; ++r)
        p[jt][r] = exp2f(fmaf(sr[jt][r], SC, -mrow));

    // PV + row-sum via MFMA (pa slot (g,i) <-> logical j matching permuted V)
    __builtin_amdgcn_s_setprio(1);
    fv4 racc = {};
#pragma unroll
    for (int ks = 0; ks < 2; ++ks) {
      uv4 w;
      w[0] = cvtpk(p[ks][0], p[ks][1]);
      w[1] = cvtpk(p[ks][2], p[ks][3]);
      w[2] = cvtpk(p[ks + 2][0], p[ks + 2][1]);
      w[3] = cvtpk(p[ks + 2][2], p[ks + 2][3]);
      bh8 pa = __builtin_bit_cast(bh8, w);
      racc = mfma16(pa, ONES, racc);
#pragma unroll
      for (int dt = 0; dt < 4; ++dt)
        oacc[dt] = mfma16(pa, vf[ks][dt], oacc[dt]);
    }
    __builtin_amdgcn_s_setprio(0);
#pragma unroll
    for (int r = 0; r < 4; ++r) lrowC[r] += racc[r];
  };

  for (int kt = 0; kt < nktB; ++kt) {
    const int j0 = kt * 64;
    __syncthreads();
    if (kt + 1 < nktB) stage((kt + 1) & 1, (kt + 1) * 64);
    const u16* Kc = Ks[kt & 1];
    const u16* Vc = Vs[kt & 1];
    bh8 kf[2][4], vf[2][4];
#pragma unroll
    for (int ks = 0; ks < 2; ++ks) {
      int b8 = ks * 4 + g;
#pragma unroll
      for (int jt = 0; jt < 4; ++jt)
        kf[ks][jt] = lds_frag(Kc, jt * 16 + l15, b8);
#pragma unroll
      for (int dt = 0; dt < 4; ++dt)
        vf[ks][dt] = lds_frag(Vc, dt * 16 + l15, b8);
    }
    process(kf, vf, j0, qb0, qfB, oaccB, mB, lB);
    if (kt <= ia) process(kf, vf, j0, qa0, qfA, oaccA, mA, lA);
  }

  auto wout = [&](fv4* oacc, fv4 lrowC, int q0x) {
#pragma unroll
    for (int dt = 0; dt < 4; ++dt)
#pragma unroll
      for (int r = 0; r < 4; ++r) {
        int row = q0x + wid * 16 + g * 4 + r;
        int col = dt * 16 + l15;
        ob[((size_t)b * S + row) * 1024 + h * 64 + col] =
            f2b(oacc[dt][r] / lrowC[r]);
      }
  };
  wout(oaccA, lA, qa0);
  wout(oaccB, lB, qb0);
}

// ---------------------------------------------------------------------------
// MoE routing (atomic-free)
// ---------------------------------------------------------------------------
__global__ __launch_bounds__(256) void gate_topk(
    const float* __restrict__ x2, const float* __restrict__ nw,
    const float* __restrict__ gw, const float* __restrict__ gb,
    int* __restrict__ topk_e, float* __restrict__ topk_w) {
  int t = blockIdx.x * 4 + (threadIdx.x >> 6);
  int lane = threadIdx.x & 63;
  const float* xr = x2 + (size_t)t * 1024;
  float hv[16];
  float ss = 0.f;
#pragma unroll
  for (int i = 0; i < 4; ++i) {
    fv4 v = *(const fv4*)(xr + lane * 16 + i * 4);
#pragma unroll
    for (int j = 0; j < 4; ++j) {
      hv[i * 4 + j] = v[j];
      ss += v[j] * v[j];
    }
  }
#pragma unroll
  for (int off = 1; off < 64; off <<= 1) ss += __shfl_xor(ss, off);
  float inv = rsqrtf(ss * (1.0f / 1024.f) + 1e-6f);
  const fv4* nwp = (const fv4*)(nw + lane * 16);
#pragma unroll
  for (int i = 0; i < 4; ++i) {
    fv4 wv = nwp[i];
#pragma unroll
    for (int j = 0; j < 4; ++j) hv[i * 4 + j] *= inv * wv[j];
  }
  float logit[8];
#pragma unroll
  for (int e = 0; e < 8; ++e) {
    const fv4* wp = (const fv4*)(gw + (size_t)e * 1024 + lane * 16);
    float s = 0.f;
#pragma unroll
    for (int i = 0; i < 4; ++i) {
      fv4 wv = wp[i];
#pragma unroll
      for (int j = 0; j < 4; ++j) s += hv[i * 4 + j] * wv[j];
    }
    logit[e] = s;
  }
#pragma unroll
  for (int off = 1; off < 64; off <<= 1)
#pragma unroll
    for (int e = 0; e < 8; ++e) logit[e] += __shfl_xor(logit[e], off);
  if (lane == 0) {
#pragma unroll
    for (int e = 0; e < 8; ++e) logit[e] += gb[e];
    float mx = logit[0];
#pragma unroll
    for (int e = 1; e < 8; ++e) mx = fmaxf(mx, logit[e]);
    float pe[8], se = 0.f;
#pragma unroll
    for (int e = 0; e < 8; ++e) { pe[e] = __expf(logit[e] - mx); se += pe[e]; }
    float rs = 1.f / se;
#pragma unroll
    for (int e = 0; e < 8; ++e) pe[e] *= rs;
    int i0 = 0;
    float b0 = pe[0];
#pragma unroll
    for (int e = 1; e < 8; ++e)
      if (pe[e] > b0) { b0 = pe[e]; i0 = e; }
    int i1 = -1;
    float b1v = -1.f;
#pragma unroll
    for (int e = 0; e < 8; ++e)
      if (e != i0 && pe[e] > b1v) { b1v = pe[e]; i1 = e; }
    topk_e[2 * t] = i0;
    topk_e[2 * t + 1] = i1;
    topk_w[2 * t] = b0;
    topk_w[2 * t + 1] = b1v;
  }
}

// One block, 8 waves: wave e ballot-ranks its tokens (deterministic order),
// then thread 0 builds the padded tile map. Replaces scatter+sched kernels.
__global__ __launch_bounds__(512) void route_tokens(
    const int* __restrict__ topk_e, int* __restrict__ pos_of,
    int* __restrict__ etok, int* __restrict__ meta, int T2) {
  __shared__ int scnt[8];
  const int e = threadIdx.x >> 6;
  const int lane = threadIdx.x & 63;
  int base = 0;
  for (int i0 = 0; i0 < T2; i0 += 128) {
    iv2 te = *(const iv2*)(topk_e + i0 + lane * 2);
    unsigned long long m0 = __ballot(te[0] == e);
    unsigned long long m1 = __ballot(te[1] == e);
    unsigned long long lt = (1ull << lane) - 1;
    int pre = __popcll(m0 & lt) + __popcll(m1 & lt);
    if (te[0] == e) {
      int pos = base + pre;
      etok[e * 4096 + pos] = (i0 >> 1) + lane;
      pos_of[i0 + lane * 2] = pos;
      ++pre;
    }
    if (te[1] == e) {
      int pos = base + pre;
      etok[e * 4096 + pos] = (i0 >> 1) + lane;
      pos_of[i0 + lane * 2 + 1] = pos;
    }
    base += __popcll(m0) + __popcll(m1);
  }
  if (lane == 0) scnt[e] = base;
  __syncthreads();
  if (threadIdx.x == 0) {
    int tt = 0, rb = 0;
#pragma unroll
    for (int e2 = 0; e2 < 8; ++e2) {
      meta[1 + e2] = rb;
      int c = scnt[e2];
      int nt = (c + 127) >> 7;
      for (int i = 0; i < nt; ++i) {
        meta[16 + tt * 4] = e2;
        meta[17 + tt * 4] = i * 128;
        meta[18 + tt * 4] = c;
        meta[19 + tt * 4] = rb + i * 128;
        ++tt;
      }
      rb += nt * 128;
    }
    meta[0] = tt;
  }
}

__global__ __launch_bounds__(128) void combine_router(
    const u16* __restrict__ eo, const int* __restrict__ topk_e,
    const float* __restrict__ topk_w, const int* __restrict__ pos_of,
    const int* __restrict__ meta, float* __restrict__ router) {
  int t = blockIdx.x;
  int c = threadIdx.x * 8;
  int e0 = topk_e[2 * t], e1 = topk_e[2 * t + 1];
  float w0 = topk_w[2 * t], w1 = topk_w[2 * t + 1];
  int r0 = meta[1 + e0] + pos_of[2 * t];
  int r1 = meta[1 + e1] + pos_of[2 * t + 1];
  bh8 v0 = *(const bh8*)(eo + (size_t)r0 * 1024 + c);
  bh8 v1 = *(const bh8*)(eo + (size_t)r1 * 1024 + c);
  float* rp = router + (size_t)t * 1024 + c;
#pragma unroll
  for (int j = 0; j < 8; ++j)
    rp[j] = w0 * b2f((u16)v0[j]) + w1 * b2f((u16)v1[j]);
}

__global__ __launch_bounds__(256) void f2b_convert(
    const float* __restrict__ src, u16* __restrict__ dst) {
  size_t i = ((size_t)blockIdx.x * 256 + threadIdx.x) * 8;
  fv4 a = *(const fv4*)(src + i);
  fv4 b = *(const fv4*)(src + i + 4);
  bh8 o;
#pragma unroll
  for (int j = 0; j < 4; ++j) o[j] = (short)f2b(a[j]);
#pragma unroll
  for (int j = 0; j < 4; ++j) o[4 + j] = (short)f2b(b[j]);
  *(bh8*)(dst + i) = o;
}

// f32 [segs*2^seg_shift, 1024] -> bf16 interleaved per 32 rows:
// src row rl of segment e -> dst row e*2^(seg_shift+1) + (rl>>5)*64 + (rl&31)
// + 32*half.  Used to build silu-fusable gate|up weight layouts.
__global__ __launch_bounds__(256) void f2b_convert_ilv(
    const float* __restrict__ src, u16* __restrict__ dst, int half,
    int seg_shift) {
  size_t i = ((size_t)blockIdx.x * 256 + threadIdx.x) * 8;
  int r = (int)(i >> 10), col = (int)(i & 1023);
  int rl = r & ((1 << seg_shift) - 1), e = r >> seg_shift;
  int dstrow = (e << (seg_shift + 1)) + ((rl >> 5) << 6) + (rl & 31) +
               (half << 5);
  fv4 a = *(const fv4*)(src + i);
  fv4 b = *(const fv4*)(src + i + 4);
  bh8 o;
#pragma unroll
  for (int j = 0; j < 4; ++j) o[j] = (short)f2b(a[j]);
#pragma unroll
  for (int j = 0; j < 4; ++j) o[4 + j] = (short)f2b(b[j]);
  *(bh8*)(dst + (size_t)dstrow * 1024 + col) = o;
}

// ---------------------------------------------------------------------------
extern "C" void kernel_launch(void* const* d_in, const int* in_sizes, int n_in,
                              void* d_out, int out_size, void* d_ws,
                              size_t ws_size, hipStream_t stream) {
  (void)in_sizes; (void)n_in; (void)out_size; (void)ws_size;
  const int Sc = 2048, Dc = 1024, NHc = 16, Tc = 4096, SH = 2048;

  const float* x   = (const float*)d_in[0];
  const float* fc  = (const float*)d_in[1];
  const float* fs  = (const float*)d_in[2];
  const float* wq  = (const float*)d_in[4];
  const float* wk  = (const float*)d_in[5];
  const float* wv  = (const float*)d_in[6];
  const float* wo  = (const float*)d_in[7];
  const float* anw = (const float*)d_in[8];
  const float* fnw = (const float*)d_in[9];
  const float* gw  = (const float*)d_in[10];
  const float* gb  = (const float*)d_in[11];
  const float* w1  = (const float*)d_in[12];
  const float* b1  = (const float*)d_in[13];
  const float* w2  = (const float*)d_in[14];
  const float* b2  = (const float*)d_in[15];
  const float* w3  = (const float*)d_in[16];
  const float* b3  = (const float*)d_in[17];
  const float* sgw = (const float*)d_in[18];
  const float* suw = (const float*)d_in[19];
  const float* sdw = (const float*)d_in[20];
  float* out = (float*)d_out;

  char* base = (char*)d_ws;
  size_t off = 0;
  auto alloc = [&](size_t bytes) -> void* {
    void* p = base + off;
    off += (bytes + 255) & ~(size_t)255;
    return p;
  };
  // weights: wqkv+wo FIRST (their region is reused as hf_b after wo-gemm)
  u16* wqkv_b = (u16*)alloc(2ull * 3072 * 1024);     // 6.29 MB
  u16* wo_b   = (u16*)alloc(2ull * 1024 * 1024);     // 2.10 MB
  u16* sgu_b  = (u16*)alloc(2ull * 4096 * 1024);     // 8.39 MB (interleaved)
  u16* sdw_b  = (u16*)alloc(2ull * 1024 * 2048);     // 4.19 MB
  u16* w13_b  = (u16*)alloc(2ull * 8 * 2048 * 1024); // 33.6 MB (interleaved)
  u16* w2_b   = (u16*)alloc(2ull * 8 * 1024 * 1024); // 16.8 MB
  // region A: qkv_out (25.2) -> eo (18.6)
  char* regA = (char*)alloc(2ull * Tc * 4096);
  // region B: h_b/qr/kr/vt/o_b (33.6) -> a13 (18.6) -> router (16.8)
  char* regB = (char*)alloc(2ull * (size_t)MAX_TILES * 128 * 2048);
  float* x2  = (float*)alloc(4ull * Tc * Dc);        // 16.8 MB
  u16* hs_b  = (u16*)alloc(2ull * Tc * SH);          // 16.8 MB
  int* topk_e = (int*)alloc(2ull * Tc * 4);
  float* topk_w = (float*)alloc(2ull * Tc * 4);
  int* pos_of = (int*)alloc(2ull * Tc * 4);
  int* etok = (int*)alloc(8ull * 4096 * 4);
  int* meta = (int*)alloc(512 * 4);

  u16* qkv_out = (u16*)regA;
  u16* eo_c    = (u16*)regA;
  u16* h_b  = (u16*)regB;
  u16* qr   = (u16*)regB;
  u16* kr   = (u16*)(regB + 2ull * Tc * Dc);
  u16* vt_  = (u16*)(regB + 4ull * Tc * Dc);
  u16* o_b  = (u16*)(regB + 6ull * Tc * Dc);
  u16* a13_c = (u16*)regB;
  float* router = (float*)regB;
  u16* hf_b = wqkv_b;  // overlays wqkv+wo after attention branch done

  auto conv = [&](const float* s, u16* d, size_t n) {
    f2b_convert<<<dim3((unsigned)(n / 2048)), 256, 0, stream>>>(s, d);
  };
  conv(wq, wqkv_b, (size_t)Dc * Dc);
  conv(wk, wqkv_b + 1048576, (size_t)Dc * Dc);
  conv(wv, wqkv_b + 2097152, (size_t)Dc * Dc);
  conv(wo, wo_b, (size_t)Dc * Dc);
  conv(sdw, sdw_b, (size_t)Dc * SH);
  conv(w2, w2_b, 8ull * 1024 * 1024);
  f2b_convert_ilv<<<1024, 256, 0, stream>>>(sgw, sgu_b, 0, 11);
  f2b_convert_ilv<<<1024, 256, 0, stream>>>(suw, sgu_b, 1, 11);
  f2b_convert_ilv<<<4096, 256, 0, stream>>>(w1, w13_b, 0, 10);
  f2b_convert_ilv<<<4096, 256, 0, stream>>>(w3, w13_b, 1, 10);

  // ---- attention branch ----
  rmsnorm_bf16<<<Tc, 256, 0, stream>>>(x, anw, h_b);
  gemm_bt<0><<<dim3(3072 / 128, Tc / 128), 256, 0, stream>>>(
      h_b, wqkv_b, Tc, 3072, Dc, qkv_out, nullptr, nullptr, nullptr, nullptr,
      nullptr, nullptr);
  rope_repack<<<dim3(Sc / 64, 2, 4), 256, 0, stream>>>(qkv_out, fc, fs, qr, kr,
                                                       vt_, Sc);
  attn_fwd<<<dim3(2 * NHc, Sc / 128), 256, 0, stream>>>(qr, kr, vt_, o_b, Sc,
                                                        NHc);
  gemm_bt<1, 64><<<dim3(Dc / 128, Tc / 64), 256, 0, stream>>>(
      o_b, wo_b, Tc, Dc, Dc, nullptr, x2, x, nullptr, nullptr, nullptr,
      nullptr);

  // ---- ffn branch ----
  rmsnorm_bf16<<<Tc, 256, 0, stream>>>(x2, fnw, hf_b);
  gate_topk<<<Tc / 4, 256, 0, stream>>>(x2, fnw, gw, gb, topk_e, topk_w);
  route_tokens<<<1, 512, 0, stream>>>(topk_e, pos_of, etok, meta, 2 * Tc);

  // shared expert: fused gate|up GEMM with silu epilogue -> hs
  gemm_bt<7><<<dim3(4096 / 128, Tc / 128), 256, 0, stream>>>(
      hf_b, sgu_b, Tc, 4096, Dc, hs_b, nullptr, nullptr, nullptr, nullptr,
      nullptr, nullptr);

  // sparse MoE: gather w13 GEMM with fused silu+biases -> compact a13, w2
  gemm_bt<8><<<dim3(2048 / 128, MAX_TILES), 256, 0, stream>>>(
      hf_b, w13_b, Tc, 2048, Dc, a13_c, nullptr, b1, b3, nullptr, meta, etok);
  gemm_bt<6><<<dim3(Dc / 128, MAX_TILES), 256, 0, stream>>>(
      a13_c, w2_b, /*lda=*/1024, Dc, 1024, eo_c, nullptr, nullptr, nullptr,
      b2, meta, etok);
  combine_router<<<Tc, 128, 0, stream>>>(eo_c, topk_e, topk_w, pos_of, meta,
                                         router);

  // final: out = x2 + router + hs @ sdw^T
  gemm_bt<4, 64><<<dim3(Dc / 128, Tc / 64), 256, 0, stream>>>(
      hs_b, sdw_b, Tc, Dc, SH, nullptr, out, x2, router, nullptr, nullptr,
      nullptr);
}

// Round 7
// 414.851 us; speedup vs baseline: 3.0178x; 1.0272x over previous
//
#include <hip/hip_runtime.h>

// ---------------------------------------------------------------------------
// TransformerBlock on MI355X (gfx950), round 7:
//  - bijective XCD-chunked blockIdx swizzle in all GEMMs (L2 locality)
//  - expert-combine fused into final GEMM epilogue (MODE 9, rowid gather)
//  - ffn rmsnorm fused into gate_topk (writes hf_b)
//  - attention: paired q-tiles, hoisted frags, MFMA row-sum, permuted-V
//  - silu fused into GEMM epilogues via interleaved weights
// ---------------------------------------------------------------------------

typedef unsigned short u16;
typedef __attribute__((ext_vector_type(8))) short bh8;   // 8 x bf16
typedef __attribute__((ext_vector_type(4))) float fv4;
typedef __attribute__((ext_vector_type(4))) unsigned uv4;
typedef __attribute__((ext_vector_type(2))) int iv2;

#define LOG2E 1.4426950408889634f
#define MAX_TILES 71

__device__ __forceinline__ float b2f(u16 u) {
  return __builtin_bit_cast(float, ((unsigned)u) << 16);
}
__device__ __forceinline__ u16 f2b(float f) {
  unsigned x = __builtin_bit_cast(unsigned, f);
  return (u16)((x + 0x7fffu + ((x >> 16) & 1u)) >> 16);  // RNE
}
__device__ __forceinline__ fv4 mfma16(bh8 a, bh8 b, fv4 c) {
  return __builtin_amdgcn_mfma_f32_16x16x32_bf16(a, b, c, 0, 0, 0);
}
__device__ __forceinline__ unsigned cvtpk(float lo, float hi) {
  unsigned r;
  asm("v_cvt_pk_bf16_f32 %0, %1, %2" : "=v"(r) : "v"(lo), "v"(hi));
  return r;
}

// Bijective XCD-chunk swizzle (m204): blocks resident on one XCD cover a
// contiguous chunk of logical (y,x) space -> A-tiles/weights fetched once.
__device__ __forceinline__ void xcd_swizzle(int& bx, int& by) {
  int gx = gridDim.x;
  int nwg = gx * gridDim.y;
  int flat = by * gx + bx;
  int q = nwg >> 3, r = nwg & 7;
  int xcd = flat & 7, idx = flat >> 3;
  int swz = (xcd < r ? xcd * (q + 1) : r * (q + 1) + (xcd - r) * q) + idx;
  by = swz / gx;
  bx = swz - by * gx;
}

#define GLD16(g, l)                                                        \
  __builtin_amdgcn_global_load_lds(                                        \
      (const __attribute__((address_space(1))) void*)(g),                  \
      (__attribute__((address_space(3))) void*)(l), 16, 0, 0)

// Read one MFMA fragment (16B) from a [rows][64] bf16 LDS tile whose rows are
// 128B and whose 16B blocks are XOR-swizzled by (row&7).
__device__ __forceinline__ bh8 lds_frag(const u16* base, int row, int b8) {
  int off = row * 128 + ((b8 * 16) ^ ((row & 7) << 4));
  return *(const bh8*)((const char*)base + off);
}

// ---------------------------------------------------------------------------
// Generic GEMM: C[M,N] = A[M,K] (bf16) @ B[N,K]^T (bf16), f32 accumulate.
// TM: A-tile rows (128 or 64). B-tile is always 128 cols.
// MODE 0: Cb = bf16(gemm)
// MODE 1: Cf = add1 + gemm
// MODE 6: compact-A grouped MoE (w2): lda via M; Cb = bf16(gemm + bias_e)
// MODE 7: interleaved silu (shared expert): Cb[.,N/2] = silu(g)*u
// MODE 8: gather-A grouped MoE w13, interleaved silu + biases:
//         Cb[.,N/2] = silu(g + b1[e]) * (u + b3[e])   (add1=b1, add2=b3)
// MODE 9: final: Cf = add1 + gemm + w0*eo[r0] + w1*eo[r1]
//         (Cb=eo read-only, tmeta=rowid[2T], bias=topk_w[2T])
// ---------------------------------------------------------------------------
template <int MODE, int TM = 128>
__global__ __launch_bounds__(256) void gemm_bt(
    const u16* __restrict__ A, const u16* __restrict__ B, int M, int N, int K,
    u16* __restrict__ Cb, float* __restrict__ Cf,
    const float* __restrict__ add1, const float* __restrict__ add2,
    const float* __restrict__ bias, const int* __restrict__ tmeta,
    const int* __restrict__ etok) {
  constexpr int MR = TM / 32;  // M-frags per wave: 128->4, 64->2
  __shared__ u16 As[TM * 64];
  __shared__ u16 Bs[128 * 64];
  int bx = blockIdx.x, by = blockIdx.y;
  xcd_swizzle(bx, by);
  const int lane = threadIdx.x & 63;
  const int wid = threadIdx.x >> 6;
  const int wr = wid >> 1, wc = wid & 1;
  const int n0 = bx * 128;
  const int rr = lane >> 3;
  const int b8s = (lane & 7) ^ rr;
  const int ldA = (MODE == 6) ? M : K;

  int m0 = 0, e = 0, m0l = 0, cnt = 0, row0 = 0;
  const u16* Bp = B;
  if constexpr (MODE == 6 || MODE == 8) {
    int tile = by;
    if (tile >= tmeta[0]) return;
    e = tmeta[16 + tile * 4];
    m0l = tmeta[17 + tile * 4];
    cnt = tmeta[18 + tile * 4];
    row0 = tmeta[19 + tile * 4];
    Bp = B + (size_t)e * N * K;
  } else {
    m0 = by * TM;
  }

  const u16* Arow[MR];
  const u16* Brow[4];
#pragma unroll
  for (int i = 0; i < MR; ++i) {
    int c = wid * MR + i;
    int row = c * 8 + rr;
    if constexpr (MODE == 8) {
      int li = m0l + row;
      li = li < cnt ? li : cnt - 1;
      int tok = etok[e * 4096 + li];
      Arow[i] = A + (size_t)tok * ldA + b8s * 8;
    } else if constexpr (MODE == 6) {
      Arow[i] = A + (size_t)(row0 + row) * ldA + b8s * 8;
    } else {
      Arow[i] = A + (size_t)(m0 + row) * ldA + b8s * 8;
    }
  }
#pragma unroll
  for (int i = 0; i < 4; ++i)
    Brow[i] = Bp + (size_t)(n0 + (wid * 4 + i) * 8 + rr) * K + b8s * 8;

  fv4 acc[MR][4] = {};
  for (int k0 = 0; k0 < K; k0 += 64) {
    __syncthreads();
#pragma unroll
    for (int i = 0; i < MR; ++i)
      GLD16(Arow[i] + k0, &As[(wid * MR + i) * 512]);
#pragma unroll
    for (int i = 0; i < 4; ++i)
      GLD16(Brow[i] + k0, &Bs[(wid * 4 + i) * 512]);
    __syncthreads();
#pragma unroll
    for (int ks = 0; ks < 2; ++ks) {
      int b8 = ks * 4 + (lane >> 4);
      bh8 af[MR], bf[4];
#pragma unroll
      for (int mi = 0; mi < MR; ++mi)
        af[mi] = lds_frag(As, wr * (16 * MR) + mi * 16 + (lane & 15), b8);
#pragma unroll
      for (int ni = 0; ni < 4; ++ni)
        bf[ni] = lds_frag(Bs, wc * 64 + ni * 16 + (lane & 15), b8);
      __builtin_amdgcn_s_setprio(1);
#pragma unroll
      for (int mi = 0; mi < MR; ++mi)
#pragma unroll
        for (int ni = 0; ni < 4; ++ni)
          acc[mi][ni] = mfma16(af[mi], bf[ni], acc[mi][ni]);
      __builtin_amdgcn_s_setprio(0);
    }
  }

  const int rbase = (MODE == 6 || MODE == 8) ? row0 : m0;
  const int r0b = rbase + wr * (16 * MR) + (lane >> 4) * 4;
  const int c0b = n0 + wc * 64 + (lane & 15);

  if constexpr (MODE == 7 || MODE == 8) {
    const int OUTN = N >> 1;
    const int colb = (n0 >> 1) + wc * 32;
    const float* bb1 = nullptr;
    const float* bb3 = nullptr;
    if constexpr (MODE == 8) {
      bb1 = add1 + (size_t)e * OUTN;
      bb3 = add2 + (size_t)e * OUTN;
    }
#pragma unroll
    for (int mi = 0; mi < MR; ++mi) {
#pragma unroll
      for (int ni = 0; ni < 2; ++ni) {
        int c = colb + ni * 16 + (lane & 15);
#pragma unroll
        for (int r = 0; r < 4; ++r) {
          int row = r0b + mi * 16 + r;
          float xg = acc[mi][ni][r];
          float yu = acc[mi][ni + 2][r];
          if constexpr (MODE == 8) {
            xg += bb1[c];
            yu += bb3[c];
          }
          float s = xg / (1.f + __expf(-xg));
          Cb[(size_t)row * OUTN + c] = f2b(s * yu);
        }
      }
    }
  } else if constexpr (MODE == 9) {
#pragma unroll
    for (int mi = 0; mi < MR; ++mi) {
#pragma unroll
      for (int r = 0; r < 4; ++r) {
        int row = r0b + mi * 16 + r;
        int g0 = tmeta[2 * row], g1 = tmeta[2 * row + 1];
        float w0 = bias[2 * row], w1 = bias[2 * row + 1];
        const u16* e0p = Cb + (size_t)g0 * 1024;
        const u16* e1p = Cb + (size_t)g1 * 1024;
#pragma unroll
        for (int ni = 0; ni < 4; ++ni) {
          int c = c0b + ni * 16;
          size_t idx = (size_t)row * N + c;
          Cf[idx] = add1[idx] + acc[mi][ni][r] + w0 * b2f(e0p[c]) +
                    w1 * b2f(e1p[c]);
        }
      }
    }
  } else {
    const float* bb = nullptr;
    if constexpr (MODE == 6) bb = bias + (size_t)e * N;
#pragma unroll
    for (int mi = 0; mi < MR; ++mi) {
#pragma unroll
      for (int ni = 0; ni < 4; ++ni) {
        int c = c0b + ni * 16;
#pragma unroll
        for (int r = 0; r < 4; ++r) {
          int row = r0b + mi * 16 + r;
          size_t idx = (size_t)row * N + c;
          float v = acc[mi][ni][r];
          if constexpr (MODE == 0) Cb[idx] = f2b(v);
          else if constexpr (MODE == 1) Cf[idx] = add1[idx] + v;
          else Cb[idx] = f2b(v + bb[c]);
        }
      }
    }
  }
}

// ---------------------------------------------------------------------------
// RMSNorm: f32 [T,1024] -> bf16 [T,1024], one block per token.
// ---------------------------------------------------------------------------
__global__ __launch_bounds__(256) void rmsnorm_bf16(
    const float* __restrict__ x, const float* __restrict__ w,
    u16* __restrict__ out) {
  int t = blockIdx.x;
  const float* xr = x + (size_t)t * 1024;
  fv4 v = *(const fv4*)(xr + threadIdx.x * 4);
  float ss = v[0] * v[0] + v[1] * v[1] + v[2] * v[2] + v[3] * v[3];
#pragma unroll
  for (int off = 1; off < 64; off <<= 1) ss += __shfl_xor(ss, off);
  __shared__ float red[4];
  int lane = threadIdx.x & 63, wid = threadIdx.x >> 6;
  if (lane == 0) red[wid] = ss;
  __syncthreads();
  float inv = rsqrtf((red[0] + red[1] + red[2] + red[3]) * (1.0f / 1024.f) + 1e-6f);
  u16* op = out + (size_t)t * 1024 + threadIdx.x * 4;
  const float* wp = w + threadIdx.x * 4;
#pragma unroll
  for (int i = 0; i < 4; ++i) op[i] = f2b(v[i] * inv * wp[i]);
}

// ---------------------------------------------------------------------------
// RoPE + repack from fused qkv [T,3072]:
//   q,k -> rotated [B,NH,S,64]; v -> vt [B,NH,64,S] (transposed AND column-
//   permuted per 64-block: physical group pg=4ks+g holds logical j
//   {16ks+4g+r, 16ks+32+4g+r}).  Grid: (S/64, B, NH/4).
// ---------------------------------------------------------------------------
__global__ __launch_bounds__(256) void rope_repack(
    const u16* __restrict__ qkv, const float* __restrict__ fc,
    const float* __restrict__ fs, u16* __restrict__ qr, u16* __restrict__ kr,
    u16* __restrict__ vt, int S) {
  __shared__ u16 tile[64][65];
  const int s0 = blockIdx.x * 64;
  const int b = blockIdx.y;
  const int h0 = blockIdx.z * 4;
#pragma unroll 4
  for (int it = 0; it < 32; ++it) {
    int idx = threadIdx.x + it * 256;
    int tl = idx >> 7, rem = idx & 127;
    int h = h0 + (rem >> 5), i = rem & 31;
    int s = s0 + tl;
    float c = fc[s * 32 + i], sn = fs[s * 32 + i];
    size_t src = ((size_t)(b * S + s)) * 3072 + h * 64 + 2 * i;
    size_t dst = ((size_t)((b * 16 + h) * S + s)) * 64 + 2 * i;
    float a0 = b2f(qkv[src]), a1 = b2f(qkv[src + 1]);
    qr[dst] = f2b(a0 * c - a1 * sn);
    qr[dst + 1] = f2b(a0 * sn + a1 * c);
    float b0 = b2f(qkv[src + 1024]), b1 = b2f(qkv[src + 1025]);
    kr[dst] = f2b(b0 * c - b1 * sn);
    kr[dst + 1] = f2b(b0 * sn + b1 * c);
  }
  for (int hh = 0; hh < 4; ++hh) {
    int h = h0 + hh;
    __syncthreads();
    for (int cc = threadIdx.x; cc < 512; cc += 256) {
      int tl = cc >> 3, d8 = cc & 7;
      bh8 val = *(const bh8*)(qkv + ((size_t)(b * S + s0 + tl)) * 3072 + 2048 +
                              h * 64 + d8 * 8);
#pragma unroll
      for (int j = 0; j < 8; ++j) tile[tl][d8 * 8 + j] = (u16)val[j];
    }
    __syncthreads();
    for (int cc = threadIdx.x; cc < 512; cc += 256) {
      int d = cc >> 3, pg = cc & 7;
      int sbase = 16 * (pg >> 2) + 4 * (pg & 3);
      bh8 o;
#pragma unroll
      for (int j = 0; j < 8; ++j)
        o[j] = (short)tile[sbase + (j & 3) + ((j >> 2) << 5)][d];
      *(bh8*)(vt + ((size_t)((b * 16 + h) * 64 + d)) * S + s0 + pg * 8) = o;
    }
  }
}

// ---------------------------------------------------------------------------
// Flash attention (causal), paired q-tiles, hoisted shared K/V frags,
// MFMA row-sum (l in C-layout), fma-folded scale, defer-max.
// Grid: (B*NH, nq/2). 4 waves x 16 q-rows, KVBLK=64, dbuf staging.
// ---------------------------------------------------------------------------
__global__ __launch_bounds__(256) void attn_fwd(
    const u16* __restrict__ qr, const u16* __restrict__ kr,
    const u16* __restrict__ vt, u16* __restrict__ ob, int S, int NHc) {
  __shared__ u16 Ks[2][64 * 64];
  __shared__ u16 Vs[2][64 * 64];   // V^T tile, column-permuted
  const int lane = threadIdx.x & 63;
  const int wid = threadIdx.x >> 6;
  const int g = lane >> 4;
  const int l15 = lane & 15;
  const int bh = blockIdx.x;
  const int ia = blockIdx.y;
  const int nq = S / 64;
  const int qa0 = ia * 64;                 // light q-tile
  const int qb0 = (nq - 1 - ia) * 64;      // heavy q-tile
  const int b = bh / NHc, h = bh % NHc;
  const u16* qbase = qr + (size_t)bh * S * 64;
  const u16* kb = kr + (size_t)bh * S * 64;
  const u16* vb = vt + (size_t)bh * 64 * S;
  const float SC = 0.015625f * LOG2E;  // both ref scales, log2 domain
  const int rr = lane >> 3;
  const int b8s = (lane & 7) ^ rr;

  bh8 ONES;
#pragma unroll
  for (int j = 0; j < 8; ++j) ONES[j] = (short)0x3f80;  // bf16 1.0

  bh8 qfA[2], qfB[2];
  {
    const u16* qp = qbase + (size_t)(qa0 + wid * 16 + l15) * 64 + g * 8;
    qfA[0] = *(const bh8*)qp;
    qfA[1] = *(const bh8*)(qp + 32);
    qp = qbase + (size_t)(qb0 + wid * 16 + l15) * 64 + g * 8;
    qfB[0] = *(const bh8*)qp;
    qfB[1] = *(const bh8*)(qp + 32);
  }
  fv4 oaccA[4] = {}, oaccB[4] = {};
  fv4 lA = {}, lB = {};                // row-sums, C-layout (row = 4g+r)
  float mA = -1e30f, mB = -1e30f;
  const int nktB = nq - ia;

  auto stage = [&](int buf, int j0) {
#pragma unroll
    for (int i = 0; i < 2; ++i) {
      int c = wid * 2 + i;
      int row = c * 8 + rr;
      GLD16(kb + (size_t)(j0 + row) * 64 + b8s * 8, &Ks[buf][c * 512]);
      GLD16(vb + (size_t)row * S + j0 + b8s * 8, &Vs[buf][c * 512]);
    }
  };
  stage(0, 0);

  auto process = [&](const bh8 (&kf)[2][4], const bh8 (&vf)[2][4], int j0,
                     int q0x, bh8* qf, fv4* oacc, float& mrow, fv4& lrowC) {
    const int q_my = q0x + wid * 16 + l15;
    fv4 st[4] = {};
    __builtin_amdgcn_s_setprio(1);
#pragma unroll
    for (int ks = 0; ks < 2; ++ks)
#pragma unroll
      for (int jt = 0; jt < 4; ++jt)
        st[jt] = mfma16(kf[ks][jt], qf[ks], st[jt]);
    __builtin_amdgcn_s_setprio(0);

    // mask + max on RAW scores (SC > 0 so max commutes with the scale)
    float sr[4][4];
    float mloc = -1e30f;
    const int jb = j0 + 4 * g;
    if (j0 + 63 > q0x + wid * 16) {   // diagonal tile
#pragma unroll
      for (int jt = 0; jt < 4; ++jt)
#pragma unroll
        for (int r = 0; r < 4; ++r) {
          int j = jb + jt * 16 + r;
          float s = (j <= q_my) ? st[jt][r] : -1e30f;
          sr[jt][r] = s;
          mloc = fmaxf(mloc, s);
        }
    } else {                          // interior: fully visible
#pragma unroll
      for (int jt = 0; jt < 4; ++jt)
#pragma unroll
        for (int r = 0; r < 4; ++r) {
          sr[jt][r] = st[jt][r];
          mloc = fmaxf(mloc, st[jt][r]);
        }
    }
    mloc = fmaxf(mloc, __shfl_xor(mloc, 16));
    mloc = fmaxf(mloc, __shfl_xor(mloc, 32));
    mloc *= SC;                        // scaled row max (log2 domain)
    bool defer = __all(mloc <= mrow + 8.f);   // T13
    if (!defer) {
      float mnew = fmaxf(mrow, mloc);
      float sfac = exp2f(mrow - mnew);
      mrow = mnew;
      float sfC[4];
#pragma unroll
      for (int r = 0; r < 4; ++r) sfC[r] = __shfl(sfac, g * 4 + r);
#pragma unroll
      for (int dt = 0; dt < 4; ++dt)
#pragma unroll
        for (int r = 0; r < 4; ++r) oacc[dt][r] *= sfC[r];
#pragma unroll
      for (int r = 0; r < 4; ++r) lrowC[r] *= sfC[r];
    }
    float p[4][4];
#pragma unroll
    for (int jt = 0; jt < 4; ++jt)
#pragma unroll
      for (int r = 0; r < 4; ++r)
        p[jt][r] = exp2f(fmaf(sr[jt][r], SC, -mrow));

    // PV + row-sum via MFMA (pa slot (g,i) <-> logical j matching permuted V)
    __builtin_amdgcn_s_setprio(1);
    fv4 racc = {};
#pragma unroll
    for (int ks = 0; ks < 2; ++ks) {
      uv4 w;
      w[0] = cvtpk(p[ks][0], p[ks][1]);
      w[1] = cvtpk(p[ks][2], p[ks][3]);
      w[2] = cvtpk(p[ks + 2][0], p[ks + 2][1]);
      w[3] = cvtpk(p[ks + 2][2], p[ks + 2][3]);
      bh8 pa = __builtin_bit_cast(bh8, w);
      racc = mfma16(pa, ONES, racc);
#pragma unroll
      for (int dt = 0; dt < 4; ++dt)
        oacc[dt] = mfma16(pa, vf[ks][dt], oacc[dt]);
    }
    __builtin_amdgcn_s_setprio(0);
#pragma unroll
    for (int r = 0; r < 4; ++r) lrowC[r] += racc[r];
  };

  for (int kt = 0; kt < nktB; ++kt) {
    const int j0 = kt * 64;
    __syncthreads();
    if (kt + 1 < nktB) stage((kt + 1) & 1, (kt + 1) * 64);
    const u16* Kc = Ks[kt & 1];
    const u16* Vc = Vs[kt & 1];
    bh8 kf[2][4], vf[2][4];
#pragma unroll
    for (int ks = 0; ks < 2; ++ks) {
      int b8 = ks * 4 + g;
#pragma unroll
      for (int jt = 0; jt < 4; ++jt)
        kf[ks][jt] = lds_frag(Kc, jt * 16 + l15, b8);
#pragma unroll
      for (int dt = 0; dt < 4; ++dt)
        vf[ks][dt] = lds_frag(Vc, dt * 16 + l15, b8);
    }
    process(kf, vf, j0, qb0, qfB, oaccB, mB, lB);
    if (kt <= ia) process(kf, vf, j0, qa0, qfA, oaccA, mA, lA);
  }

  auto wout = [&](fv4* oacc, fv4 lrowC, int q0x) {
#pragma unroll
    for (int dt = 0; dt < 4; ++dt)
#pragma unroll
      for (int r = 0; r < 4; ++r) {
        int row = q0x + wid * 16 + g * 4 + r;
        int col = dt * 16 + l15;
        ob[((size_t)b * S + row) * 1024 + h * 64 + col] =
            f2b(oacc[dt][r] / lrowC[r]);
      }
  };
  wout(oaccA, lA, qa0);
  wout(oaccB, lB, qb0);
}

// ---------------------------------------------------------------------------
// Gate + fused ffn-rmsnorm: computes top-2 AND writes hf_b = bf16(rmsnorm).
// ---------------------------------------------------------------------------
__global__ __launch_bounds__(256) void gate_topk(
    const float* __restrict__ x2, const float* __restrict__ nw,
    const float* __restrict__ gw, const float* __restrict__ gb,
    int* __restrict__ topk_e, float* __restrict__ topk_w,
    u16* __restrict__ hf) {
  int t = blockIdx.x * 4 + (threadIdx.x >> 6);
  int lane = threadIdx.x & 63;
  const float* xr = x2 + (size_t)t * 1024;
  float hv[16];
  float ss = 0.f;
#pragma unroll
  for (int i = 0; i < 4; ++i) {
    fv4 v = *(const fv4*)(xr + lane * 16 + i * 4);
#pragma unroll
    for (int j = 0; j < 4; ++j) {
      hv[i * 4 + j] = v[j];
      ss += v[j] * v[j];
    }
  }
#pragma unroll
  for (int off = 1; off < 64; off <<= 1) ss += __shfl_xor(ss, off);
  float inv = rsqrtf(ss * (1.0f / 1024.f) + 1e-6f);
  const fv4* nwp = (const fv4*)(nw + lane * 16);
#pragma unroll
  for (int i = 0; i < 4; ++i) {
    fv4 wv = nwp[i];
#pragma unroll
    for (int j = 0; j < 4; ++j) hv[i * 4 + j] *= inv * wv[j];
  }
  {  // fused rmsnorm output
    bh8 o0, o1;
#pragma unroll
    for (int j = 0; j < 8; ++j) {
      o0[j] = (short)f2b(hv[j]);
      o1[j] = (short)f2b(hv[8 + j]);
    }
    u16* hp = hf + (size_t)t * 1024 + lane * 16;
    *(bh8*)hp = o0;
    *(bh8*)(hp + 8) = o1;
  }
  float logit[8];
#pragma unroll
  for (int e = 0; e < 8; ++e) {
    const fv4* wp = (const fv4*)(gw + (size_t)e * 1024 + lane * 16);
    float s = 0.f;
#pragma unroll
    for (int i = 0; i < 4; ++i) {
      fv4 wv = wp[i];
#pragma unroll
      for (int j = 0; j < 4; ++j) s += hv[i * 4 + j] * wv[j];
    }
    logit[e] = s;
  }
#pragma unroll
  for (int off = 1; off < 64; off <<= 1)
#pragma unroll
    for (int e = 0; e < 8; ++e) logit[e] += __shfl_xor(logit[e], off);
  if (lane == 0) {
#pragma unroll
    for (int e = 0; e < 8; ++e) logit[e] += gb[e];
    float mx = logit[0];
#pragma unroll
    for (int e = 1; e < 8; ++e) mx = fmaxf(mx, logit[e]);
    float pe[8], se = 0.f;
#pragma unroll
    for (int e = 0; e < 8; ++e) { pe[e] = __expf(logit[e] - mx); se += pe[e]; }
    float rs = 1.f / se;
#pragma unroll
    for (int e = 0; e < 8; ++e) pe[e] *= rs;
    int i0 = 0;
    float b0 = pe[0];
#pragma unroll
    for (int e = 1; e < 8; ++e)
      if (pe[e] > b0) { b0 = pe[e]; i0 = e; }
    int i1 = -1;
    float b1v = -1.f;
#pragma unroll
    for (int e = 0; e < 8; ++e)
      if (e != i0 && pe[e] > b1v) { b1v = pe[e]; i1 = e; }
    topk_e[2 * t] = i0;
    topk_e[2 * t + 1] = i1;
    topk_w[2 * t] = b0;
    topk_w[2 * t + 1] = b1v;
  }
}

// One block, 8 waves: wave e ballot-ranks its tokens (deterministic order),
// thread 0 builds the padded tile map, then all threads fill rowid[2T]
// (compact row index of each token's two expert outputs).
__global__ __launch_bounds__(512) void route_tokens(
    const int* __restrict__ topk_e, int* __restrict__ pos_of,
    int* __restrict__ etok, int* __restrict__ meta, int* __restrict__ rowid,
    int T2) {
  __shared__ int scnt[8], sbase[8];
  const int e = threadIdx.x >> 6;
  const int lane = threadIdx.x & 63;
  int base = 0;
  for (int i0 = 0; i0 < T2; i0 += 128) {
    iv2 te = *(const iv2*)(topk_e + i0 + lane * 2);
    unsigned long long m0 = __ballot(te[0] == e);
    unsigned long long m1 = __ballot(te[1] == e);
    unsigned long long lt = (1ull << lane) - 1;
    int pre = __popcll(m0 & lt) + __popcll(m1 & lt);
    if (te[0] == e) {
      int pos = base + pre;
      etok[e * 4096 + pos] = (i0 >> 1) + lane;
      pos_of[i0 + lane * 2] = pos;
      ++pre;
    }
    if (te[1] == e) {
      int pos = base + pre;
      etok[e * 4096 + pos] = (i0 >> 1) + lane;
      pos_of[i0 + lane * 2 + 1] = pos;
    }
    base += __popcll(m0) + __popcll(m1);
  }
  if (lane == 0) scnt[e] = base;
  __syncthreads();
  if (threadIdx.x == 0) {
    int tt = 0, rb = 0;
#pragma unroll
    for (int e2 = 0; e2 < 8; ++e2) {
      sbase[e2] = rb;
      int c = scnt[e2];
      int nt = (c + 127) >> 7;
      for (int i = 0; i < nt; ++i) {
        meta[16 + tt * 4] = e2;
        meta[17 + tt * 4] = i * 128;
        meta[18 + tt * 4] = c;
        meta[19 + tt * 4] = rb + i * 128;
        ++tt;
      }
      rb += nt * 128;
    }
    meta[0] = tt;
  }
  __syncthreads();
  for (int i = threadIdx.x; i < T2; i += 512)
    rowid[i] = sbase[topk_e[i]] + pos_of[i];
}

__global__ __launch_bounds__(256) void f2b_convert(
    const float* __restrict__ src, u16* __restrict__ dst) {
  size_t i = ((size_t)blockIdx.x * 256 + threadIdx.x) * 8;
  fv4 a = *(const fv4*)(src + i);
  fv4 b = *(const fv4*)(src + i + 4);
  bh8 o;
#pragma unroll
  for (int j = 0; j < 4; ++j) o[j] = (short)f2b(a[j]);
#pragma unroll
  for (int j = 0; j < 4; ++j) o[4 + j] = (short)f2b(b[j]);
  *(bh8*)(dst + i) = o;
}

// f32 [segs*2^seg_shift, 1024] -> bf16 interleaved per 32 rows:
// src row rl of segment e -> dst row e*2^(seg_shift+1) + (rl>>5)*64 + (rl&31)
// + 32*half.  Used to build silu-fusable gate|up weight layouts.
__global__ __launch_bounds__(256) void f2b_convert_ilv(
    const float* __restrict__ src, u16* __restrict__ dst, int half,
    int seg_shift) {
  size_t i = ((size_t)blockIdx.x * 256 + threadIdx.x) * 8;
  int r = (int)(i >> 10), col = (int)(i & 1023);
  int rl = r & ((1 << seg_shift) - 1), e = r >> seg_shift;
  int dstrow = (e << (seg_shift + 1)) + ((rl >> 5) << 6) + (rl & 31) +
               (half << 5);
  fv4 a = *(const fv4*)(src + i);
  fv4 b = *(const fv4*)(src + i + 4);
  bh8 o;
#pragma unroll
  for (int j = 0; j < 4; ++j) o[j] = (short)f2b(a[j]);
#pragma unroll
  for (int j = 0; j < 4; ++j) o[4 + j] = (short)f2b(b[j]);
  *(bh8*)(dst + (size_t)dstrow * 1024 + col) = o;
}

// ---------------------------------------------------------------------------
extern "C" void kernel_launch(void* const* d_in, const int* in_sizes, int n_in,
                              void* d_out, int out_size, void* d_ws,
                              size_t ws_size, hipStream_t stream) {
  (void)in_sizes; (void)n_in; (void)out_size; (void)ws_size;
  const int Sc = 2048, Dc = 1024, NHc = 16, Tc = 4096, SH = 2048;

  const float* x   = (const float*)d_in[0];
  const float* fc  = (const float*)d_in[1];
  const float* fs  = (const float*)d_in[2];
  const float* wq  = (const float*)d_in[4];
  const float* wk  = (const float*)d_in[5];
  const float* wv  = (const float*)d_in[6];
  const float* wo  = (const float*)d_in[7];
  const float* anw = (const float*)d_in[8];
  const float* fnw = (const float*)d_in[9];
  const float* gw  = (const float*)d_in[10];
  const float* gb  = (const float*)d_in[11];
  const float* w1  = (const float*)d_in[12];
  const float* b1  = (const float*)d_in[13];
  const float* w2  = (const float*)d_in[14];
  const float* b2  = (const float*)d_in[15];
  const float* w3  = (const float*)d_in[16];
  const float* b3  = (const float*)d_in[17];
  const float* sgw = (const float*)d_in[18];
  const float* suw = (const float*)d_in[19];
  const float* sdw = (const float*)d_in[20];
  float* out = (float*)d_out;

  char* base = (char*)d_ws;
  size_t off = 0;
  auto alloc = [&](size_t bytes) -> void* {
    void* p = base + off;
    off += (bytes + 255) & ~(size_t)255;
    return p;
  };
  // weights: wqkv+wo FIRST (their region is reused as hf_b after wo-gemm)
  u16* wqkv_b = (u16*)alloc(2ull * 3072 * 1024);     // 6.29 MB
  u16* wo_b   = (u16*)alloc(2ull * 1024 * 1024);     // 2.10 MB
  u16* sgu_b  = (u16*)alloc(2ull * 4096 * 1024);     // 8.39 MB (interleaved)
  u16* sdw_b  = (u16*)alloc(2ull * 1024 * 2048);     // 4.19 MB
  u16* w13_b  = (u16*)alloc(2ull * 8 * 2048 * 1024); // 33.6 MB (interleaved)
  u16* w2_b   = (u16*)alloc(2ull * 8 * 1024 * 1024); // 16.8 MB
  // region A: qkv_out (25.2) -> eo (18.6)
  char* regA = (char*)alloc(2ull * Tc * 4096);
  // region B: h_b/qr/kr/vt/o_b (33.6) -> a13 (18.6)
  char* regB = (char*)alloc(2ull * (size_t)MAX_TILES * 128 * 2048);
  float* x2  = (float*)alloc(4ull * Tc * Dc);        // 16.8 MB
  u16* hs_b  = (u16*)alloc(2ull * Tc * SH);          // 16.8 MB
  int* topk_e = (int*)alloc(2ull * Tc * 4);
  float* topk_w = (float*)alloc(2ull * Tc * 4);
  int* pos_of = (int*)alloc(2ull * Tc * 4);
  int* rowid = (int*)alloc(2ull * Tc * 4);
  int* etok = (int*)alloc(8ull * 4096 * 4);
  int* meta = (int*)alloc(512 * 4);

  u16* qkv_out = (u16*)regA;
  u16* eo_c    = (u16*)regA;
  u16* h_b  = (u16*)regB;
  u16* qr   = (u16*)regB;
  u16* kr   = (u16*)(regB + 2ull * Tc * Dc);
  u16* vt_  = (u16*)(regB + 4ull * Tc * Dc);
  u16* o_b  = (u16*)(regB + 6ull * Tc * Dc);
  u16* a13_c = (u16*)regB;
  u16* hf_b = wqkv_b;  // overlays wqkv+wo after attention branch done

  auto conv = [&](const float* s, u16* d, size_t n) {
    f2b_convert<<<dim3((unsigned)(n / 2048)), 256, 0, stream>>>(s, d);
  };
  conv(wq, wqkv_b, (size_t)Dc * Dc);
  conv(wk, wqkv_b + 1048576, (size_t)Dc * Dc);
  conv(wv, wqkv_b + 2097152, (size_t)Dc * Dc);
  conv(wo, wo_b, (size_t)Dc * Dc);
  conv(sdw, sdw_b, (size_t)Dc * SH);
  conv(w2, w2_b, 8ull * 1024 * 1024);
  f2b_convert_ilv<<<1024, 256, 0, stream>>>(sgw, sgu_b, 0, 11);
  f2b_convert_ilv<<<1024, 256, 0, stream>>>(suw, sgu_b, 1, 11);
  f2b_convert_ilv<<<4096, 256, 0, stream>>>(w1, w13_b, 0, 10);
  f2b_convert_ilv<<<4096, 256, 0, stream>>>(w3, w13_b, 1, 10);

  // ---- attention branch ----
  rmsnorm_bf16<<<Tc, 256, 0, stream>>>(x, anw, h_b);
  gemm_bt<0><<<dim3(3072 / 128, Tc / 128), 256, 0, stream>>>(
      h_b, wqkv_b, Tc, 3072, Dc, qkv_out, nullptr, nullptr, nullptr, nullptr,
      nullptr, nullptr);
  rope_repack<<<dim3(Sc / 64, 2, 4), 256, 0, stream>>>(qkv_out, fc, fs, qr, kr,
                                                       vt_, Sc);
  attn_fwd<<<dim3(2 * NHc, Sc / 128), 256, 0, stream>>>(qr, kr, vt_, o_b, Sc,
                                                        NHc);
  gemm_bt<1, 64><<<dim3(Dc / 128, Tc / 64), 256, 0, stream>>>(
      o_b, wo_b, Tc, Dc, Dc, nullptr, x2, x, nullptr, nullptr, nullptr,
      nullptr);

  // ---- ffn branch ----
  gate_topk<<<Tc / 4, 256, 0, stream>>>(x2, fnw, gw, gb, topk_e, topk_w,
                                        hf_b);
  route_tokens<<<1, 512, 0, stream>>>(topk_e, pos_of, etok, meta, rowid,
                                      2 * Tc);

  // shared expert: fused gate|up GEMM with silu epilogue -> hs
  gemm_bt<7><<<dim3(4096 / 128, Tc / 128), 256, 0, stream>>>(
      hf_b, sgu_b, Tc, 4096, Dc, hs_b, nullptr, nullptr, nullptr, nullptr,
      nullptr, nullptr);

  // sparse MoE: gather w13 GEMM with fused silu+biases -> compact a13, w2
  gemm_bt<8><<<dim3(2048 / 128, MAX_TILES), 256, 0, stream>>>(
      hf_b, w13_b, Tc, 2048, Dc, a13_c, nullptr, b1, b3, nullptr, meta, etok);
  gemm_bt<6><<<dim3(Dc / 128, MAX_TILES), 256, 0, stream>>>(
      a13_c, w2_b, /*lda=*/1024, Dc, 1024, eo_c, nullptr, nullptr, nullptr,
      b2, meta, etok);

  // final: out = x2 + hs @ sdw^T + w0*eo[r0] + w1*eo[r1]
  gemm_bt<9, 64><<<dim3(Dc / 128, Tc / 64), 256, 0, stream>>>(
      hs_b, sdw_b, Tc, Dc, SH, eo_c, out, x2, nullptr, topk_w, rowid,
      nullptr);
}

// Round 8
// 406.597 us; speedup vs baseline: 3.0790x; 1.0203x over previous
//
#include <hip/hip_runtime.h>

// ---------------------------------------------------------------------------
// TransformerBlock on MI355X (gfx950), round 8:
//  - GEMM K-loop: cross-tile prefetch with counted s_waitcnt vmcnt(N) +
//    raw s_barrier + LDS double-buffer (T3/T4 minimum 2-phase). Loads for
//    tile t+1 stay in flight across tile t's MFMA -> HBM latency hidden
//    in-block instead of relying on (absent) multi-block TLP.
//  - everything else unchanged from round 7 (XCD swizzle, fused epilogues,
//    paired-q-tile attention, atomic-free routing).
// ---------------------------------------------------------------------------

typedef unsigned short u16;
typedef __attribute__((ext_vector_type(8))) short bh8;   // 8 x bf16
typedef __attribute__((ext_vector_type(4))) float fv4;
typedef __attribute__((ext_vector_type(4))) unsigned uv4;
typedef __attribute__((ext_vector_type(2))) int iv2;

#define LOG2E 1.4426950408889634f
#define MAX_TILES 71

__device__ __forceinline__ float b2f(u16 u) {
  return __builtin_bit_cast(float, ((unsigned)u) << 16);
}
__device__ __forceinline__ u16 f2b(float f) {
  unsigned x = __builtin_bit_cast(unsigned, f);
  return (u16)((x + 0x7fffu + ((x >> 16) & 1u)) >> 16);  // RNE
}
__device__ __forceinline__ fv4 mfma16(bh8 a, bh8 b, fv4 c) {
  return __builtin_amdgcn_mfma_f32_16x16x32_bf16(a, b, c, 0, 0, 0);
}
__device__ __forceinline__ unsigned cvtpk(float lo, float hi) {
  unsigned r;
  asm("v_cvt_pk_bf16_f32 %0, %1, %2" : "=v"(r) : "v"(lo), "v"(hi));
  return r;
}

// Bijective XCD-chunk swizzle (m204): blocks resident on one XCD cover a
// contiguous chunk of logical (y,x) space -> A-tiles/weights fetched once.
__device__ __forceinline__ void xcd_swizzle(int& bx, int& by) {
  int gx = gridDim.x;
  int nwg = gx * gridDim.y;
  int flat = by * gx + bx;
  int q = nwg >> 3, r = nwg & 7;
  int xcd = flat & 7, idx = flat >> 3;
  int swz = (xcd < r ? xcd * (q + 1) : r * (q + 1) + (xcd - r) * q) + idx;
  by = swz / gx;
  bx = swz - by * gx;
}

#define GLD16(g, l)                                                        \
  __builtin_amdgcn_global_load_lds(                                        \
      (const __attribute__((address_space(1))) void*)(g),                  \
      (__attribute__((address_space(3))) void*)(l), 16, 0, 0)

// Read one MFMA fragment (16B) from a [rows][64] bf16 LDS tile whose rows are
// 128B and whose 16B blocks are XOR-swizzled by (row&7).
__device__ __forceinline__ bh8 lds_frag(const u16* base, int row, int b8) {
  int off = row * 128 + ((b8 * 16) ^ ((row & 7) << 4));
  return *(const bh8*)((const char*)base + off);
}

// ---------------------------------------------------------------------------
// Generic GEMM: C[M,N] = A[M,K] (bf16) @ B[N,K]^T (bf16), f32 accumulate.
// TM: A-tile rows (128 or 64). B-tile is always 128 cols.
// MODE 0: Cb = bf16(gemm)
// MODE 1: Cf = add1 + gemm
// MODE 6: compact-A grouped MoE (w2): lda via M; Cb = bf16(gemm + bias_e)
// MODE 7: interleaved silu (shared expert): Cb[.,N/2] = silu(g)*u
// MODE 8: gather-A grouped MoE w13, interleaved silu + biases:
//         Cb[.,N/2] = silu(g + b1[e]) * (u + b3[e])   (add1=b1, add2=b3)
// MODE 9: final: Cf = add1 + gemm + w0*eo[r0] + w1*eo[r1]
//         (Cb=eo read-only, tmeta=rowid[2T], bias=topk_w[2T])
// K-loop: prefetch-next + counted vmcnt + raw barriers, LDS double-buffered.
// ---------------------------------------------------------------------------
template <int MODE, int TM = 128>
__global__ __launch_bounds__(256) void gemm_bt(
    const u16* __restrict__ A, const u16* __restrict__ B, int M, int N, int K,
    u16* __restrict__ Cb, float* __restrict__ Cf,
    const float* __restrict__ add1, const float* __restrict__ add2,
    const float* __restrict__ bias, const int* __restrict__ tmeta,
    const int* __restrict__ etok) {
  constexpr int MR = TM / 32;  // M-frags per wave: 128->4, 64->2
  __shared__ u16 As[2][TM * 64];
  __shared__ u16 Bs[2][128 * 64];
  int bx = blockIdx.x, by = blockIdx.y;
  xcd_swizzle(bx, by);
  const int lane = threadIdx.x & 63;
  const int wid = threadIdx.x >> 6;
  const int wr = wid >> 1, wc = wid & 1;
  const int n0 = bx * 128;
  const int rr = lane >> 3;
  const int b8s = (lane & 7) ^ rr;
  const int ldA = (MODE == 6) ? M : K;

  int m0 = 0, e = 0, m0l = 0, cnt = 0, row0 = 0;
  const u16* Bp = B;
  if constexpr (MODE == 6 || MODE == 8) {
    int tile = by;
    if (tile >= tmeta[0]) return;
    e = tmeta[16 + tile * 4];
    m0l = tmeta[17 + tile * 4];
    cnt = tmeta[18 + tile * 4];
    row0 = tmeta[19 + tile * 4];
    Bp = B + (size_t)e * N * K;
  } else {
    m0 = by * TM;
  }

  const u16* Arow[MR];
  const u16* Brow[4];
#pragma unroll
  for (int i = 0; i < MR; ++i) {
    int c = wid * MR + i;
    int row = c * 8 + rr;
    if constexpr (MODE == 8) {
      int li = m0l + row;
      li = li < cnt ? li : cnt - 1;
      int tok = etok[e * 4096 + li];
      Arow[i] = A + (size_t)tok * ldA + b8s * 8;
    } else if constexpr (MODE == 6) {
      Arow[i] = A + (size_t)(row0 + row) * ldA + b8s * 8;
    } else {
      Arow[i] = A + (size_t)(m0 + row) * ldA + b8s * 8;
    }
  }
#pragma unroll
  for (int i = 0; i < 4; ++i)
    Brow[i] = Bp + (size_t)(n0 + (wid * 4 + i) * 8 + rr) * K + b8s * 8;

  fv4 acc[MR][4] = {};
  const int nt = K >> 6;

  // prologue: stage tile 0 into buffer 0
#pragma unroll
  for (int i = 0; i < MR; ++i)
    GLD16(Arow[i], &As[0][(wid * MR + i) * 512]);
#pragma unroll
  for (int i = 0; i < 4; ++i)
    GLD16(Brow[i], &Bs[0][(wid * 4 + i) * 512]);

  for (int t = 0; t < nt; ++t) {
    const int cur = t & 1;
    if (t + 1 < nt) {
      const int k0 = (t + 1) * 64;
#pragma unroll
      for (int i = 0; i < MR; ++i)
        GLD16(Arow[i] + k0, &As[cur ^ 1][(wid * MR + i) * 512]);
#pragma unroll
      for (int i = 0; i < 4; ++i)
        GLD16(Brow[i] + k0, &Bs[cur ^ 1][(wid * 4 + i) * 512]);
      // wait only for the OLDEST (cur-tile) loads; next-tile stays in flight
      if constexpr (MR == 4)
        asm volatile("s_waitcnt vmcnt(8)" ::: "memory");
      else
        asm volatile("s_waitcnt vmcnt(6)" ::: "memory");
    } else {
      asm volatile("s_waitcnt vmcnt(0)" ::: "memory");
    }
    __builtin_amdgcn_s_barrier();          // buf[cur] visible to all waves
    __builtin_amdgcn_sched_barrier(0);     // pin ds_reads below barrier

#pragma unroll
    for (int ks = 0; ks < 2; ++ks) {
      int b8 = ks * 4 + (lane >> 4);
      bh8 af[MR], bf[4];
#pragma unroll
      for (int mi = 0; mi < MR; ++mi)
        af[mi] = lds_frag(As[cur], wr * (16 * MR) + mi * 16 + (lane & 15), b8);
#pragma unroll
      for (int ni = 0; ni < 4; ++ni)
        bf[ni] = lds_frag(Bs[cur], wc * 64 + ni * 16 + (lane & 15), b8);
      __builtin_amdgcn_s_setprio(1);
#pragma unroll
      for (int mi = 0; mi < MR; ++mi)
#pragma unroll
        for (int ni = 0; ni < 4; ++ni)
          acc[mi][ni] = mfma16(af[mi], bf[ni], acc[mi][ni]);
      __builtin_amdgcn_s_setprio(0);
    }
    __builtin_amdgcn_sched_barrier(0);     // pin reads above barrier
    __builtin_amdgcn_s_barrier();          // all waves done reading buf[cur]
    __builtin_amdgcn_sched_barrier(0);     // pin next stage below barrier
  }

  const int rbase = (MODE == 6 || MODE == 8) ? row0 : m0;
  const int r0b = rbase + wr * (16 * MR) + (lane >> 4) * 4;
  const int c0b = n0 + wc * 64 + (lane & 15);

  if constexpr (MODE == 7 || MODE == 8) {
    const int OUTN = N >> 1;
    const int colb = (n0 >> 1) + wc * 32;
    const float* bb1 = nullptr;
    const float* bb3 = nullptr;
    if constexpr (MODE == 8) {
      bb1 = add1 + (size_t)e * OUTN;
      bb3 = add2 + (size_t)e * OUTN;
    }
#pragma unroll
    for (int mi = 0; mi < MR; ++mi) {
#pragma unroll
      for (int ni = 0; ni < 2; ++ni) {
        int c = colb + ni * 16 + (lane & 15);
#pragma unroll
        for (int r = 0; r < 4; ++r) {
          int row = r0b + mi * 16 + r;
          float xg = acc[mi][ni][r];
          float yu = acc[mi][ni + 2][r];
          if constexpr (MODE == 8) {
            xg += bb1[c];
            yu += bb3[c];
          }
          float s = xg / (1.f + __expf(-xg));
          Cb[(size_t)row * OUTN + c] = f2b(s * yu);
        }
      }
    }
  } else if constexpr (MODE == 9) {
#pragma unroll
    for (int mi = 0; mi < MR; ++mi) {
#pragma unroll
      for (int r = 0; r < 4; ++r) {
        int row = r0b + mi * 16 + r;
        int g0 = tmeta[2 * row], g1 = tmeta[2 * row + 1];
        float w0 = bias[2 * row], w1 = bias[2 * row + 1];
        const u16* e0p = Cb + (size_t)g0 * 1024;
        const u16* e1p = Cb + (size_t)g1 * 1024;
#pragma unroll
        for (int ni = 0; ni < 4; ++ni) {
          int c = c0b + ni * 16;
          size_t idx = (size_t)row * N + c;
          Cf[idx] = add1[idx] + acc[mi][ni][r] + w0 * b2f(e0p[c]) +
                    w1 * b2f(e1p[c]);
        }
      }
    }
  } else {
    const float* bb = nullptr;
    if constexpr (MODE == 6) bb = bias + (size_t)e * N;
#pragma unroll
    for (int mi = 0; mi < MR; ++mi) {
#pragma unroll
      for (int ni = 0; ni < 4; ++ni) {
        int c = c0b + ni * 16;
#pragma unroll
        for (int r = 0; r < 4; ++r) {
          int row = r0b + mi * 16 + r;
          size_t idx = (size_t)row * N + c;
          float v = acc[mi][ni][r];
          if constexpr (MODE == 0) Cb[idx] = f2b(v);
          else if constexpr (MODE == 1) Cf[idx] = add1[idx] + v;
          else Cb[idx] = f2b(v + bb[c]);
        }
      }
    }
  }
}

// ---------------------------------------------------------------------------
// RMSNorm: f32 [T,1024] -> bf16 [T,1024], one block per token.
// ---------------------------------------------------------------------------
__global__ __launch_bounds__(256) void rmsnorm_bf16(
    const float* __restrict__ x, const float* __restrict__ w,
    u16* __restrict__ out) {
  int t = blockIdx.x;
  const float* xr = x + (size_t)t * 1024;
  fv4 v = *(const fv4*)(xr + threadIdx.x * 4);
  float ss = v[0] * v[0] + v[1] * v[1] + v[2] * v[2] + v[3] * v[3];
#pragma unroll
  for (int off = 1; off < 64; off <<= 1) ss += __shfl_xor(ss, off);
  __shared__ float red[4];
  int lane = threadIdx.x & 63, wid = threadIdx.x >> 6;
  if (lane == 0) red[wid] = ss;
  __syncthreads();
  float inv = rsqrtf((red[0] + red[1] + red[2] + red[3]) * (1.0f / 1024.f) + 1e-6f);
  u16* op = out + (size_t)t * 1024 + threadIdx.x * 4;
  const float* wp = w + threadIdx.x * 4;
#pragma unroll
  for (int i = 0; i < 4; ++i) op[i] = f2b(v[i] * inv * wp[i]);
}

// ---------------------------------------------------------------------------
// RoPE + repack from fused qkv [T,3072]:
//   q,k -> rotated [B,NH,S,64]; v -> vt [B,NH,64,S] (transposed AND column-
//   permuted per 64-block: physical group pg=4ks+g holds logical j
//   {16ks+4g+r, 16ks+32+4g+r}).  Grid: (S/64, B, NH/4).
// ---------------------------------------------------------------------------
__global__ __launch_bounds__(256) void rope_repack(
    const u16* __restrict__ qkv, const float* __restrict__ fc,
    const float* __restrict__ fs, u16* __restrict__ qr, u16* __restrict__ kr,
    u16* __restrict__ vt, int S) {
  __shared__ u16 tile[64][65];
  const int s0 = blockIdx.x * 64;
  const int b = blockIdx.y;
  const int h0 = blockIdx.z * 4;
#pragma unroll 4
  for (int it = 0; it < 32; ++it) {
    int idx = threadIdx.x + it * 256;
    int tl = idx >> 7, rem = idx & 127;
    int h = h0 + (rem >> 5), i = rem & 31;
    int s = s0 + tl;
    float c = fc[s * 32 + i], sn = fs[s * 32 + i];
    size_t src = ((size_t)(b * S + s)) * 3072 + h * 64 + 2 * i;
    size_t dst = ((size_t)((b * 16 + h) * S + s)) * 64 + 2 * i;
    float a0 = b2f(qkv[src]), a1 = b2f(qkv[src + 1]);
    qr[dst] = f2b(a0 * c - a1 * sn);
    qr[dst + 1] = f2b(a0 * sn + a1 * c);
    float b0 = b2f(qkv[src + 1024]), b1 = b2f(qkv[src + 1025]);
    kr[dst] = f2b(b0 * c - b1 * sn);
    kr[dst + 1] = f2b(b0 * sn + b1 * c);
  }
  for (int hh = 0; hh < 4; ++hh) {
    int h = h0 + hh;
    __syncthreads();
    for (int cc = threadIdx.x; cc < 512; cc += 256) {
      int tl = cc >> 3, d8 = cc & 7;
      bh8 val = *(const bh8*)(qkv + ((size_t)(b * S + s0 + tl)) * 3072 + 2048 +
                              h * 64 + d8 * 8);
#pragma unroll
      for (int j = 0; j < 8; ++j) tile[tl][d8 * 8 + j] = (u16)val[j];
    }
    __syncthreads();
    for (int cc = threadIdx.x; cc < 512; cc += 256) {
      int d = cc >> 3, pg = cc & 7;
      int sbase = 16 * (pg >> 2) + 4 * (pg & 3);
      bh8 o;
#pragma unroll
      for (int j = 0; j < 8; ++j)
        o[j] = (short)tile[sbase + (j & 3) + ((j >> 2) << 5)][d];
      *(bh8*)(vt + ((size_t)((b * 16 + h) * 64 + d)) * S + s0 + pg * 8) = o;
    }
  }
}

// ---------------------------------------------------------------------------
// Flash attention (causal), paired q-tiles, hoisted shared K/V frags,
// MFMA row-sum (l in C-layout), fma-folded scale, defer-max.
// Grid: (B*NH, nq/2). 4 waves x 16 q-rows, KVBLK=64, dbuf staging.
// ---------------------------------------------------------------------------
__global__ __launch_bounds__(256) void attn_fwd(
    const u16* __restrict__ qr, const u16* __restrict__ kr,
    const u16* __restrict__ vt, u16* __restrict__ ob, int S, int NHc) {
  __shared__ u16 Ks[2][64 * 64];
  __shared__ u16 Vs[2][64 * 64];   // V^T tile, column-permuted
  const int lane = threadIdx.x & 63;
  const int wid = threadIdx.x >> 6;
  const int g = lane >> 4;
  const int l15 = lane & 15;
  const int bh = blockIdx.x;
  const int ia = blockIdx.y;
  const int nq = S / 64;
  const int qa0 = ia * 64;                 // light q-tile
  const int qb0 = (nq - 1 - ia) * 64;      // heavy q-tile
  const int b = bh / NHc, h = bh % NHc;
  const u16* qbase = qr + (size_t)bh * S * 64;
  const u16* kb = kr + (size_t)bh * S * 64;
  const u16* vb = vt + (size_t)bh * 64 * S;
  const float SC = 0.015625f * LOG2E;  // both ref scales, log2 domain
  const int rr = lane >> 3;
  const int b8s = (lane & 7) ^ rr;

  bh8 ONES;
#pragma unroll
  for (int j = 0; j < 8; ++j) ONES[j] = (short)0x3f80;  // bf16 1.0

  bh8 qfA[2], qfB[2];
  {
    const u16* qp = qbase + (size_t)(qa0 + wid * 16 + l15) * 64 + g * 8;
    qfA[0] = *(const bh8*)qp;
    qfA[1] = *(const bh8*)(qp + 32);
    qp = qbase + (size_t)(qb0 + wid * 16 + l15) * 64 + g * 8;
    qfB[0] = *(const bh8*)qp;
    qfB[1] = *(const bh8*)(qp + 32);
  }
  fv4 oaccA[4] = {}, oaccB[4] = {};
  fv4 lA = {}, lB = {};                // row-sums, C-layout (row = 4g+r)
  float mA = -1e30f, mB = -1e30f;
  const int nktB = nq - ia;

  auto stage = [&](int buf, int j0) {
#pragma unroll
    for (int i = 0; i < 2; ++i) {
      int c = wid * 2 + i;
      int row = c * 8 + rr;
      GLD16(kb + (size_t)(j0 + row) * 64 + b8s * 8, &Ks[buf][c * 512]);
      GLD16(vb + (size_t)row * S + j0 + b8s * 8, &Vs[buf][c * 512]);
    }
  };
  stage(0, 0);

  auto process = [&](const bh8 (&kf)[2][4], const bh8 (&vf)[2][4], int j0,
                     int q0x, bh8* qf, fv4* oacc, float& mrow, fv4& lrowC) {
    const int q_my = q0x + wid * 16 + l15;
    fv4 st[4] = {};
    __builtin_amdgcn_s_setprio(1);
#pragma unroll
    for (int ks = 0; ks < 2; ++ks)
#pragma unroll
      for (int jt = 0; jt < 4; ++jt)
        st[jt] = mfma16(kf[ks][jt], qf[ks], st[jt]);
    __builtin_amdgcn_s_setprio(0);

    // mask + max on RAW scores (SC > 0 so max commutes with the scale)
    float sr[4][4];
    float mloc = -1e30f;
    const int jb = j0 + 4 * g;
    if (j0 + 63 > q0x + wid * 16) {   // diagonal tile
#pragma unroll
      for (int jt = 0; jt < 4; ++jt)
#pragma unroll
        for (int r = 0; r < 4; ++r) {
          int j = jb + jt * 16 + r;
          float s = (j <= q_my) ? st[jt][r] : -1e30f;
          sr[jt][r] = s;
          mloc = fmaxf(mloc, s);
        }
    } else {                          // interior: fully visible
#pragma unroll
      for (int jt = 0; jt < 4; ++jt)
#pragma unroll
        for (int r = 0; r < 4; ++r) {
          sr[jt][r] = st[jt][r];
          mloc = fmaxf(mloc, st[jt][r]);
        }
    }
    mloc = fmaxf(mloc, __shfl_xor(mloc, 16));
    mloc = fmaxf(mloc, __shfl_xor(mloc, 32));
    mloc *= SC;                        // scaled row max (log2 domain)
    bool defer = __all(mloc <= mrow + 8.f);   // T13
    if (!defer) {
      float mnew = fmaxf(mrow, mloc);
      float sfac = exp2f(mrow - mnew);
      mrow = mnew;
      float sfC[4];
#pragma unroll
      for (int r = 0; r < 4; ++r) sfC[r] = __shfl(sfac, g * 4 + r);
#pragma unroll
      for (int dt = 0; dt < 4; ++dt)
#pragma unroll
        for (int r = 0; r < 4; ++r) oacc[dt][r] *= sfC[r];
#pragma unroll
      for (int r = 0; r < 4; ++r) lrowC[r] *= sfC[r];
    }
    float p[4][4];
#pragma unroll
    for (int jt = 0; jt < 4; ++jt)
#pragma unroll
      for (int r = 0; r < 4; ++r)
        p[jt][r] = exp2f(fmaf(sr[jt][r], SC, -mrow));

    // PV + row-sum via MFMA (pa slot (g,i) <-> logical j matching permuted V)
    __builtin_amdgcn_s_setprio(1);
    fv4 racc = {};
#pragma unroll
    for (int ks = 0; ks < 2; ++ks) {
      uv4 w;
      w[0] = cvtpk(p[ks][0], p[ks][1]);
      w[1] = cvtpk(p[ks][2], p[ks][3]);
      w[2] = cvtpk(p[ks + 2][0], p[ks + 2][1]);
      w[3] = cvtpk(p[ks + 2][2], p[ks + 2][3]);
      bh8 pa = __builtin_bit_cast(bh8, w);
      racc = mfma16(pa, ONES, racc);
#pragma unroll
      for (int dt = 0; dt < 4; ++dt)
        oacc[dt] = mfma16(pa, vf[ks][dt], oacc[dt]);
    }
    __builtin_amdgcn_s_setprio(0);
#pragma unroll
    for (int r = 0; r < 4; ++r) lrowC[r] += racc[r];
  };

  for (int kt = 0; kt < nktB; ++kt) {
    const int j0 = kt * 64;
    __syncthreads();
    if (kt + 1 < nktB) stage((kt + 1) & 1, (kt + 1) * 64);
    const u16* Kc = Ks[kt & 1];
    const u16* Vc = Vs[kt & 1];
    bh8 kf[2][4], vf[2][4];
#pragma unroll
    for (int ks = 0; ks < 2; ++ks) {
      int b8 = ks * 4 + g;
#pragma unroll
      for (int jt = 0; jt < 4; ++jt)
        kf[ks][jt] = lds_frag(Kc, jt * 16 + l15, b8);
#pragma unroll
      for (int dt = 0; dt < 4; ++dt)
        vf[ks][dt] = lds_frag(Vc, dt * 16 + l15, b8);
    }
    process(kf, vf, j0, qb0, qfB, oaccB, mB, lB);
    if (kt <= ia) process(kf, vf, j0, qa0, qfA, oaccA, mA, lA);
  }

  auto wout = [&](fv4* oacc, fv4 lrowC, int q0x) {
#pragma unroll
    for (int dt = 0; dt < 4; ++dt)
#pragma unroll
      for (int r = 0; r < 4; ++r) {
        int row = q0x + wid * 16 + g * 4 + r;
        int col = dt * 16 + l15;
        ob[((size_t)b * S + row) * 1024 + h * 64 + col] =
            f2b(oacc[dt][r] / lrowC[r]);
      }
  };
  wout(oaccA, lA, qa0);
  wout(oaccB, lB, qb0);
}

// ---------------------------------------------------------------------------
// Gate + fused ffn-rmsnorm: computes top-2 AND writes hf_b = bf16(rmsnorm).
// ---------------------------------------------------------------------------
__global__ __launch_bounds__(256) void gate_topk(
    const float* __restrict__ x2, const float* __restrict__ nw,
    const float* __restrict__ gw, const float* __restrict__ gb,
    int* __restrict__ topk_e, float* __restrict__ topk_w,
    u16* __restrict__ hf) {
  int t = blockIdx.x * 4 + (threadIdx.x >> 6);
  int lane = threadIdx.x & 63;
  const float* xr = x2 + (size_t)t * 1024;
  float hv[16];
  float ss = 0.f;
#pragma unroll
  for (int i = 0; i < 4; ++i) {
    fv4 v = *(const fv4*)(xr + lane * 16 + i * 4);
#pragma unroll
    for (int j = 0; j < 4; ++j) {
      hv[i * 4 + j] = v[j];
      ss += v[j] * v[j];
    }
  }
#pragma unroll
  for (int off = 1; off < 64; off <<= 1) ss += __shfl_xor(ss, off);
  float inv = rsqrtf(ss * (1.0f / 1024.f) + 1e-6f);
  const fv4* nwp = (const fv4*)(nw + lane * 16);
#pragma unroll
  for (int i = 0; i < 4; ++i) {
    fv4 wv = nwp[i];
#pragma unroll
    for (int j = 0; j < 4; ++j) hv[i * 4 + j] *= inv * wv[j];
  }
  {  // fused rmsnorm output
    bh8 o0, o1;
#pragma unroll
    for (int j = 0; j < 8; ++j) {
      o0[j] = (short)f2b(hv[j]);
      o1[j] = (short)f2b(hv[8 + j]);
    }
    u16* hp = hf + (size_t)t * 1024 + lane * 16;
    *(bh8*)hp = o0;
    *(bh8*)(hp + 8) = o1;
  }
  float logit[8];
#pragma unroll
  for (int e = 0; e < 8; ++e) {
    const fv4* wp = (const fv4*)(gw + (size_t)e * 1024 + lane * 16);
    float s = 0.f;
#pragma unroll
    for (int i = 0; i < 4; ++i) {
      fv4 wv = wp[i];
#pragma unroll
      for (int j = 0; j < 4; ++j) s += hv[i * 4 + j] * wv[j];
    }
    logit[e] = s;
  }
#pragma unroll
  for (int off = 1; off < 64; off <<= 1)
#pragma unroll
    for (int e = 0; e < 8; ++e) logit[e] += __shfl_xor(logit[e], off);
  if (lane == 0) {
#pragma unroll
    for (int e = 0; e < 8; ++e) logit[e] += gb[e];
    float mx = logit[0];
#pragma unroll
    for (int e = 1; e < 8; ++e) mx = fmaxf(mx, logit[e]);
    float pe[8], se = 0.f;
#pragma unroll
    for (int e = 0; e < 8; ++e) { pe[e] = __expf(logit[e] - mx); se += pe[e]; }
    float rs = 1.f / se;
#pragma unroll
    for (int e = 0; e < 8; ++e) pe[e] *= rs;
    int i0 = 0;
    float b0 = pe[0];
#pragma unroll
    for (int e = 1; e < 8; ++e)
      if (pe[e] > b0) { b0 = pe[e]; i0 = e; }
    int i1 = -1;
    float b1v = -1.f;
#pragma unroll
    for (int e = 0; e < 8; ++e)
      if (e != i0 && pe[e] > b1v) { b1v = pe[e]; i1 = e; }
    topk_e[2 * t] = i0;
    topk_e[2 * t + 1] = i1;
    topk_w[2 * t] = b0;
    topk_w[2 * t + 1] = b1v;
  }
}

// One block, 8 waves: wave e ballot-ranks its tokens (deterministic order),
// thread 0 builds the padded tile map, then all threads fill rowid[2T]
// (compact row index of each token's two expert outputs).
__global__ __launch_bounds__(512) void route_tokens(
    const int* __restrict__ topk_e, int* __restrict__ pos_of,
    int* __restrict__ etok, int* __restrict__ meta, int* __restrict__ rowid,
    int T2) {
  __shared__ int scnt[8], sbase[8];
  const int e = threadIdx.x >> 6;
  const int lane = threadIdx.x & 63;
  int base = 0;
  for (int i0 = 0; i0 < T2; i0 += 128) {
    iv2 te = *(const iv2*)(topk_e + i0 + lane * 2);
    unsigned long long m0 = __ballot(te[0] == e);
    unsigned long long m1 = __ballot(te[1] == e);
    unsigned long long lt = (1ull << lane) - 1;
    int pre = __popcll(m0 & lt) + __popcll(m1 & lt);
    if (te[0] == e) {
      int pos = base + pre;
      etok[e * 4096 + pos] = (i0 >> 1) + lane;
      pos_of[i0 + lane * 2] = pos;
      ++pre;
    }
    if (te[1] == e) {
      int pos = base + pre;
      etok[e * 4096 + pos] = (i0 >> 1) + lane;
      pos_of[i0 + lane * 2 + 1] = pos;
    }
    base += __popcll(m0) + __popcll(m1);
  }
  if (lane == 0) scnt[e] = base;
  __syncthreads();
  if (threadIdx.x == 0) {
    int tt = 0, rb = 0;
#pragma unroll
    for (int e2 = 0; e2 < 8; ++e2) {
      sbase[e2] = rb;
      int c = scnt[e2];
      int nt = (c + 127) >> 7;
      for (int i = 0; i < nt; ++i) {
        meta[16 + tt * 4] = e2;
        meta[17 + tt * 4] = i * 128;
        meta[18 + tt * 4] = c;
        meta[19 + tt * 4] = rb + i * 128;
        ++tt;
      }
      rb += nt * 128;
    }
    meta[0] = tt;
  }
  __syncthreads();
  for (int i = threadIdx.x; i < T2; i += 512)
    rowid[i] = sbase[topk_e[i]] + pos_of[i];
}

__global__ __launch_bounds__(256) void f2b_convert(
    const float* __restrict__ src, u16* __restrict__ dst) {
  size_t i = ((size_t)blockIdx.x * 256 + threadIdx.x) * 8;
  fv4 a = *(const fv4*)(src + i);
  fv4 b = *(const fv4*)(src + i + 4);
  bh8 o;
#pragma unroll
  for (int j = 0; j < 4; ++j) o[j] = (short)f2b(a[j]);
#pragma unroll
  for (int j = 0; j < 4; ++j) o[4 + j] = (short)f2b(b[j]);
  *(bh8*)(dst + i) = o;
}

// f32 [segs*2^seg_shift, 1024] -> bf16 interleaved per 32 rows:
// src row rl of segment e -> dst row e*2^(seg_shift+1) + (rl>>5)*64 + (rl&31)
// + 32*half.  Used to build silu-fusable gate|up weight layouts.
__global__ __launch_bounds__(256) void f2b_convert_ilv(
    const float* __restrict__ src, u16* __restrict__ dst, int half,
    int seg_shift) {
  size_t i = ((size_t)blockIdx.x * 256 + threadIdx.x) * 8;
  int r = (int)(i >> 10), col = (int)(i & 1023);
  int rl = r & ((1 << seg_shift) - 1), e = r >> seg_shift;
  int dstrow = (e << (seg_shift + 1)) + ((rl >> 5) << 6) + (rl & 31) +
               (half << 5);
  fv4 a = *(const fv4*)(src + i);
  fv4 b = *(const fv4*)(src + i + 4);
  bh8 o;
#pragma unroll
  for (int j = 0; j < 4; ++j) o[j] = (short)f2b(a[j]);
#pragma unroll
  for (int j = 0; j < 4; ++j) o[4 + j] = (short)f2b(b[j]);
  *(bh8*)(dst + (size_t)dstrow * 1024 + col) = o;
}

// ---------------------------------------------------------------------------
extern "C" void kernel_launch(void* const* d_in, const int* in_sizes, int n_in,
                              void* d_out, int out_size, void* d_ws,
                              size_t ws_size, hipStream_t stream) {
  (void)in_sizes; (void)n_in; (void)out_size; (void)ws_size;
  const int Sc = 2048, Dc = 1024, NHc = 16, Tc = 4096, SH = 2048;

  const float* x   = (const float*)d_in[0];
  const float* fc  = (const float*)d_in[1];
  const float* fs  = (const float*)d_in[2];
  const float* wq  = (const float*)d_in[4];
  const float* wk  = (const float*)d_in[5];
  const float* wv  = (const float*)d_in[6];
  const float* wo  = (const float*)d_in[7];
  const float* anw = (const float*)d_in[8];
  const float* fnw = (const float*)d_in[9];
  const float* gw  = (const float*)d_in[10];
  const float* gb  = (const float*)d_in[11];
  const float* w1  = (const float*)d_in[12];
  const float* b1  = (const float*)d_in[13];
  const float* w2  = (const float*)d_in[14];
  const float* b2  = (const float*)d_in[15];
  const float* w3  = (const float*)d_in[16];
  const float* b3  = (const float*)d_in[17];
  const float* sgw = (const float*)d_in[18];
  const float* suw = (const float*)d_in[19];
  const float* sdw = (const float*)d_in[20];
  float* out = (float*)d_out;

  char* base = (char*)d_ws;
  size_t off = 0;
  auto alloc = [&](size_t bytes) -> void* {
    void* p = base + off;
    off += (bytes + 255) & ~(size_t)255;
    return p;
  };
  // weights: wqkv+wo FIRST (their region is reused as hf_b after wo-gemm)
  u16* wqkv_b = (u16*)alloc(2ull * 3072 * 1024);     // 6.29 MB
  u16* wo_b   = (u16*)alloc(2ull * 1024 * 1024);     // 2.10 MB
  u16* sgu_b  = (u16*)alloc(2ull * 4096 * 1024);     // 8.39 MB (interleaved)
  u16* sdw_b  = (u16*)alloc(2ull * 1024 * 2048);     // 4.19 MB
  u16* w13_b  = (u16*)alloc(2ull * 8 * 2048 * 1024); // 33.6 MB (interleaved)
  u16* w2_b   = (u16*)alloc(2ull * 8 * 1024 * 1024); // 16.8 MB
  // region A: qkv_out (25.2) -> eo (18.6)
  char* regA = (char*)alloc(2ull * Tc * 4096);
  // region B: h_b/qr/kr/vt/o_b (33.6) -> a13 (18.6)
  char* regB = (char*)alloc(2ull * (size_t)MAX_TILES * 128 * 2048);
  float* x2  = (float*)alloc(4ull * Tc * Dc);        // 16.8 MB
  u16* hs_b  = (u16*)alloc(2ull * Tc * SH);          // 16.8 MB
  int* topk_e = (int*)alloc(2ull * Tc * 4);
  float* topk_w = (float*)alloc(2ull * Tc * 4);
  int* pos_of = (int*)alloc(2ull * Tc * 4);
  int* rowid = (int*)alloc(2ull * Tc * 4);
  int* etok = (int*)alloc(8ull * 4096 * 4);
  int* meta = (int*)alloc(512 * 4);

  u16* qkv_out = (u16*)regA;
  u16* eo_c    = (u16*)regA;
  u16* h_b  = (u16*)regB;
  u16* qr   = (u16*)regB;
  u16* kr   = (u16*)(regB + 2ull * Tc * Dc);
  u16* vt_  = (u16*)(regB + 4ull * Tc * Dc);
  u16* o_b  = (u16*)(regB + 6ull * Tc * Dc);
  u16* a13_c = (u16*)regB;
  u16* hf_b = wqkv_b;  // overlays wqkv+wo after attention branch done

  auto conv = [&](const float* s, u16* d, size_t n) {
    f2b_convert<<<dim3((unsigned)(n / 2048)), 256, 0, stream>>>(s, d);
  };
  conv(wq, wqkv_b, (size_t)Dc * Dc);
  conv(wk, wqkv_b + 1048576, (size_t)Dc * Dc);
  conv(wv, wqkv_b + 2097152, (size_t)Dc * Dc);
  conv(wo, wo_b, (size_t)Dc * Dc);
  conv(sdw, sdw_b, (size_t)Dc * SH);
  conv(w2, w2_b, 8ull * 1024 * 1024);
  f2b_convert_ilv<<<1024, 256, 0, stream>>>(sgw, sgu_b, 0, 11);
  f2b_convert_ilv<<<1024, 256, 0, stream>>>(suw, sgu_b, 1, 11);
  f2b_convert_ilv<<<4096, 256, 0, stream>>>(w1, w13_b, 0, 10);
  f2b_convert_ilv<<<4096, 256, 0, stream>>>(w3, w13_b, 1, 10);

  // ---- attention branch ----
  rmsnorm_bf16<<<Tc, 256, 0, stream>>>(x, anw, h_b);
  gemm_bt<0><<<dim3(3072 / 128, Tc / 128), 256, 0, stream>>>(
      h_b, wqkv_b, Tc, 3072, Dc, qkv_out, nullptr, nullptr, nullptr, nullptr,
      nullptr, nullptr);
  rope_repack<<<dim3(Sc / 64, 2, 4), 256, 0, stream>>>(qkv_out, fc, fs, qr, kr,
                                                       vt_, Sc);
  attn_fwd<<<dim3(2 * NHc, Sc / 128), 256, 0, stream>>>(qr, kr, vt_, o_b, Sc,
                                                        NHc);
  gemm_bt<1, 64><<<dim3(Dc / 128, Tc / 64), 256, 0, stream>>>(
      o_b, wo_b, Tc, Dc, Dc, nullptr, x2, x, nullptr, nullptr, nullptr,
      nullptr);

  // ---- ffn branch ----
  gate_topk<<<Tc / 4, 256, 0, stream>>>(x2, fnw, gw, gb, topk_e, topk_w,
                                        hf_b);
  route_tokens<<<1, 512, 0, stream>>>(topk_e, pos_of, etok, meta, rowid,
                                      2 * Tc);

  // shared expert: fused gate|up GEMM with silu epilogue -> hs
  gemm_bt<7><<<dim3(4096 / 128, Tc / 128), 256, 0, stream>>>(
      hf_b, sgu_b, Tc, 4096, Dc, hs_b, nullptr, nullptr, nullptr, nullptr,
      nullptr, nullptr);

  // sparse MoE: gather w13 GEMM with fused silu+biases -> compact a13, w2
  gemm_bt<8><<<dim3(2048 / 128, MAX_TILES), 256, 0, stream>>>(
      hf_b, w13_b, Tc, 2048, Dc, a13_c, nullptr, b1, b3, nullptr, meta, etok);
  gemm_bt<6><<<dim3(Dc / 128, MAX_TILES), 256, 0, stream>>>(
      a13_c, w2_b, /*lda=*/1024, Dc, 1024, eo_c, nullptr, nullptr, nullptr,
      b2, meta, etok);

  // final: out = x2 + hs @ sdw^T + w0*eo[r0] + w1*eo[r1]
  gemm_bt<9, 64><<<dim3(Dc / 128, Tc / 64), 256, 0, stream>>>(
      hs_b, sdw_b, Tc, Dc, SH, eo_c, out, x2, nullptr, topk_w, rowid,
      nullptr);
}